// Round 1
// baseline (7855.000 us; speedup 1.0000x reference)
//
#include <hip/hip_runtime.h>
#include <math.h>

#define NN 2048
#define NB 8
#define FF 256
#define HH 128
#define KSEL 1025
#define NROWS (NB*NN)

// ---------- row stats: rowsum + diagonal, one wave per row ----------
__global__ __launch_bounds__(256) void rowstats_k(const float* __restrict__ A,
                                                  float* __restrict__ rowsum,
                                                  float* __restrict__ diag) {
  int gw = (blockIdx.x * 256 + threadIdx.x) >> 6;   // row id in [0, B*N)
  int lane = threadIdx.x & 63;
  const float* row = A + (long long)gw * NN;
  float s = 0.f;
  for (int j = lane; j < NN; j += 64) s += row[j];
  for (int off = 32; off > 0; off >>= 1) s += __shfl_down(s, off);
  if (lane == 0) { rowsum[gw] = s; diag[gw] = row[gw & (NN - 1)]; }
}

// ---------- derive dgcn (dense_gcn deg), dnorm (normalize_batch_adj deg), rz ----------
__global__ void derive_k(const float* __restrict__ rowsum, const float* __restrict__ diag,
                         float* __restrict__ dgcn, float* __restrict__ dnorm, float* __restrict__ rz) {
  int i = blockIdx.x * 256 + threadIdx.x;
  if (i >= NROWS) return;
  float rs = rowsum[i], dg = diag[i];
  dgcn[i]  = rsqrtf(fmaxf(rs - dg + 1.f, 1.f));  // a = adj offdiag, diag=1
  dnorm[i] = rsqrtf(fmaxf(rs + 1.f, 1.f));       // A = adj + I
  rz[i]    = rs > 0.f ? 1.f : 0.f;
}

// ---------- w = dnorm * (x @ Watt + batt), x feature dim = 128, one wave/row ----------
__global__ __launch_bounds__(256) void wvec_k(const float* __restrict__ x,
                                              const float* __restrict__ Watt,
                                              const float* __restrict__ batt,
                                              const float* __restrict__ dnorm,
                                              float* __restrict__ w) {
  int gw = (blockIdx.x * 256 + threadIdx.x) >> 6;
  int lane = threadIdx.x & 63;
  const float* r = x + (long long)gw * HH;
  float s = r[lane] * Watt[lane] + r[lane + 64] * Watt[lane + 64];
  for (int off = 32; off > 0; off >>= 1) s += __shfl_down(s, off);
  if (lane == 0) w[gw] = dnorm[gw] * (s + batt[0]);
}

// ---------- alpha = sigmoid((rz*dnorm*((ADJ+I)@w))^2), one wave/row ----------
__global__ __launch_bounds__(256) void alpha_k(const float* __restrict__ ADJ,
                                               const float* __restrict__ w,
                                               const float* __restrict__ dnorm,
                                               const float* __restrict__ rz,
                                               float* __restrict__ alpha) {
  int gw = (blockIdx.x * 256 + threadIdx.x) >> 6;
  int lane = threadIdx.x & 63;
  int b = gw >> 11, n = gw & (NN - 1);
  const float* row = ADJ + (long long)gw * NN;
  const float* wb = w + b * NN;
  float s = 0.f;
  for (int j = lane; j < NN; j += 64) s += row[j] * wb[j];
  for (int off = 32; off > 0; off >>= 1) s += __shfl_down(s, off);
  if (lane == 0) {
    float a = rz[gw] * dnorm[gw] * (s + wb[n]);
    a = a * a;
    alpha[gw] = 1.f / (1.f + expf(-a));
  }
}

// ---------- exact k-th largest via bitonic sort (2048 elems, 1024 threads) ----------
__global__ __launch_bounds__(1024) void topcut_k(const float* __restrict__ alpha, float* __restrict__ cut) {
  __shared__ float a[NN];
  int b = blockIdx.x, t = threadIdx.x;
  a[t] = alpha[b * NN + t];
  a[t + 1024] = alpha[b * NN + t + 1024];
  __syncthreads();
  for (int k = 2; k <= NN; k <<= 1) {
    for (int j = k >> 1; j > 0; j >>= 1) {
      for (int i = t; i < NN; i += 1024) {
        int ixj = i ^ j;
        if (ixj > i) {
          float x = a[i], y = a[ixj];
          bool up = ((i & k) == 0);
          if ((x > y) == up) { a[i] = y; a[ixj] = x; }
        }
      }
      __syncthreads();
    }
  }
  if (t == 0) cut[b] = a[NN - KSEL];  // k-th largest (ascending index N-K)
}

// ---------- colw = dnorm * relu(alpha + 1e-7 - cut) ----------
__global__ void colw_k(const float* __restrict__ alpha, const float* __restrict__ cut,
                       const float* __restrict__ dnorm, float* __restrict__ colw) {
  int i = blockIdx.x * 256 + threadIdx.x;
  if (i >= NROWS) return;
  int b = i >> 11;
  float c = fmaxf(alpha[i] + 1e-7f - cut[b], 0.f);
  colw[i] = dnorm[i] * c;
}

// ---------- scale_n = rz*dnorm / max(rowSsum, 1e-12), one wave/row ----------
__global__ __launch_bounds__(256) void scale_k(const float* __restrict__ ADJ,
                                               const float* __restrict__ colw,
                                               const float* __restrict__ dnorm,
                                               const float* __restrict__ rz,
                                               float* __restrict__ scale) {
  int gw = (blockIdx.x * 256 + threadIdx.x) >> 6;
  int lane = threadIdx.x & 63;
  int b = gw >> 11, n = gw & (NN - 1);
  const float* row = ADJ + (long long)gw * NN;
  const float* cw = colw + b * NN;
  float s = 0.f;
  for (int j = lane; j < NN; j += 64) s += row[j] * cw[j];
  for (int off = 32; off > 0; off >>= 1) s += __shfl_down(s, off);
  if (lane == 0) {
    float rsum = rz[gw] * dnorm[gw] * (s + cw[n]);  // L1 row sum of S_unnorm (all >= 0)
    scale[gw] = rz[gw] * dnorm[gw] / fmaxf(rsum, 1e-12f);
  }
}

// ---------- S[n,m] = scale_n * (ADJ[n,m] + delta_nm) * colw_m ----------
__global__ void writeS_k(const float* __restrict__ ADJ, const float* __restrict__ scale,
                         const float* __restrict__ colw, float* __restrict__ S) {
  long long i4 = ((long long)blockIdx.x * 256 + threadIdx.x) * 4;
  int bn = (int)(i4 >> 11);
  int b = bn >> 11;
  int n = bn & (NN - 1);
  int m = (int)(i4 & (NN - 1));
  float sc = scale[bn];
  float4 av = *(const float4*)(ADJ + i4);
  float4 cwv = *(const float4*)(colw + b * NN + m);
  float4 o;
  o.x = sc * (av.x + (float)(m     == n)) * cwv.x;
  o.y = sc * (av.y + (float)(m + 1 == n)) * cwv.y;
  o.z = sc * (av.z + (float)(m + 2 == n)) * cwv.z;
  o.w = sc * (av.w + (float)(m + 3 == n)) * cwv.w;
  *(float4*)(S + i4) = o;
}

// ---------- quantize: floor(x*10000)/10000 ----------
__global__ void quant_k(float* __restrict__ A) {
  long long i = (long long)blockIdx.x * 256 + threadIdx.x;
  A[i] = floorf(A[i] * 10000.f) / 10000.f;
}

// ---------- y = dgcn[row] * xw ----------
__global__ void scaley_k(const float* __restrict__ xw, const float* __restrict__ dgcn,
                         float* __restrict__ y, int shift) {
  long long i = (long long)blockIdx.x * 256 + threadIdx.x;
  int rowi = (int)(i >> shift);
  y[i] = dgcn[rowi] * xw[i];
}

// ---------- gcn epilogue: out = relu?((dgcn*(acc + (1-diag)*y) + bias) * mask) ----------
__global__ void epi_k(const float* __restrict__ acc, const float* __restrict__ y,
                      const float* __restrict__ dgcn, const float* __restrict__ diag,
                      const float* __restrict__ bias, const float* __restrict__ mask,
                      float* __restrict__ outx, int shift, int relu) {
  long long i = (long long)blockIdx.x * 256 + threadIdx.x;
  int rowi = (int)(i >> shift);
  int f = (int)(i & ((1 << shift) - 1));
  float t = dgcn[rowi] * (acc[i] + (1.f - diag[rowi]) * y[i]) + bias[f];
  t *= mask[rowi];
  if (relu) t = fmaxf(t, 0.f);
  outx[i] = t;
}

// ---------- column mean over n ----------
__global__ void mean_k(const float* __restrict__ X, float* __restrict__ out, int Fdim, int outoff) {
  int b = blockIdx.x, f = threadIdx.x;
  const float* p = X + (long long)b * NN * Fdim + f;
  float s = 0.f;
  for (int n = 0; n < NN; n++) s += p[(long long)n * Fdim];
  out[b * (HH + FF) + outoff + f] = s * (1.f / NN);
}

// ---------- fp32 GEMM: C = op(A) @ B.  BM=BN=128, BK=16, 256 thr, 8x8/thread ----------
// TRANSA=0: A is M x K row-major. TRANSA=1: A is K x M row-major (C = A^T B).
template<int TRANSA>
__global__ __launch_bounds__(256) void gemm_k(const float* __restrict__ A, const float* __restrict__ B,
                                              float* __restrict__ C, int M, int Nw, int Kk,
                                              long long sA, long long sB, long long sC) {
  __shared__ float As[16][128];
  __shared__ float Bs[16][128];
  int tid = threadIdx.x;
  int n0 = blockIdx.x * 128, m0 = blockIdx.y * 128;
  const float* Ab = A + (long long)blockIdx.z * sA;
  const float* Bb = B + (long long)blockIdx.z * sB;
  float* Cb = C + (long long)blockIdx.z * sC;
  float acc[8][8];
#pragma unroll
  for (int i = 0; i < 8; i++)
#pragma unroll
    for (int j = 0; j < 8; j++) acc[i][j] = 0.f;
  int tx = tid & 15, ty = tid >> 4;

  for (int k0 = 0; k0 < Kk; k0 += 16) {
    if (TRANSA == 0) {
      int r = tid >> 2, c = (tid & 3) << 2;
#pragma unroll
      for (int rr = 0; rr < 2; rr++) {
        int rrow = r + rr * 64;
        float4 v = *(const float4*)(Ab + (long long)(m0 + rrow) * Kk + k0 + c);
        As[c + 0][rrow] = v.x; As[c + 1][rrow] = v.y;
        As[c + 2][rrow] = v.z; As[c + 3][rrow] = v.w;
      }
    } else {
      int kk = tid >> 5, cc = (tid & 31) << 2;
#pragma unroll
      for (int k2 = 0; k2 < 2; k2++) {
        float4 v = *(const float4*)(Ab + (long long)(k0 + kk + k2 * 8) * M + m0 + cc);
        *(float4*)&As[kk + k2 * 8][cc] = v;
      }
    }
    {
      int kk = tid >> 5, cc = (tid & 31) << 2;
#pragma unroll
      for (int k2 = 0; k2 < 2; k2++) {
        float4 v = *(const float4*)(Bb + (long long)(k0 + kk + k2 * 8) * Nw + n0 + cc);
        *(float4*)&Bs[kk + k2 * 8][cc] = v;
      }
    }
    __syncthreads();
#pragma unroll
    for (int kk = 0; kk < 16; kk++) {
      float a[8], bb[8];
      *(float4*)&a[0]  = *(float4*)&As[kk][ty * 8];
      *(float4*)&a[4]  = *(float4*)&As[kk][ty * 8 + 4];
      *(float4*)&bb[0] = *(float4*)&Bs[kk][tx * 8];
      *(float4*)&bb[4] = *(float4*)&Bs[kk][tx * 8 + 4];
#pragma unroll
      for (int i = 0; i < 8; i++)
#pragma unroll
        for (int j = 0; j < 8; j++) acc[i][j] += a[i] * bb[j];
    }
    __syncthreads();
  }
#pragma unroll
  for (int i = 0; i < 8; i++) {
    float* cp = Cb + (long long)(m0 + ty * 8 + i) * Nw + n0 + tx * 8;
    *(float4*)cp = *(float4*)&acc[i][0];
    *(float4*)(cp + 4) = *(float4*)&acc[i][4];
  }
}

static inline void launch_gemm(const float* A, const float* B, float* C, int M, int Nw, int Kk,
                               long long sA, long long sB, long long sC, int batch, int transA,
                               hipStream_t st) {
  dim3 g(Nw / 128, M / 128, batch), blk(256);
  if (transA) gemm_k<1><<<g, blk, 0, st>>>(A, B, C, M, Nw, Kk, sA, sB, sC);
  else        gemm_k<0><<<g, blk, 0, st>>>(A, B, C, M, Nw, Kk, sA, sB, sC);
}

extern "C" void kernel_launch(void* const* d_in, const int* in_sizes, int n_in,
                              void* d_out, int out_size, void* d_ws, size_t ws_size,
                              hipStream_t stream) {
  const float* x    = (const float*)d_in[0];
  float*       adj  = (float*)d_in[1];   // overwritten with A2 (harness restores inputs)
  const float* mask = (const float*)d_in[2];
  const float* W1   = (const float*)d_in[3];
  const float* b1   = (const float*)d_in[4];
  const float* Watt = (const float*)d_in[5];
  const float* batt = (const float*)d_in[6];
  const float* W2   = (const float*)d_in[7];
  const float* b2   = (const float*)d_in[8];
  float* out = (float*)d_out;

  // workspace layout
  float* ws = (float*)d_ws;
  long long off = 0;
  float* bigA = ws + off; off += (long long)NB * NN * NN;   // S / y-buffer
  float* bigB = ws + off; off += (long long)NB * NN * NN;   // tmp / xw / acc buffer
  float* xa   = ws + off; off += (long long)NROWS * HH;
  float* xb   = ws + off; off += (long long)NROWS * HH;
  float* rowsum = ws + off; off += NROWS;
  float* diag   = ws + off; off += NROWS;
  float* dgcn   = ws + off; off += NROWS;
  float* dnorm  = ws + off; off += NROWS;
  float* rz     = ws + off; off += NROWS;
  float* wv     = ws + off; off += NROWS;
  float* alphav = ws + off; off += NROWS;
  float* colwv  = ws + off; off += NROWS;
  float* scalev = ws + off; off += NROWS;
  float* cutv   = ws + off; off += NB;

  const long long NN2 = (long long)NN * NN;

  // ================= GCN1 =================
  rowstats_k<<<NROWS / 4, 256, 0, stream>>>(adj, rowsum, diag);
  derive_k<<<NROWS / 256, 256, 0, stream>>>(rowsum, diag, dgcn, dnorm, rz);
  // xw1 = x @ W1  -> bigB  (M=B*N, K=256, N=128)
  launch_gemm(x, W1, bigB, NROWS, HH, FF, 0, 0, 0, 1, 0, stream);
  // y1 = dgcn * xw1 -> bigA
  scaley_k<<<(NROWS * HH) / 256, 256, 0, stream>>>(bigB, dgcn, bigA, 7);
  // acc1 = adj @ y1 -> bigB
  launch_gemm(adj, bigA, bigB, NN, HH, NN, NN2, (long long)NN * HH, (long long)NN * HH, NB, 0, stream);
  // x1 = relu((dgcn*(acc + (1-diag)*y) + b1) * mask) -> xa
  epi_k<<<(NROWS * HH) / 256, 256, 0, stream>>>(bigB, bigA, dgcn, diag, b1, mask, xa, 7, 1);
  mean_k<<<NB, HH, 0, stream>>>(xa, out, HH, 0);

  // ================= 2 coarsen layers =================
  float* curx = xa;
  float* nxtx = xb;
  for (int layer = 0; layer < 2; layer++) {
    if (layer > 0) {
      rowstats_k<<<NROWS / 4, 256, 0, stream>>>(adj, rowsum, diag);
      derive_k<<<NROWS / 256, 256, 0, stream>>>(rowsum, diag, dgcn, dnorm, rz);
    }
    wvec_k<<<NROWS / 4, 256, 0, stream>>>(curx, Watt, batt, dnorm, wv);
    alpha_k<<<NROWS / 4, 256, 0, stream>>>(adj, wv, dnorm, rz, alphav);
    topcut_k<<<NB, 1024, 0, stream>>>(alphav, cutv);
    colw_k<<<NROWS / 256, 256, 0, stream>>>(alphav, cutv, dnorm, colwv);
    scale_k<<<NROWS / 4, 256, 0, stream>>>(adj, colwv, dnorm, rz, scalev);
    writeS_k<<<(int)(NB * NN2 / 4 / 256), 256, 0, stream>>>(adj, scalev, colwv, bigA);
    // tmp = adj @ S -> bigB
    launch_gemm(adj, bigA, bigB, NN, NN, NN, NN2, NN2, NN2, NB, 0, stream);
    // x2 = S^T @ x -> nxtx
    launch_gemm(bigA, curx, nxtx, NN, HH, NN, NN2, (long long)NN * HH, (long long)NN * HH, NB, 1, stream);
    // A2 = S^T @ tmp -> adj (input buffer reuse; adj no longer needed)
    launch_gemm(bigA, bigB, adj, NN, NN, NN, NN2, NN2, NN2, NB, 1, stream);
    quant_k<<<(int)(NB * NN2 / 256), 256, 0, stream>>>(adj);
    float* t = curx; curx = nxtx; nxtx = t;
  }

  // ================= final GCN =================
  rowstats_k<<<NROWS / 4, 256, 0, stream>>>(adj, rowsum, diag);
  derive_k<<<NROWS / 256, 256, 0, stream>>>(rowsum, diag, dgcn, dnorm, rz);
  // xw2 = curx @ W2 -> bigB  (M=B*N, K=128, N=256)
  launch_gemm(curx, W2, bigB, NROWS, FF, HH, 0, 0, 0, 1, 0, stream);
  // y2 = dgcn * xw2 -> bigA
  scaley_k<<<(NROWS * FF) / 256, 256, 0, stream>>>(bigB, dgcn, bigA, 8);
  // acc2 = adj @ y2 -> bigB
  launch_gemm(adj, bigA, bigB, NN, FF, NN, NN2, (long long)NN * FF, (long long)NN * FF, NB, 0, stream);
  // x2 = (dgcn*(acc + (1-diag)*y) + b2) * mask  (in place on bigB)
  epi_k<<<(NROWS * FF) / 256, 256, 0, stream>>>(bigB, bigA, dgcn, diag, b2, mask, bigB, 8, 0);
  mean_k<<<NB, FF, 0, stream>>>(bigB, out, FF, HH);
}

// Round 2
// 3333.289 us; speedup vs baseline: 2.3565x; 2.3565x over previous
//
#include <hip/hip_runtime.h>
#include <math.h>

#define NN 2048
#define NB 8
#define FF 256
#define HH 128
#define KSEL 1025
#define NROWS (NB*NN)

typedef unsigned short ushort_t;
typedef __attribute__((ext_vector_type(8))) short short8;
typedef __attribute__((ext_vector_type(4))) float f32x4;

__device__ inline ushort_t f2bf(float f) {
  unsigned u = __float_as_uint(f);
  unsigned r = (u + 0x7FFFu + ((u >> 16) & 1u)) >> 16;
  return (ushort_t)r;
}
__device__ inline float bf2f(ushort_t u) {
  unsigned x = ((unsigned)u) << 16;
  return __uint_as_float(x);
}

#define GLDS16(g, l) __builtin_amdgcn_global_load_lds( \
    (const __attribute__((address_space(1))) unsigned int*)(g), \
    (__attribute__((address_space(3))) unsigned int*)(l), 16, 0, 0)

// ---------- row stats: rowsum + diagonal, one wave per row ----------
__global__ __launch_bounds__(256) void rowstats_k(const float* __restrict__ A,
                                                  float* __restrict__ rowsum,
                                                  float* __restrict__ diag) {
  int gw = (blockIdx.x * 256 + threadIdx.x) >> 6;
  int lane = threadIdx.x & 63;
  const float* row = A + (long long)gw * NN;
  float s = 0.f;
  for (int j = lane; j < NN; j += 64) s += row[j];
  for (int off = 32; off > 0; off >>= 1) s += __shfl_down(s, off);
  if (lane == 0) { rowsum[gw] = s; diag[gw] = row[gw & (NN - 1)]; }
}

__global__ void derive_k(const float* __restrict__ rowsum, const float* __restrict__ diag,
                         float* __restrict__ dgcn, float* __restrict__ dnorm, float* __restrict__ rz) {
  int i = blockIdx.x * 256 + threadIdx.x;
  if (i >= NROWS) return;
  float rs = rowsum[i], dg = diag[i];
  dgcn[i]  = rsqrtf(fmaxf(rs - dg + 1.f, 1.f));
  dnorm[i] = rsqrtf(fmaxf(rs + 1.f, 1.f));
  rz[i]    = rs > 0.f ? 1.f : 0.f;
}

__global__ __launch_bounds__(256) void wvec_k(const float* __restrict__ x,
                                              const float* __restrict__ Watt,
                                              const float* __restrict__ batt,
                                              const float* __restrict__ dnorm,
                                              float* __restrict__ w) {
  int gw = (blockIdx.x * 256 + threadIdx.x) >> 6;
  int lane = threadIdx.x & 63;
  const float* r = x + (long long)gw * HH;
  float s = r[lane] * Watt[lane] + r[lane + 64] * Watt[lane + 64];
  for (int off = 32; off > 0; off >>= 1) s += __shfl_down(s, off);
  if (lane == 0) w[gw] = dnorm[gw] * (s + batt[0]);
}

__global__ __launch_bounds__(256) void alpha_k(const float* __restrict__ ADJ,
                                               const float* __restrict__ w,
                                               const float* __restrict__ dnorm,
                                               const float* __restrict__ rz,
                                               float* __restrict__ alpha) {
  int gw = (blockIdx.x * 256 + threadIdx.x) >> 6;
  int lane = threadIdx.x & 63;
  int b = gw >> 11, n = gw & (NN - 1);
  const float* row = ADJ + (long long)gw * NN;
  const float* wb = w + b * NN;
  float s = 0.f;
  for (int j = lane; j < NN; j += 64) s += row[j] * wb[j];
  for (int off = 32; off > 0; off >>= 1) s += __shfl_down(s, off);
  if (lane == 0) {
    float a = rz[gw] * dnorm[gw] * (s + wb[n]);
    a = a * a;
    alpha[gw] = 1.f / (1.f + expf(-a));
  }
}

__global__ __launch_bounds__(1024) void topcut_k(const float* __restrict__ alpha, float* __restrict__ cut) {
  __shared__ float a[NN];
  int b = blockIdx.x, t = threadIdx.x;
  a[t] = alpha[b * NN + t];
  a[t + 1024] = alpha[b * NN + t + 1024];
  __syncthreads();
  for (int k = 2; k <= NN; k <<= 1) {
    for (int j = k >> 1; j > 0; j >>= 1) {
      for (int i = t; i < NN; i += 1024) {
        int ixj = i ^ j;
        if (ixj > i) {
          float x = a[i], y = a[ixj];
          bool up = ((i & k) == 0);
          if ((x > y) == up) { a[i] = y; a[ixj] = x; }
        }
      }
      __syncthreads();
    }
  }
  if (t == 0) cut[b] = a[NN - KSEL];
}

__global__ void colw_k(const float* __restrict__ alpha, const float* __restrict__ cut,
                       const float* __restrict__ dnorm, float* __restrict__ colw) {
  int i = blockIdx.x * 256 + threadIdx.x;
  if (i >= NROWS) return;
  int b = i >> 11;
  float c = fmaxf(alpha[i] + 1e-7f - cut[b], 0.f);
  colw[i] = dnorm[i] * c;
}

__global__ __launch_bounds__(256) void scale_k(const float* __restrict__ ADJ,
                                               const float* __restrict__ colw,
                                               const float* __restrict__ dnorm,
                                               const float* __restrict__ rz,
                                               float* __restrict__ scale) {
  int gw = (blockIdx.x * 256 + threadIdx.x) >> 6;
  int lane = threadIdx.x & 63;
  int b = gw >> 11, n = gw & (NN - 1);
  const float* row = ADJ + (long long)gw * NN;
  const float* cw = colw + b * NN;
  float s = 0.f;
  for (int j = lane; j < NN; j += 64) s += row[j] * cw[j];
  for (int off = 32; off > 0; off >>= 1) s += __shfl_down(s, off);
  if (lane == 0) {
    float rsum = rz[gw] * dnorm[gw] * (s + cw[n]);
    scale[gw] = rz[gw] * dnorm[gw] / fmaxf(rsum, 1e-12f);
  }
}

// ---------- St[l][k] = scale_k * (adj[l][k] + delta_kl) * colw_l (adj symmetric), split bf16 ----------
__global__ void writeSbt_k(const float* __restrict__ ADJ, const float* __restrict__ scale,
                           const float* __restrict__ colw,
                           ushort_t* __restrict__ Sh, ushort_t* __restrict__ Sl) {
  long long i4 = ((long long)blockIdx.x * 256 + threadIdx.x) * 4;
  int bl = (int)(i4 >> 11);
  int b = bl >> 11, l = bl & (NN - 1);
  int k = (int)(i4 & (NN - 1));
  float cw = colw[bl];
  float4 sc = *(const float4*)(scale + b * NN + k);
  float4 av = *(const float4*)(ADJ + i4);
  float v0 = sc.x * (av.x + (float)(k     == l)) * cw;
  float v1 = sc.y * (av.y + (float)(k + 1 == l)) * cw;
  float v2 = sc.z * (av.z + (float)(k + 2 == l)) * cw;
  float v3 = sc.w * (av.w + (float)(k + 3 == l)) * cw;
  ushort_t h0 = f2bf(v0), h1 = f2bf(v1), h2 = f2bf(v2), h3 = f2bf(v3);
  *(uint2*)&Sh[i4] = make_uint2((unsigned)h0 | ((unsigned)h1 << 16),
                                (unsigned)h2 | ((unsigned)h3 << 16));
  ushort_t l0 = f2bf(v0 - bf2f(h0)), l1 = f2bf(v1 - bf2f(h1));
  ushort_t l2 = f2bf(v2 - bf2f(h2)), l3 = f2bf(v3 - bf2f(h3));
  *(uint2*)&Sl[i4] = make_uint2((unsigned)l0 | ((unsigned)l1 << 16),
                                (unsigned)l2 | ((unsigned)l3 << 16));
}

// ---------- transpose + split: xT[b][f][n] = curx[b][n][f] ----------
__global__ __launch_bounds__(256) void cvt_xT_k(const float* __restrict__ X,
                                                ushort_t* __restrict__ Th, ushort_t* __restrict__ Tl) {
  __shared__ float t[32][33];
  int b = blockIdx.z;
  int n0 = blockIdx.x * 32, f0 = blockIdx.y * 32;
  int tx = threadIdx.x & 31, ty = threadIdx.x >> 5;   // 8 rows of threads
  const float* Xb = X + ((long long)b * NN + n0) * HH + f0;
  for (int r = ty; r < 32; r += 8) t[r][tx] = Xb[(long long)r * HH + tx];
  __syncthreads();
  for (int r = ty; r < 32; r += 8) {
    float v = t[tx][r];                               // out[f0+r][n0+tx]
    ushort_t h = f2bf(v);
    long long idx = ((long long)b * HH + f0 + r) * NN + n0 + tx;
    Th[idx] = h;
    Tl[idx] = f2bf(v - bf2f(h));
  }
}

// ============ MFMA split-bf16 GEMM ============
// C[m][n] = sum_k A[m][k]*B[n][k]   (B given in [n][k] i.e. B^T row-major)
// A = Ah + Al (bf16 split).  B either bf16 split (Bh/Bl) or fp32 (Bf, BCVT=1, split in-kernel).
// Products: Ah*Bh (+ Ah*Bl if SB) (+ Al*Bh if SA).
// EPI: 0 = fp32 store, 1 = split-bf16 store (Toh/Tol), 2 = fp32 store with floor(x*1e4)/1e4.
template<int SA, int SB, int BCVT, int EPI>
__global__ __launch_bounds__(256) void mgemm_k(
    const ushort_t* __restrict__ Ah, const ushort_t* __restrict__ Al,
    const ushort_t* __restrict__ Bh, const ushort_t* __restrict__ Bl,
    const float* __restrict__ Bf,
    float* __restrict__ Co, ushort_t* __restrict__ Toh, ushort_t* __restrict__ Tol,
    int M, int Ncol, int K, long long sA, long long sB, long long sC) {
  __shared__ ushort_t Ahs[128 * 32];
  __shared__ ushort_t Bhs[128 * 32];
  __shared__ ushort_t Als[SA ? 128 * 32 : 64];
  __shared__ ushort_t Bls[(SB && !BCVT) ? 128 * 32 : (SB ? 128 * 32 : 64)];

  int tid = threadIdx.x;
  int n0 = blockIdx.x * 128, m0 = blockIdx.y * 128;
  long long bz = blockIdx.z;
  const ushort_t* Ahb = Ah + bz * sA;
  const ushort_t* Alb = SA ? (Al + bz * sA) : Ah;
  const ushort_t* Bhb = (!BCVT) ? (Bh + bz * sB) : (const ushort_t*)0;
  const ushort_t* Blb = (!BCVT && SB) ? (Bl + bz * sB) : (const ushort_t*)0;
  const float*    Bfb = BCVT ? (Bf + bz * sB) : (const float*)0;

  int sr = tid >> 2;            // staging row 0..63
  int sc = (tid & 3) * 8;       // elem offset (8 bf16 = 16B)
  int br = tid >> 1, bc = (tid & 1) * 16;  // BCVT staging: 2 thr/row, 16 floats each
  int lane = tid & 63, w = tid >> 6;
  int wm = (w >> 1) * 64, wn = (w & 1) * 64;
  int fr = lane & 15;           // m or n within 16-tile
  int fo = (lane >> 4) * 8;     // k offset
  int q = lane >> 4;

  f32x4 acc[4][4];
  f32x4 zz = {0.f, 0.f, 0.f, 0.f};
#pragma unroll
  for (int i = 0; i < 4; i++)
#pragma unroll
    for (int j = 0; j < 4; j++) acc[i][j] = zz;

  for (int k0 = 0; k0 < K; k0 += 32) {
    __syncthreads();
    // stage A hi (+lo) via global_load_lds (16B/lane, LDS dest = contiguous lane order)
#pragma unroll
    for (int r = 0; r < 128; r += 64) {
      GLDS16(Ahb + (long long)(m0 + sr + r) * K + k0 + sc, &Ahs[(r + sr) * 32 + sc]);
      if constexpr (SA) {
        GLDS16(Alb + (long long)(m0 + sr + r) * K + k0 + sc, &Als[(r + sr) * 32 + sc]);
      }
    }
    if constexpr (!BCVT) {
#pragma unroll
      for (int r = 0; r < 128; r += 64) {
        GLDS16(Bhb + (long long)(n0 + sr + r) * K + k0 + sc, &Bhs[(r + sr) * 32 + sc]);
        if constexpr (SB) {
          GLDS16(Blb + (long long)(n0 + sr + r) * K + k0 + sc, &Bls[(r + sr) * 32 + sc]);
        }
      }
    } else {
      // load 16 fp32 from B row, convert to split bf16, write LDS
      const float* g = Bfb + (long long)(n0 + br) * K + k0 + bc;
      float vv[16];
      *(float4*)&vv[0]  = *(const float4*)(g);
      *(float4*)&vv[4]  = *(const float4*)(g + 4);
      *(float4*)&vv[8]  = *(const float4*)(g + 8);
      *(float4*)&vv[12] = *(const float4*)(g + 12);
      unsigned ph[8], pl[8];
#pragma unroll
      for (int t = 0; t < 8; t++) {
        ushort_t h0 = f2bf(vv[2 * t]), h1 = f2bf(vv[2 * t + 1]);
        ph[t] = (unsigned)h0 | ((unsigned)h1 << 16);
        if constexpr (SB) {
          ushort_t l0 = f2bf(vv[2 * t] - bf2f(h0)), l1 = f2bf(vv[2 * t + 1] - bf2f(h1));
          pl[t] = (unsigned)l0 | ((unsigned)l1 << 16);
        }
      }
      *(uint4*)&Bhs[br * 32 + bc]     = make_uint4(ph[0], ph[1], ph[2], ph[3]);
      *(uint4*)&Bhs[br * 32 + bc + 8] = make_uint4(ph[4], ph[5], ph[6], ph[7]);
      if constexpr (SB) {
        *(uint4*)&Bls[br * 32 + bc]     = make_uint4(pl[0], pl[1], pl[2], pl[3]);
        *(uint4*)&Bls[br * 32 + bc + 8] = make_uint4(pl[4], pl[5], pl[6], pl[7]);
      }
    }
    __syncthreads();

    short8 ah[4], al[4], bh[4], bl[4];
#pragma unroll
    for (int i = 0; i < 4; i++) {
      ah[i] = *(const short8*)&Ahs[(wm + i * 16 + fr) * 32 + fo];
      if constexpr (SA) al[i] = *(const short8*)&Als[(wm + i * 16 + fr) * 32 + fo];
    }
#pragma unroll
    for (int j = 0; j < 4; j++) {
      bh[j] = *(const short8*)&Bhs[(wn + j * 16 + fr) * 32 + fo];
      if constexpr (SB) bl[j] = *(const short8*)&Bls[(wn + j * 16 + fr) * 32 + fo];
    }
#pragma unroll
    for (int i = 0; i < 4; i++)
#pragma unroll
      for (int j = 0; j < 4; j++) {
        acc[i][j] = __builtin_amdgcn_mfma_f32_16x16x32_bf16(ah[i], bh[j], acc[i][j], 0, 0, 0);
        if constexpr (SB)
          acc[i][j] = __builtin_amdgcn_mfma_f32_16x16x32_bf16(ah[i], bl[j], acc[i][j], 0, 0, 0);
        if constexpr (SA)
          acc[i][j] = __builtin_amdgcn_mfma_f32_16x16x32_bf16(al[i], bh[j], acc[i][j], 0, 0, 0);
      }
  }

  // epilogue: C/D layout col=lane&15, row=quad*4+reg  [m89-verified]
#pragma unroll
  for (int i = 0; i < 4; i++)
#pragma unroll
    for (int j = 0; j < 4; j++)
#pragma unroll
      for (int r = 0; r < 4; r++) {
        float v = acc[i][j][r];
        long long row = m0 + wm + i * 16 + q * 4 + r;
        long long col = n0 + wn + j * 16 + fr;
        long long idx = bz * sC + row * (long long)Ncol + col;
        if constexpr (EPI == 0) {
          Co[idx] = v;
        } else if constexpr (EPI == 2) {
          Co[idx] = floorf(v * 10000.f) / 10000.f;
        } else {
          ushort_t h = f2bf(v);
          Toh[idx] = h;
          Tol[idx] = f2bf(v - bf2f(h));
        }
      }
}

// ---------- y = dgcn[row] * xw ----------
__global__ void scaley_k(const float* __restrict__ xw, const float* __restrict__ dgcn,
                         float* __restrict__ y, int shift) {
  long long i = (long long)blockIdx.x * 256 + threadIdx.x;
  int rowi = (int)(i >> shift);
  y[i] = dgcn[rowi] * xw[i];
}

__global__ void epi_k(const float* __restrict__ acc, const float* __restrict__ y,
                      const float* __restrict__ dgcn, const float* __restrict__ diag,
                      const float* __restrict__ bias, const float* __restrict__ mask,
                      float* __restrict__ outx, int shift, int relu) {
  long long i = (long long)blockIdx.x * 256 + threadIdx.x;
  int rowi = (int)(i >> shift);
  int f = (int)(i & ((1 << shift) - 1));
  float t = dgcn[rowi] * (acc[i] + (1.f - diag[rowi]) * y[i]) + bias[f];
  t *= mask[rowi];
  if (relu) t = fmaxf(t, 0.f);
  outx[i] = t;
}

__global__ void mean_k(const float* __restrict__ X, float* __restrict__ out, int Fdim, int outoff) {
  int b = blockIdx.x, f = threadIdx.x;
  const float* p = X + (long long)b * NN * Fdim + f;
  float s = 0.f;
  for (int n = 0; n < NN; n++) s += p[(long long)n * Fdim];
  out[b * (HH + FF) + outoff + f] = s * (1.f / NN);
}

// ---------- fp32 VALU GEMM for the small matmuls ----------
template<int TRANSA>
__global__ __launch_bounds__(256) void gemm_k(const float* __restrict__ A, const float* __restrict__ B,
                                              float* __restrict__ C, int M, int Nw, int Kk,
                                              long long sA, long long sB, long long sC) {
  __shared__ float As[16][128];
  __shared__ float Bs[16][128];
  int tid = threadIdx.x;
  int n0 = blockIdx.x * 128, m0 = blockIdx.y * 128;
  const float* Ab = A + (long long)blockIdx.z * sA;
  const float* Bb = B + (long long)blockIdx.z * sB;
  float* Cb = C + (long long)blockIdx.z * sC;
  float acc[8][8];
#pragma unroll
  for (int i = 0; i < 8; i++)
#pragma unroll
    for (int j = 0; j < 8; j++) acc[i][j] = 0.f;
  int tx = tid & 15, ty = tid >> 4;

  for (int k0 = 0; k0 < Kk; k0 += 16) {
    if (TRANSA == 0) {
      int r = tid >> 2, c = (tid & 3) << 2;
#pragma unroll
      for (int rr = 0; rr < 2; rr++) {
        int rrow = r + rr * 64;
        float4 v = *(const float4*)(Ab + (long long)(m0 + rrow) * Kk + k0 + c);
        As[c + 0][rrow] = v.x; As[c + 1][rrow] = v.y;
        As[c + 2][rrow] = v.z; As[c + 3][rrow] = v.w;
      }
    } else {
      int kk = tid >> 5, cc = (tid & 31) << 2;
#pragma unroll
      for (int k2 = 0; k2 < 2; k2++) {
        float4 v = *(const float4*)(Ab + (long long)(k0 + kk + k2 * 8) * M + m0 + cc);
        *(float4*)&As[kk + k2 * 8][cc] = v;
      }
    }
    {
      int kk = tid >> 5, cc = (tid & 31) << 2;
#pragma unroll
      for (int k2 = 0; k2 < 2; k2++) {
        float4 v = *(const float4*)(Bb + (long long)(k0 + kk + k2 * 8) * Nw + n0 + cc);
        *(float4*)&Bs[kk + k2 * 8][cc] = v;
      }
    }
    __syncthreads();
#pragma unroll
    for (int kk = 0; kk < 16; kk++) {
      float a[8], bb[8];
      *(float4*)&a[0]  = *(float4*)&As[kk][ty * 8];
      *(float4*)&a[4]  = *(float4*)&As[kk][ty * 8 + 4];
      *(float4*)&bb[0] = *(float4*)&Bs[kk][tx * 8];
      *(float4*)&bb[4] = *(float4*)&Bs[kk][tx * 8 + 4];
#pragma unroll
      for (int i = 0; i < 8; i++)
#pragma unroll
        for (int j = 0; j < 8; j++) acc[i][j] += a[i] * bb[j];
    }
    __syncthreads();
  }
#pragma unroll
  for (int i = 0; i < 8; i++) {
    float* cp = Cb + (long long)(m0 + ty * 8 + i) * Nw + n0 + tx * 8;
    *(float4*)cp = *(float4*)&acc[i][0];
    *(float4*)(cp + 4) = *(float4*)&acc[i][4];
  }
}

static inline void launch_gemm(const float* A, const float* B, float* C, int M, int Nw, int Kk,
                               long long sA, long long sB, long long sC, int batch, int transA,
                               hipStream_t st) {
  dim3 g(Nw / 128, M / 128, batch), blk(256);
  if (transA) gemm_k<1><<<g, blk, 0, st>>>(A, B, C, M, Nw, Kk, sA, sB, sC);
  else        gemm_k<0><<<g, blk, 0, st>>>(A, B, C, M, Nw, Kk, sA, sB, sC);
}

extern "C" void kernel_launch(void* const* d_in, const int* in_sizes, int n_in,
                              void* d_out, int out_size, void* d_ws, size_t ws_size,
                              hipStream_t stream) {
  const float* x    = (const float*)d_in[0];
  float*       adj  = (float*)d_in[1];   // overwritten with A2 (harness restores inputs)
  const float* mask = (const float*)d_in[2];
  const float* W1   = (const float*)d_in[3];
  const float* b1   = (const float*)d_in[4];
  const float* Watt = (const float*)d_in[5];
  const float* batt = (const float*)d_in[6];
  const float* W2   = (const float*)d_in[7];
  const float* b2   = (const float*)d_in[8];
  float* out = (float*)d_out;

  const long long NN2 = (long long)NN * NN;          // 4,194,304
  const long long BIG = (long long)NB * NN2;         // 33,554,432 elements

  // ---- workspace layout (~286 MB, same footprint as the passing round-1 layout) ----
  float* ws = (float*)d_ws;
  long long off = 0;
  ushort_t* Sth = (ushort_t*)(ws + off); off += BIG / 2;   // bf16 hi of S^T  (67.1 MB)
  ushort_t* Stl = (ushort_t*)(ws + off); off += BIG / 2;   // bf16 lo of S^T
  float* Treg = ws + off; off += BIG;                      // 134.2 MB multi-phase region
  float* xa   = ws + off; off += (long long)NROWS * HH;
  float* xb   = ws + off; off += (long long)NROWS * HH;
  float* rowsum = ws + off; off += NROWS;
  float* diag   = ws + off; off += NROWS;
  float* dgcn   = ws + off; off += NROWS;
  float* dnorm  = ws + off; off += NROWS;
  float* rz     = ws + off; off += NROWS;
  float* wv     = ws + off; off += NROWS;
  float* alphav = ws + off; off += NROWS;
  float* colwv  = ws + off; off += NROWS;
  float* scalev = ws + off; off += NROWS;
  float* cutv   = ws + off; off += NB;

  // phase-overlapped views of Treg:
  ushort_t* Th = (ushort_t*)Treg;        // tmp^T hi (bf16), live GEMM1 -> GEMM3
  ushort_t* Tl = Th + BIG;               // tmp^T lo
  float* u1 = Treg;                      // GCN scratch (outside coarsen loop only)
  float* u2 = Treg + (long long)NROWS * FF;
  ushort_t* xTh = (ushort_t*)Treg;       // x^T split (after GEMM3, before next GEMM1)
  ushort_t* xTl = xTh + (long long)NB * HH * NN;

  // ================= GCN1 =================
  rowstats_k<<<NROWS / 4, 256, 0, stream>>>(adj, rowsum, diag);
  derive_k<<<NROWS / 256, 256, 0, stream>>>(rowsum, diag, dgcn, dnorm, rz);
  launch_gemm(x, W1, u1, NROWS, HH, FF, 0, 0, 0, 1, 0, stream);            // xw1 = x@W1
  scaley_k<<<(NROWS * HH) / 256, 256, 0, stream>>>(u1, dgcn, u2, 7);       // y1
  launch_gemm(adj, u2, u1, NN, HH, NN, NN2, (long long)NN * HH, (long long)NN * HH, NB, 0, stream);
  epi_k<<<(NROWS * HH) / 256, 256, 0, stream>>>(u1, u2, dgcn, diag, b1, mask, xa, 7, 1);
  mean_k<<<NB, HH, 0, stream>>>(xa, out, HH, 0);

  // ================= 2 coarsen layers =================
  float* curx = xa;
  float* nxtx = xb;
  for (int layer = 0; layer < 2; layer++) {
    if (layer > 0) {
      rowstats_k<<<NROWS / 4, 256, 0, stream>>>(adj, rowsum, diag);
      derive_k<<<NROWS / 256, 256, 0, stream>>>(rowsum, diag, dgcn, dnorm, rz);
    }
    wvec_k<<<NROWS / 4, 256, 0, stream>>>(curx, Watt, batt, dnorm, wv);
    alpha_k<<<NROWS / 4, 256, 0, stream>>>(adj, wv, dnorm, rz, alphav);
    topcut_k<<<NB, 1024, 0, stream>>>(alphav, cutv);
    colw_k<<<NROWS / 256, 256, 0, stream>>>(alphav, cutv, dnorm, colwv);
    scale_k<<<NROWS / 4, 256, 0, stream>>>(adj, colwv, dnorm, rz, scalev);
    writeSbt_k<<<(int)(BIG / 4 / 256), 256, 0, stream>>>(adj, scalev, colwv, Sth, Stl);

    dim3 gbig(NN / 128, NN / 128, NB), blk(256);
    // tmp^T = S^T @ adj  (adj symmetric) -> Th/Tl (split-bf16 epilogue)
    if (layer == 0)  // binary adj: exact in bf16, skip B-lo product
      mgemm_k<1, 0, 1, 1><<<gbig, blk, 0, stream>>>(Sth, Stl, 0, 0, adj, 0, Th, Tl,
                                                    NN, NN, NN, NN2, NN2, NN2);
    else
      mgemm_k<1, 1, 1, 1><<<gbig, blk, 0, stream>>>(Sth, Stl, 0, 0, adj, 0, Th, Tl,
                                                    NN, NN, NN, NN2, NN2, NN2);
    // A2 = S^T @ tmp = St * T  -> adj, fused floor-quant
    mgemm_k<1, 1, 0, 2><<<gbig, blk, 0, stream>>>(Sth, Stl, Th, Tl, 0, adj, 0, 0,
                                                  NN, NN, NN, NN2, NN2, NN2);
    // x2 = S^T @ curx : transpose+split curx, then MFMA (T region dead now)
    cvt_xT_k<<<dim3(NN / 32, HH / 32, NB), 256, 0, stream>>>(curx, xTh, xTl);
    mgemm_k<1, 1, 0, 0><<<dim3(1, NN / 128, NB), blk, 0, stream>>>(
        Sth, Stl, xTh, xTl, 0, nxtx, 0, 0,
        NN, HH, NN, NN2, (long long)HH * NN, (long long)NN * HH);
    float* t = curx; curx = nxtx; nxtx = t;
  }

  // ================= final GCN =================
  rowstats_k<<<NROWS / 4, 256, 0, stream>>>(adj, rowsum, diag);
  derive_k<<<NROWS / 256, 256, 0, stream>>>(rowsum, diag, dgcn, dnorm, rz);
  launch_gemm(curx, W2, u1, NROWS, FF, HH, 0, 0, 0, 1, 0, stream);         // xw2
  scaley_k<<<(NROWS * FF) / 256, 256, 0, stream>>>(u1, dgcn, u2, 8);       // y2
  launch_gemm(adj, u2, u1, NN, FF, NN, NN2, (long long)NN * FF, (long long)NN * FF, NB, 0, stream);
  epi_k<<<(NROWS * FF) / 256, 256, 0, stream>>>(u1, u2, dgcn, diag, b2, mask, u1, 8, 0);
  mean_k<<<NB, FF, 0, stream>>>(u1, out, FF, HH);
}

// Round 3
// 2470.893 us; speedup vs baseline: 3.1790x; 1.3490x over previous
//
#include <hip/hip_runtime.h>
#include <math.h>

#define NN 2048
#define NB 8
#define FF 256
#define HH 128
#define KSEL 1025
#define NROWS (NB*NN)
#define MPAD 1152                    // compact-row pad (keep ~1025 -> 9 blocks of 128)

typedef unsigned short ushort_t;
typedef __attribute__((ext_vector_type(8))) short short8;
typedef __attribute__((ext_vector_type(4))) float f32x4;

__device__ inline ushort_t f2bf(float f) {
  unsigned u = __float_as_uint(f);
  unsigned r = (u + 0x7FFFu + ((u >> 16) & 1u)) >> 16;
  return (ushort_t)r;
}
__device__ inline float bf2f(ushort_t u) {
  unsigned x = ((unsigned)u) << 16;
  return __uint_as_float(x);
}

#define GLDS16(g, l) __builtin_amdgcn_global_load_lds( \
    (const __attribute__((address_space(1))) unsigned int*)(g), \
    (__attribute__((address_space(3))) unsigned int*)(l), 16, 0, 0)

// ---------- row stats ----------
__global__ __launch_bounds__(256) void rowstats_k(const float* __restrict__ A,
                                                  float* __restrict__ rowsum,
                                                  float* __restrict__ diag) {
  int gw = (blockIdx.x * 256 + threadIdx.x) >> 6;
  int lane = threadIdx.x & 63;
  const float* row = A + (long long)gw * NN;
  float s = 0.f;
  for (int j = lane; j < NN; j += 64) s += row[j];
  for (int off = 32; off > 0; off >>= 1) s += __shfl_down(s, off);
  if (lane == 0) { rowsum[gw] = s; diag[gw] = row[gw & (NN - 1)]; }
}

__global__ void derive_k(const float* __restrict__ rowsum, const float* __restrict__ diag,
                         float* __restrict__ dgcn, float* __restrict__ dnorm, float* __restrict__ rz) {
  int i = blockIdx.x * 256 + threadIdx.x;
  if (i >= NROWS) return;
  float rs = rowsum[i], dg = diag[i];
  dgcn[i]  = rsqrtf(fmaxf(rs - dg + 1.f, 1.f));
  dnorm[i] = rsqrtf(fmaxf(rs + 1.f, 1.f));
  rz[i]    = rs > 0.f ? 1.f : 0.f;
}

__global__ __launch_bounds__(256) void wvec_k(const float* __restrict__ x,
                                              const float* __restrict__ Watt,
                                              const float* __restrict__ batt,
                                              const float* __restrict__ dnorm,
                                              float* __restrict__ w) {
  int gw = (blockIdx.x * 256 + threadIdx.x) >> 6;
  int lane = threadIdx.x & 63;
  const float* r = x + (long long)gw * HH;
  float s = r[lane] * Watt[lane] + r[lane + 64] * Watt[lane + 64];
  for (int off = 32; off > 0; off >>= 1) s += __shfl_down(s, off);
  if (lane == 0) w[gw] = dnorm[gw] * (s + batt[0]);
}

__global__ __launch_bounds__(256) void alpha_k(const float* __restrict__ ADJ,
                                               const float* __restrict__ w,
                                               const float* __restrict__ dnorm,
                                               const float* __restrict__ rz,
                                               float* __restrict__ alpha) {
  int gw = (blockIdx.x * 256 + threadIdx.x) >> 6;
  int lane = threadIdx.x & 63;
  int b = gw >> 11, n = gw & (NN - 1);
  const float* row = ADJ + (long long)gw * NN;
  const float* wb = w + b * NN;
  float s = 0.f;
  for (int j = lane; j < NN; j += 64) s += row[j] * wb[j];
  for (int off = 32; off > 0; off >>= 1) s += __shfl_down(s, off);
  if (lane == 0) {
    float a = rz[gw] * dnorm[gw] * (s + wb[n]);
    a = a * a;
    alpha[gw] = 1.f / (1.f + expf(-a));
  }
}

__global__ __launch_bounds__(1024) void topcut_k(const float* __restrict__ alpha, float* __restrict__ cut) {
  __shared__ float a[NN];
  int b = blockIdx.x, t = threadIdx.x;
  a[t] = alpha[b * NN + t];
  a[t + 1024] = alpha[b * NN + t + 1024];
  __syncthreads();
  for (int k = 2; k <= NN; k <<= 1) {
    for (int j = k >> 1; j > 0; j >>= 1) {
      for (int i = t; i < NN; i += 1024) {
        int ixj = i ^ j;
        if (ixj > i) {
          float x = a[i], y = a[ixj];
          bool up = ((i & k) == 0);
          if ((x > y) == up) { a[i] = y; a[ixj] = x; }
        }
      }
      __syncthreads();
    }
  }
  if (t == 0) cut[b] = a[NN - KSEL];
}

__global__ void colw_k(const float* __restrict__ alpha, const float* __restrict__ cut,
                       const float* __restrict__ dnorm, float* __restrict__ colw) {
  int i = blockIdx.x * 256 + threadIdx.x;
  if (i >= NROWS) return;
  int b = i >> 11;
  float c = fmaxf(alpha[i] + 1e-7f - cut[b], 0.f);
  colw[i] = dnorm[i] * c;
}

__global__ __launch_bounds__(256) void scale_k(const float* __restrict__ ADJ,
                                               const float* __restrict__ colw,
                                               const float* __restrict__ dnorm,
                                               const float* __restrict__ rz,
                                               float* __restrict__ scale) {
  int gw = (blockIdx.x * 256 + threadIdx.x) >> 6;
  int lane = threadIdx.x & 63;
  int b = gw >> 11, n = gw & (NN - 1);
  const float* row = ADJ + (long long)gw * NN;
  const float* cw = colw + b * NN;
  float s = 0.f;
  for (int j = lane; j < NN; j += 64) s += row[j] * cw[j];
  for (int off = 32; off > 0; off >>= 1) s += __shfl_down(s, off);
  if (lane == 0) {
    float rsum = rz[gw] * dnorm[gw] * (s + cw[n]);
    scale[gw] = rz[gw] * dnorm[gw] / fmaxf(rsum, 1e-12f);
  }
}

// ---------- keep list: column m of S nonzero iff colw_m != 0 && rz_m != 0 (exact) ----------
__global__ __launch_bounds__(1024) void keep_k(const float* __restrict__ colw,
                                               const float* __restrict__ rz,
                                               int* __restrict__ keepidx, int* __restrict__ cnt) {
  __shared__ int ps[NN];
  int b = blockIdx.x, t = threadIdx.x;
  int f0 = (colw[b * NN + t]        != 0.f && rz[b * NN + t]        != 0.f) ? 1 : 0;
  int f1 = (colw[b * NN + t + 1024] != 0.f && rz[b * NN + t + 1024] != 0.f) ? 1 : 0;
  ps[t] = f0; ps[t + 1024] = f1;
  __syncthreads();
  for (int off = 1; off < NN; off <<= 1) {
    int v0 = (t >= off) ? ps[t - off] : 0;
    int v1 = (t + 1024 >= off) ? ps[t + 1024 - off] : 0;
    __syncthreads();
    ps[t] += v0; ps[t + 1024] += v1;
    __syncthreads();
  }
  if (t < MPAD) keepidx[b * MPAD + t] = -1;
  if (t + 1024 < MPAD) keepidx[b * MPAD + t + 1024] = -1;
  __syncthreads();
  if (f0 && ps[t] - 1 < MPAD) keepidx[b * MPAD + ps[t] - 1] = t;
  if (f1 && ps[t + 1024] - 1 < MPAD) keepidx[b * MPAD + ps[t + 1024] - 1] = t + 1024;
  if (t == 0) cnt[b] = ps[NN - 1];
}

// ---------- adj (fp32, binary) -> bf16 hi ----------
__global__ void cvtadjh_k(const float* __restrict__ A, ushort_t* __restrict__ H) {
  long long i4 = ((long long)blockIdx.x * 256 + threadIdx.x) * 4;
  float4 v = *(const float4*)(A + i4);
  ushort_t h0 = f2bf(v.x), h1 = f2bf(v.y), h2 = f2bf(v.z), h3 = f2bf(v.w);
  *(uint2*)&H[i4] = make_uint2((unsigned)h0 | ((unsigned)h1 << 16),
                               (unsigned)h2 | ((unsigned)h3 << 16));
}

// ---------- compact Stc[i][n] = colw_{keep[i]} * scale_n * (adj[keep[i]][n] + delta), split ----------
__global__ void writeStc_k(const float* __restrict__ adj, const float* __restrict__ scale,
                           const float* __restrict__ colw, const int* __restrict__ keepidx,
                           ushort_t* __restrict__ Sh, ushort_t* __restrict__ Sl) {
  long long g = (long long)blockIdx.x * 256 + threadIdx.x;
  int bi = (int)(g >> 9);            // b*MPAD + i   (512 threads per row)
  int n = (int)(g & 511) * 4;
  int b = bi / MPAD;
  long long o = (long long)bi * NN + n;
  int row = keepidx[bi];
  if (row < 0) {
    *(uint2*)&Sh[o] = make_uint2(0, 0);
    *(uint2*)&Sl[o] = make_uint2(0, 0);
    return;
  }
  float cw = colw[b * NN + row];
  float4 sc = *(const float4*)(scale + b * NN + n);
  float4 av = *(const float4*)(adj + ((long long)b * NN + row) * NN + n);
  float v0 = sc.x * (av.x + (float)(n     == row)) * cw;
  float v1 = sc.y * (av.y + (float)(n + 1 == row)) * cw;
  float v2 = sc.z * (av.z + (float)(n + 2 == row)) * cw;
  float v3 = sc.w * (av.w + (float)(n + 3 == row)) * cw;
  ushort_t h0 = f2bf(v0), h1 = f2bf(v1), h2 = f2bf(v2), h3 = f2bf(v3);
  *(uint2*)&Sh[o] = make_uint2((unsigned)h0 | ((unsigned)h1 << 16),
                               (unsigned)h2 | ((unsigned)h3 << 16));
  ushort_t l0 = f2bf(v0 - bf2f(h0)), l1 = f2bf(v1 - bf2f(h1));
  ushort_t l2 = f2bf(v2 - bf2f(h2)), l3 = f2bf(v3 - bf2f(h3));
  *(uint2*)&Sl[o] = make_uint2((unsigned)l0 | ((unsigned)l1 << 16),
                               (unsigned)l2 | ((unsigned)l3 << 16));
}

// ---------- transpose + split: xT[b][f][n] = X[b][n][f], F=128 ----------
__global__ __launch_bounds__(256) void cvt_xT_k(const float* __restrict__ X,
                                                ushort_t* __restrict__ Th, ushort_t* __restrict__ Tl) {
  __shared__ float t[32][33];
  int b = blockIdx.z;
  int n0 = blockIdx.x * 32, f0 = blockIdx.y * 32;
  int tx = threadIdx.x & 31, ty = threadIdx.x >> 5;
  const float* Xb = X + ((long long)b * NN + n0) * HH + f0;
  for (int r = ty; r < 32; r += 8) t[r][tx] = Xb[(long long)r * HH + tx];
  __syncthreads();
  for (int r = ty; r < 32; r += 8) {
    float v = t[tx][r];
    ushort_t h = f2bf(v);
    long long idx = ((long long)b * HH + f0 + r) * NN + n0 + tx;
    Th[idx] = h;
    Tl[idx] = f2bf(v - bf2f(h));
  }
}

// ============ MFMA split-bf16 GEMM ============
// C[m][n] = sum_k A[m][k]*B[n][k].  Products: Ah*Bh (+Ah*Bl if SB) (+Al*Bh if SA).
// EPI: 0 fp32 store; 1 split-bf16 store; 3 scatter rows+cols via kmap into 2048-wide fp32 w/ floor-quant;
//      4 scatter rows via kmap, fp32.
template<int SA, int SB, int BCVT, int EPI>
__global__ __launch_bounds__(256) void mgemm_k(
    const ushort_t* __restrict__ Ah, const ushort_t* __restrict__ Al,
    const ushort_t* __restrict__ Bh, const ushort_t* __restrict__ Bl,
    const float* __restrict__ Bf,
    float* __restrict__ Co, ushort_t* __restrict__ Toh, ushort_t* __restrict__ Tol,
    int M, int Ncol, int K, long long sA, long long sB, long long sC,
    const int* __restrict__ kmap) {
  __shared__ ushort_t Ahs[128 * 32];
  __shared__ ushort_t Bhs[128 * 32];
  __shared__ ushort_t Als[SA ? 128 * 32 : 64];
  __shared__ ushort_t Bls[SB ? 128 * 32 : 64];

  int tid = threadIdx.x;
  int n0 = blockIdx.x * 128, m0 = blockIdx.y * 128;
  long long bz = blockIdx.z;
  const ushort_t* Ahb = Ah + bz * sA;
  const ushort_t* Alb = SA ? (Al + bz * sA) : Ah;
  const ushort_t* Bhb = (!BCVT) ? (Bh + bz * sB) : (const ushort_t*)0;
  const ushort_t* Blb = (!BCVT && SB) ? (Bl + bz * sB) : (const ushort_t*)0;
  const float*    Bfb = BCVT ? (Bf + bz * sB) : (const float*)0;

  int sr = tid >> 2;
  int sc = (tid & 3) * 8;
  int br = tid >> 1, bc = (tid & 1) * 16;
  int lane = tid & 63, w = tid >> 6;
  int wm = (w >> 1) * 64, wn = (w & 1) * 64;
  int fr = lane & 15;
  int fo = (lane >> 4) * 8;
  int q = lane >> 4;

  f32x4 acc[4][4];
  f32x4 zz = {0.f, 0.f, 0.f, 0.f};
#pragma unroll
  for (int i = 0; i < 4; i++)
#pragma unroll
    for (int j = 0; j < 4; j++) acc[i][j] = zz;

  for (int k0 = 0; k0 < K; k0 += 32) {
    __syncthreads();
#pragma unroll
    for (int r = 0; r < 128; r += 64) {
      GLDS16(Ahb + (long long)(m0 + sr + r) * K + k0 + sc, &Ahs[(r + sr) * 32 + sc]);
      if constexpr (SA) {
        GLDS16(Alb + (long long)(m0 + sr + r) * K + k0 + sc, &Als[(r + sr) * 32 + sc]);
      }
    }
    if constexpr (!BCVT) {
#pragma unroll
      for (int r = 0; r < 128; r += 64) {
        GLDS16(Bhb + (long long)(n0 + sr + r) * K + k0 + sc, &Bhs[(r + sr) * 32 + sc]);
        if constexpr (SB) {
          GLDS16(Blb + (long long)(n0 + sr + r) * K + k0 + sc, &Bls[(r + sr) * 32 + sc]);
        }
      }
    } else {
      const float* g = Bfb + (long long)(n0 + br) * K + k0 + bc;
      float vv[16];
      *(float4*)&vv[0]  = *(const float4*)(g);
      *(float4*)&vv[4]  = *(const float4*)(g + 4);
      *(float4*)&vv[8]  = *(const float4*)(g + 8);
      *(float4*)&vv[12] = *(const float4*)(g + 12);
      unsigned ph[8], pl[8];
#pragma unroll
      for (int t = 0; t < 8; t++) {
        ushort_t h0 = f2bf(vv[2 * t]), h1 = f2bf(vv[2 * t + 1]);
        ph[t] = (unsigned)h0 | ((unsigned)h1 << 16);
        if constexpr (SB) {
          ushort_t l0 = f2bf(vv[2 * t] - bf2f(h0)), l1 = f2bf(vv[2 * t + 1] - bf2f(h1));
          pl[t] = (unsigned)l0 | ((unsigned)l1 << 16);
        }
      }
      *(uint4*)&Bhs[br * 32 + bc]     = make_uint4(ph[0], ph[1], ph[2], ph[3]);
      *(uint4*)&Bhs[br * 32 + bc + 8] = make_uint4(ph[4], ph[5], ph[6], ph[7]);
      if constexpr (SB) {
        *(uint4*)&Bls[br * 32 + bc]     = make_uint4(pl[0], pl[1], pl[2], pl[3]);
        *(uint4*)&Bls[br * 32 + bc + 8] = make_uint4(pl[4], pl[5], pl[6], pl[7]);
      }
    }
    __syncthreads();

    short8 ah[4], al[4], bh[4], bl[4];
#pragma unroll
    for (int i = 0; i < 4; i++) {
      ah[i] = *(const short8*)&Ahs[(wm + i * 16 + fr) * 32 + fo];
      if constexpr (SA) al[i] = *(const short8*)&Als[(wm + i * 16 + fr) * 32 + fo];
    }
#pragma unroll
    for (int j = 0; j < 4; j++) {
      bh[j] = *(const short8*)&Bhs[(wn + j * 16 + fr) * 32 + fo];
      if constexpr (SB) bl[j] = *(const short8*)&Bls[(wn + j * 16 + fr) * 32 + fo];
    }
#pragma unroll
    for (int i = 0; i < 4; i++)
#pragma unroll
      for (int j = 0; j < 4; j++) {
        acc[i][j] = __builtin_amdgcn_mfma_f32_16x16x32_bf16(ah[i], bh[j], acc[i][j], 0, 0, 0);
        if constexpr (SB)
          acc[i][j] = __builtin_amdgcn_mfma_f32_16x16x32_bf16(ah[i], bl[j], acc[i][j], 0, 0, 0);
        if constexpr (SA)
          acc[i][j] = __builtin_amdgcn_mfma_f32_16x16x32_bf16(al[i], bh[j], acc[i][j], 0, 0, 0);
      }
  }

  // epilogue: C/D layout col=lane&15, row=quad*4+reg
#pragma unroll
  for (int i = 0; i < 4; i++)
#pragma unroll
    for (int j = 0; j < 4; j++)
#pragma unroll
      for (int r = 0; r < 4; r++) {
        float v = acc[i][j][r];
        int row = m0 + wm + i * 16 + q * 4 + r;
        int col = n0 + wn + j * 16 + fr;
        if constexpr (EPI == 0) {
          Co[bz * sC + (long long)row * Ncol + col] = v;
        } else if constexpr (EPI == 1) {
          long long idx = bz * sC + (long long)row * Ncol + col;
          ushort_t h = f2bf(v);
          Toh[idx] = h;
          Tol[idx] = f2bf(v - bf2f(h));
        } else if constexpr (EPI == 3) {
          int rr = kmap[bz * MPAD + row];
          int cc = kmap[bz * MPAD + col];
          if (rr >= 0 && cc >= 0)
            Co[bz * sC + (long long)rr * NN + cc] = floorf(v * 10000.f) / 10000.f;
        } else if constexpr (EPI == 4) {
          int rr = kmap[bz * MPAD + row];
          if (rr >= 0)
            Co[bz * sC + (long long)rr * Ncol + col] = v;
        }
      }
}

// ---------- y = dgcn[row] * xw ----------
__global__ void scaley_k(const float* __restrict__ xw, const float* __restrict__ dgcn,
                         float* __restrict__ y, int shift) {
  long long i = (long long)blockIdx.x * 256 + threadIdx.x;
  int rowi = (int)(i >> shift);
  y[i] = dgcn[rowi] * xw[i];
}

__global__ void epi_k(const float* __restrict__ acc, const float* __restrict__ y,
                      const float* __restrict__ dgcn, const float* __restrict__ diag,
                      const float* __restrict__ bias, const float* __restrict__ mask,
                      float* __restrict__ outx, int shift, int relu) {
  long long i = (long long)blockIdx.x * 256 + threadIdx.x;
  int rowi = (int)(i >> shift);
  int f = (int)(i & ((1 << shift) - 1));
  float t = dgcn[rowi] * (acc[i] + (1.f - diag[rowi]) * y[i]) + bias[f];
  t *= mask[rowi];
  if (relu) t = fmaxf(t, 0.f);
  outx[i] = t;
}

__global__ void mean_k(const float* __restrict__ X, float* __restrict__ out, int Fdim, int outoff) {
  int b = blockIdx.x, f = threadIdx.x;
  const float* p = X + (long long)b * NN * Fdim + f;
  float s = 0.f;
  for (int n = 0; n < NN; n++) s += p[(long long)n * Fdim];
  out[b * (HH + FF) + outoff + f] = s * (1.f / NN);
}

// ---------- fp32 VALU GEMM (small matmuls + final GCN) ----------
template<int TRANSA>
__global__ __launch_bounds__(256) void gemm_k(const float* __restrict__ A, const float* __restrict__ B,
                                              float* __restrict__ C, int M, int Nw, int Kk,
                                              long long sA, long long sB, long long sC) {
  __shared__ float As[16][128];
  __shared__ float Bs[16][128];
  int tid = threadIdx.x;
  int n0 = blockIdx.x * 128, m0 = blockIdx.y * 128;
  const float* Ab = A + (long long)blockIdx.z * sA;
  const float* Bb = B + (long long)blockIdx.z * sB;
  float* Cb = C + (long long)blockIdx.z * sC;
  float acc[8][8];
#pragma unroll
  for (int i = 0; i < 8; i++)
#pragma unroll
    for (int j = 0; j < 8; j++) acc[i][j] = 0.f;
  int tx = tid & 15, ty = tid >> 4;

  for (int k0 = 0; k0 < Kk; k0 += 16) {
    {
      int r = tid >> 2, c = (tid & 3) << 2;
#pragma unroll
      for (int rr = 0; rr < 2; rr++) {
        int rrow = r + rr * 64;
        float4 v = *(const float4*)(Ab + (long long)(m0 + rrow) * Kk + k0 + c);
        As[c + 0][rrow] = v.x; As[c + 1][rrow] = v.y;
        As[c + 2][rrow] = v.z; As[c + 3][rrow] = v.w;
      }
    }
    {
      int kk = tid >> 5, cc = (tid & 31) << 2;
#pragma unroll
      for (int k2 = 0; k2 < 2; k2++) {
        float4 v = *(const float4*)(Bb + (long long)(k0 + kk + k2 * 8) * Nw + n0 + cc);
        *(float4*)&Bs[kk + k2 * 8][cc] = v;
      }
    }
    __syncthreads();
#pragma unroll
    for (int kk = 0; kk < 16; kk++) {
      float a[8], bb[8];
      *(float4*)&a[0]  = *(float4*)&As[kk][ty * 8];
      *(float4*)&a[4]  = *(float4*)&As[kk][ty * 8 + 4];
      *(float4*)&bb[0] = *(float4*)&Bs[kk][tx * 8];
      *(float4*)&bb[4] = *(float4*)&Bs[kk][tx * 8 + 4];
#pragma unroll
      for (int i = 0; i < 8; i++)
#pragma unroll
        for (int j = 0; j < 8; j++) acc[i][j] += a[i] * bb[j];
    }
    __syncthreads();
  }
#pragma unroll
  for (int i = 0; i < 8; i++) {
    float* cp = Cb + (long long)(m0 + ty * 8 + i) * Nw + n0 + tx * 8;
    *(float4*)cp = *(float4*)&acc[i][0];
    *(float4*)(cp + 4) = *(float4*)&acc[i][4];
  }
}

static inline void launch_gemm(const float* A, const float* B, float* C, int M, int Nw, int Kk,
                               long long sA, long long sB, long long sC, int batch, hipStream_t st) {
  dim3 g(Nw / 128, M / 128, batch), blk(256);
  gemm_k<0><<<g, blk, 0, st>>>(A, B, C, M, Nw, Kk, sA, sB, sC);
}

extern "C" void kernel_launch(void* const* d_in, const int* in_sizes, int n_in,
                              void* d_out, int out_size, void* d_ws, size_t ws_size,
                              hipStream_t stream) {
  const float* x    = (const float*)d_in[0];
  float*       adj  = (float*)d_in[1];   // overwritten with A2 (harness restores inputs)
  const float* mask = (const float*)d_in[2];
  const float* W1   = (const float*)d_in[3];
  const float* b1   = (const float*)d_in[4];
  const float* Watt = (const float*)d_in[5];
  const float* batt = (const float*)d_in[6];
  const float* W2   = (const float*)d_in[7];
  const float* b2   = (const float*)d_in[8];
  float* out = (float*)d_out;

  const long long NN2 = (long long)NN * NN;
  const long long BIG = (long long)NB * NN2;
  const long long CSTR = (long long)MPAD * NN;        // compact stride per batch
  const long long CTOT = (long long)NB * CSTR;

  // ---- workspace (~236 MB) ----
  float* ws = (float*)d_ws;
  long long off = 0;
  ushort_t* AdjH = (ushort_t*)(ws + off); off += BIG / 2;   // 67.1 MB
  ushort_t* StcH = (ushort_t*)(ws + off); off += CTOT / 2;  // 37.7 MB
  ushort_t* StcL = (ushort_t*)(ws + off); off += CTOT / 2;
  float* TcF = ws + off; off += CTOT;                       // 75.5 MB union region
  ushort_t* TcH = (ushort_t*)TcF;
  ushort_t* TcL = TcH + CTOT;
  float* xa   = ws + off; off += (long long)NROWS * HH;
  float* xb   = ws + off; off += (long long)NROWS * HH;
  float* rowsum = ws + off; off += NROWS;
  float* diag   = ws + off; off += NROWS;
  float* dgcn   = ws + off; off += NROWS;
  float* dnorm  = ws + off; off += NROWS;
  float* rz     = ws + off; off += NROWS;
  float* wv     = ws + off; off += NROWS;
  float* alphav = ws + off; off += NROWS;
  float* colwv  = ws + off; off += NROWS;
  float* scalev = ws + off; off += NROWS;
  float* cutv   = ws + off; off += NB;
  int* keepidx  = (int*)(ws + off); off += NB * MPAD / 1 / 1;  // ints fit in float slots
  int* cntv     = (int*)(ws + off); off += NB;

  // phase-local aliases inside TcF (dead when Tc is live and vice versa)
  float* u1 = TcF;                                   // up to 16384x256 fp32
  float* u2 = u1 + (long long)NROWS * FF;
  ushort_t* y1Th = (ushort_t*)(u2 + (long long)NROWS * FF);
  ushort_t* y1Tl = y1Th + (long long)NB * HH * NN;
  ushort_t* xTh = TcH;                               // used only after G2, before next G1
  ushort_t* xTl = xTh + (long long)NB * HH * NN;

  // ================= GCN1 =================
  rowstats_k<<<NROWS / 4, 256, 0, stream>>>(adj, rowsum, diag);
  derive_k<<<NROWS / 256, 256, 0, stream>>>(rowsum, diag, dgcn, dnorm, rz);
  cvtadjh_k<<<(int)(BIG / 4 / 256), 256, 0, stream>>>(adj, AdjH);   // binary adj: exact bf16
  launch_gemm(x, W1, u1, NROWS, HH, FF, 0, 0, 0, 1, stream);        // xw1
  scaley_k<<<(NROWS * HH) / 256, 256, 0, stream>>>(u1, dgcn, u2, 7);
  cvt_xT_k<<<dim3(NN / 32, HH / 32, NB), 256, 0, stream>>>(u2, y1Th, y1Tl);
  // acc1 = adj @ y1 via MFMA (A = AdjH exact, B = y1T split) -> u1
  mgemm_k<0, 1, 0, 0><<<dim3(1, NN / 128, NB), 256, 0, stream>>>(
      AdjH, AdjH, y1Th, y1Tl, 0, u1, 0, 0,
      NN, HH, NN, NN2, (long long)HH * NN, (long long)NN * HH, 0);
  epi_k<<<(NROWS * HH) / 256, 256, 0, stream>>>(u1, u2, dgcn, diag, b1, mask, xa, 7, 1);
  mean_k<<<NB, HH, 0, stream>>>(xa, out, HH, 0);

  // ================= 2 coarsen layers =================
  float* curx = xa;
  float* nxtx = xb;
  for (int layer = 0; layer < 2; layer++) {
    if (layer > 0) {
      rowstats_k<<<NROWS / 4, 256, 0, stream>>>(adj, rowsum, diag);
      derive_k<<<NROWS / 256, 256, 0, stream>>>(rowsum, diag, dgcn, dnorm, rz);
    }
    wvec_k<<<NROWS / 4, 256, 0, stream>>>(curx, Watt, batt, dnorm, wv);
    alpha_k<<<NROWS / 4, 256, 0, stream>>>(adj, wv, dnorm, rz, alphav);
    topcut_k<<<NB, 1024, 0, stream>>>(alphav, cutv);
    colw_k<<<NROWS / 256, 256, 0, stream>>>(alphav, cutv, dnorm, colwv);
    scale_k<<<NROWS / 4, 256, 0, stream>>>(adj, colwv, dnorm, rz, scalev);
    keep_k<<<NB, 1024, 0, stream>>>(colwv, rz, keepidx, cntv);
    writeStc_k<<<(int)(CTOT / 4 / 256), 256, 0, stream>>>(adj, scalev, colwv, keepidx, StcH, StcL);

    // G1: tmpTc[j][k] = sum_i Stc[j][i] * adj[i][k]  (adj symmetric -> B row k = adj row k)
    if (layer == 0)
      mgemm_k<1, 0, 0, 1><<<dim3(NN / 128, MPAD / 128, NB), 256, 0, stream>>>(
          StcH, StcL, AdjH, 0, 0, 0, TcH, TcL,
          MPAD, NN, NN, CSTR, NN2, CSTR, 0);
    else
      mgemm_k<1, 1, 1, 1><<<dim3(NN / 128, MPAD / 128, NB), 256, 0, stream>>>(
          StcH, StcL, 0, 0, adj, 0, TcH, TcL,
          MPAD, NN, NN, CSTR, NN2, CSTR, 0);

    // G2: A2c[i][j] = sum_n Stc[i][n]*Tc[j][n] -> scatter-quant into zeroed adj
    hipMemsetAsync(adj, 0, BIG * sizeof(float), stream);
    mgemm_k<1, 1, 0, 3><<<dim3(MPAD / 128, MPAD / 128, NB), 256, 0, stream>>>(
        StcH, StcL, TcH, TcL, 0, adj, 0, 0,
        MPAD, MPAD, NN, CSTR, CSTR, NN2, keepidx);

    // G3: x2c[i][f] = sum_n Stc[i][n]*x[n][f] -> row-scatter into zeroed nxtx
    hipMemsetAsync(nxtx, 0, (long long)NROWS * HH * sizeof(float), stream);
    cvt_xT_k<<<dim3(NN / 32, HH / 32, NB), 256, 0, stream>>>(curx, xTh, xTl);
    mgemm_k<1, 1, 0, 4><<<dim3(1, MPAD / 128, NB), 256, 0, stream>>>(
        StcH, StcL, xTh, xTl, 0, nxtx, 0, 0,
        MPAD, HH, NN, CSTR, (long long)HH * NN, (long long)NN * HH, keepidx);
    float* t = curx; curx = nxtx; nxtx = t;
  }

  // ================= final GCN =================
  rowstats_k<<<NROWS / 4, 256, 0, stream>>>(adj, rowsum, diag);
  derive_k<<<NROWS / 256, 256, 0, stream>>>(rowsum, diag, dgcn, dnorm, rz);
  launch_gemm(curx, W2, u1, NROWS, FF, HH, 0, 0, 0, 1, stream);
  scaley_k<<<(NROWS * FF) / 256, 256, 0, stream>>>(u1, dgcn, u2, 8);
  launch_gemm(adj, u2, u1, NN, FF, NN, NN2, (long long)NN * FF, (long long)NN * FF, NB, stream);
  epi_k<<<(NROWS * FF) / 256, 256, 0, stream>>>(u1, u2, dgcn, diag, b2, mask, u1, 8, 0);
  mean_k<<<NB, FF, 0, stream>>>(u1, out, FF, HH);
}

// Round 4
// 1731.107 us; speedup vs baseline: 4.5376x; 1.4273x over previous
//
#include <hip/hip_runtime.h>
#include <math.h>

#define NN 2048
#define NB 8
#define FF 256
#define HH 128
#define KSEL 1025
#define NROWS (NB*NN)
#define MPAD 1152
#define MC (MPAD*NB)

typedef unsigned short ushort_t;
typedef __attribute__((ext_vector_type(8))) short short8;
typedef __attribute__((ext_vector_type(4))) float f32x4;

__device__ inline ushort_t f2bf(float f) {
  unsigned u = __float_as_uint(f);
  unsigned r = (u + 0x7FFFu + ((u >> 16) & 1u)) >> 16;
  return (ushort_t)r;
}
__device__ inline float bf2f(ushort_t u) {
  unsigned x = ((unsigned)u) << 16;
  return __uint_as_float(x);
}

#define GLDS16(g, l) __builtin_amdgcn_global_load_lds( \
    (const __attribute__((address_space(1))) unsigned int*)(g), \
    (__attribute__((address_space(3))) unsigned int*)(l), 16, 0, 0)

// ---------- row stats (float4), one wave per row; R = row length = rows/batch ----------
__global__ __launch_bounds__(256) void rowstats_k(const float* __restrict__ A,
                                                  float* __restrict__ rowsum,
                                                  float* __restrict__ diag, int R) {
  int gw = (blockIdx.x * 256 + threadIdx.x) >> 6;
  int lane = threadIdx.x & 63;
  int b = gw / R, i = gw - b * R;
  const float4* row = (const float4*)(A + (long long)gw * R);
  int R4 = R >> 2;
  float s = 0.f;
  for (int j = lane; j < R4; j += 64) {
    float4 v = row[j];
    s += v.x + v.y + v.z + v.w;
  }
  for (int off = 32; off > 0; off >>= 1) s += __shfl_down(s, off);
  if (lane == 0) { rowsum[gw] = s; diag[gw] = A[(long long)gw * R + i]; }
}

__global__ void derive_k(const float* __restrict__ rowsum, const float* __restrict__ diag,
                         float* __restrict__ dgcn, float* __restrict__ dnorm,
                         float* __restrict__ rz, int n) {
  int i = blockIdx.x * 256 + threadIdx.x;
  if (i >= n) return;
  float rs = rowsum[i], dg = diag[i];
  dgcn[i]  = rsqrtf(fmaxf(rs - dg + 1.f, 1.f));
  dnorm[i] = rsqrtf(fmaxf(rs + 1.f, 1.f));
  rz[i]    = rs > 0.f ? 1.f : 0.f;
}

// ---------- w = dnorm * (x @ Watt + batt), feature dim 128, one wave/row ----------
__global__ __launch_bounds__(256) void wvec_k(const float* __restrict__ x,
                                              const float* __restrict__ Watt,
                                              const float* __restrict__ batt,
                                              const float* __restrict__ dnorm,
                                              float* __restrict__ w) {
  int gw = (blockIdx.x * 256 + threadIdx.x) >> 6;
  int lane = threadIdx.x & 63;
  const float* r = x + (long long)gw * HH;
  float s = r[lane] * Watt[lane] + r[lane + 64] * Watt[lane + 64];
  for (int off = 32; off > 0; off >>= 1) s += __shfl_down(s, off);
  if (lane == 0) w[gw] = dnorm[gw] * (s + batt[0]);
}

// ---------- alpha = sigmoid((rz*dnorm*((A+I)@w))^2); out stride is always NN ----------
__global__ __launch_bounds__(256) void alpha_k(const float* __restrict__ A,
                                               const float* __restrict__ w,
                                               const float* __restrict__ dnorm,
                                               const float* __restrict__ rz,
                                               float* __restrict__ alpha, int R) {
  int gw = (blockIdx.x * 256 + threadIdx.x) >> 6;
  int lane = threadIdx.x & 63;
  int b = gw / R, i = gw - b * R;
  const float4* row = (const float4*)(A + (long long)gw * R);
  const float4* wb4 = (const float4*)(w + (long long)b * R);
  int R4 = R >> 2;
  float s = 0.f;
  for (int j = lane; j < R4; j += 64) {
    float4 a = row[j], ww = wb4[j];
    s += a.x * ww.x + a.y * ww.y + a.z * ww.z + a.w * ww.w;
  }
  for (int off = 32; off > 0; off >>= 1) s += __shfl_down(s, off);
  if (lane == 0) {
    float aa = rz[gw] * dnorm[gw] * (s + w[(long long)b * R + i]);
    aa = aa * aa;
    alpha[(long long)b * NN + i] = 1.f / (1.f + expf(-aa));
  }
}

__global__ void padfill_k(float* __restrict__ alpha) {
  int idx = blockIdx.x * 256 + threadIdx.x;   // (NN-MPAD)*NB entries
  int b = idx / (NN - MPAD), j = idx - b * (NN - MPAD);
  alpha[b * NN + MPAD + j] = 0.5f;
}

// ---------- exact k-th largest via bitonic sort ----------
__global__ __launch_bounds__(1024) void topcut_k(const float* __restrict__ alpha, float* __restrict__ cut) {
  __shared__ float a[NN];
  int b = blockIdx.x, t = threadIdx.x;
  a[t] = alpha[b * NN + t];
  a[t + 1024] = alpha[b * NN + t + 1024];
  __syncthreads();
  for (int k = 2; k <= NN; k <<= 1) {
    for (int j = k >> 1; j > 0; j >>= 1) {
      for (int i = t; i < NN; i += 1024) {
        int ixj = i ^ j;
        if (ixj > i) {
          float x = a[i], y = a[ixj];
          bool up = ((i & k) == 0);
          if ((x > y) == up) { a[i] = y; a[ixj] = x; }
        }
      }
      __syncthreads();
    }
  }
  if (t == 0) cut[b] = a[NN - KSEL];
}

// ---------- L0: colw + keep list (fused) ----------
__global__ __launch_bounds__(1024) void keepcolw_k(const float* __restrict__ alpha,
                                                   const float* __restrict__ cut,
                                                   const float* __restrict__ dnorm,
                                                   const float* __restrict__ rz,
                                                   float* __restrict__ colw,
                                                   int* __restrict__ keepidx, int* __restrict__ cnt) {
  __shared__ int ps[NN];
  int b = blockIdx.x, t = threadIdx.x;
  float cu = cut[b];
  float c0 = dnorm[b * NN + t]        * fmaxf(alpha[b * NN + t]        + 1e-7f - cu, 0.f);
  float c1 = dnorm[b * NN + t + 1024] * fmaxf(alpha[b * NN + t + 1024] + 1e-7f - cu, 0.f);
  colw[b * NN + t] = c0;
  colw[b * NN + t + 1024] = c1;
  int f0 = (c0 != 0.f && rz[b * NN + t]        != 0.f) ? 1 : 0;
  int f1 = (c1 != 0.f && rz[b * NN + t + 1024] != 0.f) ? 1 : 0;
  ps[t] = f0; ps[t + 1024] = f1;
  __syncthreads();
  for (int off = 1; off < NN; off <<= 1) {
    int v0 = (t >= off) ? ps[t - off] : 0;
    int v1 = (t + 1024 >= off) ? ps[t + 1024 - off] : 0;
    __syncthreads();
    ps[t] += v0; ps[t + 1024] += v1;
    __syncthreads();
  }
  if (t < MPAD) keepidx[b * MPAD + t] = -1;
  if (t + 1024 < MPAD) keepidx[b * MPAD + t + 1024] = -1;
  __syncthreads();
  if (f0 && ps[t] - 1 < MPAD) keepidx[b * MPAD + ps[t] - 1] = t;
  if (f1 && ps[t + 1024] - 1 < MPAD) keepidx[b * MPAD + ps[t + 1024] - 1] = t + 1024;
  if (t == 0) cnt[b] = ps[NN - 1];
}

// ---------- L1: colw only (compact layout, alpha at stride NN) ----------
__global__ void colwc_k(const float* __restrict__ alpha, const float* __restrict__ cut,
                        const float* __restrict__ dnorm, float* __restrict__ colw) {
  int i = blockIdx.x * 256 + threadIdx.x;   // MC entries
  int b = i / MPAD, ii = i - b * MPAD;
  float c = fmaxf(alpha[b * NN + ii] + 1e-7f - cut[b], 0.f);
  colw[i] = dnorm[i] * c;
}

// ---------- scale_n = rz*dnorm / max(rowSsum,1e-12) (float4) ----------
__global__ __launch_bounds__(256) void scale_k(const float* __restrict__ A,
                                               const float* __restrict__ colw,
                                               const float* __restrict__ dnorm,
                                               const float* __restrict__ rz,
                                               float* __restrict__ scale, int R) {
  int gw = (blockIdx.x * 256 + threadIdx.x) >> 6;
  int lane = threadIdx.x & 63;
  int b = gw / R, i = gw - b * R;
  const float4* row = (const float4*)(A + (long long)gw * R);
  const float4* cw4 = (const float4*)(colw + (long long)b * R);
  int R4 = R >> 2;
  float s = 0.f;
  for (int j = lane; j < R4; j += 64) {
    float4 a = row[j], c = cw4[j];
    s += a.x * c.x + a.y * c.y + a.z * c.z + a.w * c.w;
  }
  for (int off = 32; off > 0; off >>= 1) s += __shfl_down(s, off);
  if (lane == 0) {
    float rsum = rz[gw] * dnorm[gw] * (s + colw[(long long)b * R + i]);
    scale[gw] = rz[gw] * dnorm[gw] / fmaxf(rsum, 1e-12f);
  }
}

// ---------- L0 compact S^T rows from keep list, split bf16 ----------
__global__ void writeStc_k(const float* __restrict__ adj, const float* __restrict__ scale,
                           const float* __restrict__ colw, const int* __restrict__ keepidx,
                           ushort_t* __restrict__ Sh, ushort_t* __restrict__ Sl) {
  long long g = (long long)blockIdx.x * 256 + threadIdx.x;
  int bi = (int)(g >> 9);
  int n = (int)(g & 511) * 4;
  int b = bi / MPAD;
  long long o = (long long)bi * NN + n;
  int row = keepidx[bi];
  if (row < 0) {
    *(uint2*)&Sh[o] = make_uint2(0, 0);
    *(uint2*)&Sl[o] = make_uint2(0, 0);
    return;
  }
  float cw = colw[b * NN + row];
  float4 sc = *(const float4*)(scale + b * NN + n);
  float4 av = *(const float4*)(adj + ((long long)b * NN + row) * NN + n);
  float v0 = sc.x * (av.x + (float)(n     == row)) * cw;
  float v1 = sc.y * (av.y + (float)(n + 1 == row)) * cw;
  float v2 = sc.z * (av.z + (float)(n + 2 == row)) * cw;
  float v3 = sc.w * (av.w + (float)(n + 3 == row)) * cw;
  ushort_t h0 = f2bf(v0), h1 = f2bf(v1), h2 = f2bf(v2), h3 = f2bf(v3);
  *(uint2*)&Sh[o] = make_uint2((unsigned)h0 | ((unsigned)h1 << 16),
                               (unsigned)h2 | ((unsigned)h3 << 16));
  ushort_t l0 = f2bf(v0 - bf2f(h0)), l1 = f2bf(v1 - bf2f(h1));
  ushort_t l2 = f2bf(v2 - bf2f(h2)), l3 = f2bf(v3 - bf2f(h3));
  *(uint2*)&Sl[o] = make_uint2((unsigned)l0 | ((unsigned)l1 << 16),
                               (unsigned)l2 | ((unsigned)l3 << 16));
}

// ---------- L1 compact S2^T (all-compact, no kmap): S2t[l][k]=scale_k*(A2c[l][k]+d_kl)*colw_l ----------
__global__ void writeS2c_k(const float* __restrict__ A2c, const float* __restrict__ scale,
                           const float* __restrict__ colw,
                           ushort_t* __restrict__ Sh, ushort_t* __restrict__ Sl) {
  int g = blockIdx.x * 256 + threadIdx.x;     // MPAD*MPAD*NB/4 units
  int bl = g / (MPAD / 4);
  int k = (g - bl * (MPAD / 4)) * 4;
  int b = bl / MPAD, l = bl - b * MPAD;
  long long o = (long long)bl * MPAD + k;
  float cw = colw[b * MPAD + l];
  float4 sc = *(const float4*)(scale + b * MPAD + k);
  float4 av = *(const float4*)(A2c + o);
  float v0 = sc.x * (av.x + (float)(k     == l)) * cw;
  float v1 = sc.y * (av.y + (float)(k + 1 == l)) * cw;
  float v2 = sc.z * (av.z + (float)(k + 2 == l)) * cw;
  float v3 = sc.w * (av.w + (float)(k + 3 == l)) * cw;
  ushort_t h0 = f2bf(v0), h1 = f2bf(v1), h2 = f2bf(v2), h3 = f2bf(v3);
  *(uint2*)&Sh[o] = make_uint2((unsigned)h0 | ((unsigned)h1 << 16),
                               (unsigned)h2 | ((unsigned)h3 << 16));
  ushort_t l0 = f2bf(v0 - bf2f(h0)), l1 = f2bf(v1 - bf2f(h1));
  ushort_t l2 = f2bf(v2 - bf2f(h2)), l3 = f2bf(v3 - bf2f(h3));
  *(uint2*)&Sl[o] = make_uint2((unsigned)l0 | ((unsigned)l1 << 16),
                               (unsigned)l2 | ((unsigned)l3 << 16));
}

// ---------- transpose + split: T[b][f][n] = X[b][n][f]; params Nn, Fd ----------
__global__ __launch_bounds__(256) void cvt_xT_k(const float* __restrict__ X,
                                                ushort_t* __restrict__ Th, ushort_t* __restrict__ Tl,
                                                int Nn, int Fd) {
  __shared__ float t[32][33];
  int b = blockIdx.z;
  int n0 = blockIdx.x * 32, f0 = blockIdx.y * 32;
  int tx = threadIdx.x & 31, ty = threadIdx.x >> 5;
  const float* Xb = X + ((long long)b * Nn + n0) * Fd + f0;
  for (int r = ty; r < 32; r += 8) t[r][tx] = Xb[(long long)r * Fd + tx];
  __syncthreads();
  for (int r = ty; r < 32; r += 8) {
    float v = t[tx][r];
    ushort_t h = f2bf(v);
    long long idx = ((long long)b * Fd + f0 + r) * Nn + n0 + tx;
    Th[idx] = h;
    Tl[idx] = f2bf(v - bf2f(h));
  }
}

// ============ MFMA split-bf16 GEMM ============
// C[m][n] = sum_k A[m][k]*B[n][k].  Products: Ah*Bh (+Ah*Bl if SB) (+Al*Bh if SA).
// ACVT: stage A from fp32 (hi only).  BCVT: stage B from fp32 (hi + lo if SB).
// EPI: 0 fp32 dense; 1 split-bf16 dense; 5 fp32 floor-quant dense + splits of quant.
template<int SA, int SB, int ACVT, int BCVT, int EPI>
__global__ __launch_bounds__(256) void mgemm_k(
    const ushort_t* __restrict__ Ah, const ushort_t* __restrict__ Al,
    const float* __restrict__ Af,
    const ushort_t* __restrict__ Bh, const ushort_t* __restrict__ Bl,
    const float* __restrict__ Bf,
    float* __restrict__ Co, ushort_t* __restrict__ Toh, ushort_t* __restrict__ Tol,
    int M, int Ncol, int K, long long sA, long long sB, long long sC) {
  __shared__ ushort_t Ahs[128 * 32];
  __shared__ ushort_t Bhs[128 * 32];
  __shared__ ushort_t Als[SA ? 128 * 32 : 64];
  __shared__ ushort_t Bls[SB ? 128 * 32 : 64];

  int tid = threadIdx.x;
  int n0 = blockIdx.x * 128, m0 = blockIdx.y * 128;
  long long bz = blockIdx.z;
  const ushort_t* Ahb = (!ACVT) ? (Ah + bz * sA) : (const ushort_t*)0;
  const ushort_t* Alb = (!ACVT && SA) ? (Al + bz * sA) : (const ushort_t*)0;
  const float*    Afb = ACVT ? (Af + bz * sA) : (const float*)0;
  const ushort_t* Bhb = (!BCVT) ? (Bh + bz * sB) : (const ushort_t*)0;
  const ushort_t* Blb = (!BCVT && SB) ? (Bl + bz * sB) : (const ushort_t*)0;
  const float*    Bfb = BCVT ? (Bf + bz * sB) : (const float*)0;

  int sr = tid >> 2;
  int sc = (tid & 3) * 8;
  int br = tid >> 1, bc = (tid & 1) * 16;
  int lane = tid & 63, w = tid >> 6;
  int wm = (w >> 1) * 64, wn = (w & 1) * 64;
  int fr = lane & 15;
  int fo = (lane >> 4) * 8;
  int q = lane >> 4;

  f32x4 acc[4][4];
  f32x4 zz = {0.f, 0.f, 0.f, 0.f};
#pragma unroll
  for (int i = 0; i < 4; i++)
#pragma unroll
    for (int j = 0; j < 4; j++) acc[i][j] = zz;

  for (int k0 = 0; k0 < K; k0 += 32) {
    __syncthreads();
    if constexpr (!ACVT) {
#pragma unroll
      for (int r = 0; r < 128; r += 64) {
        GLDS16(Ahb + (long long)(m0 + sr + r) * K + k0 + sc, &Ahs[(r + sr) * 32 + sc]);
        if constexpr (SA) {
          GLDS16(Alb + (long long)(m0 + sr + r) * K + k0 + sc, &Als[(r + sr) * 32 + sc]);
        }
      }
    } else {
      const float* g = Afb + (long long)(m0 + br) * K + k0 + bc;
      float vv[16];
      *(float4*)&vv[0]  = *(const float4*)(g);
      *(float4*)&vv[4]  = *(const float4*)(g + 4);
      *(float4*)&vv[8]  = *(const float4*)(g + 8);
      *(float4*)&vv[12] = *(const float4*)(g + 12);
      unsigned ph[8];
#pragma unroll
      for (int t = 0; t < 8; t++) {
        ushort_t h0 = f2bf(vv[2 * t]), h1 = f2bf(vv[2 * t + 1]);
        ph[t] = (unsigned)h0 | ((unsigned)h1 << 16);
      }
      *(uint4*)&Ahs[br * 32 + bc]     = make_uint4(ph[0], ph[1], ph[2], ph[3]);
      *(uint4*)&Ahs[br * 32 + bc + 8] = make_uint4(ph[4], ph[5], ph[6], ph[7]);
    }
    if constexpr (!BCVT) {
#pragma unroll
      for (int r = 0; r < 128; r += 64) {
        GLDS16(Bhb + (long long)(n0 + sr + r) * K + k0 + sc, &Bhs[(r + sr) * 32 + sc]);
        if constexpr (SB) {
          GLDS16(Blb + (long long)(n0 + sr + r) * K + k0 + sc, &Bls[(r + sr) * 32 + sc]);
        }
      }
    } else {
      const float* g = Bfb + (long long)(n0 + br) * K + k0 + bc;
      float vv[16];
      *(float4*)&vv[0]  = *(const float4*)(g);
      *(float4*)&vv[4]  = *(const float4*)(g + 4);
      *(float4*)&vv[8]  = *(const float4*)(g + 8);
      *(float4*)&vv[12] = *(const float4*)(g + 12);
      unsigned ph[8], pl[8];
#pragma unroll
      for (int t = 0; t < 8; t++) {
        ushort_t h0 = f2bf(vv[2 * t]), h1 = f2bf(vv[2 * t + 1]);
        ph[t] = (unsigned)h0 | ((unsigned)h1 << 16);
        if constexpr (SB) {
          ushort_t l0 = f2bf(vv[2 * t] - bf2f(h0)), l1 = f2bf(vv[2 * t + 1] - bf2f(h1));
          pl[t] = (unsigned)l0 | ((unsigned)l1 << 16);
        }
      }
      *(uint4*)&Bhs[br * 32 + bc]     = make_uint4(ph[0], ph[1], ph[2], ph[3]);
      *(uint4*)&Bhs[br * 32 + bc + 8] = make_uint4(ph[4], ph[5], ph[6], ph[7]);
      if constexpr (SB) {
        *(uint4*)&Bls[br * 32 + bc]     = make_uint4(pl[0], pl[1], pl[2], pl[3]);
        *(uint4*)&Bls[br * 32 + bc + 8] = make_uint4(pl[4], pl[5], pl[6], pl[7]);
      }
    }
    __syncthreads();

    short8 ah[4], al[4], bh[4], bl[4];
#pragma unroll
    for (int i = 0; i < 4; i++) {
      ah[i] = *(const short8*)&Ahs[(wm + i * 16 + fr) * 32 + fo];
      if constexpr (SA) al[i] = *(const short8*)&Als[(wm + i * 16 + fr) * 32 + fo];
    }
#pragma unroll
    for (int j = 0; j < 4; j++) {
      bh[j] = *(const short8*)&Bhs[(wn + j * 16 + fr) * 32 + fo];
      if constexpr (SB) bl[j] = *(const short8*)&Bls[(wn + j * 16 + fr) * 32 + fo];
    }
#pragma unroll
    for (int i = 0; i < 4; i++)
#pragma unroll
      for (int j = 0; j < 4; j++) {
        acc[i][j] = __builtin_amdgcn_mfma_f32_16x16x32_bf16(ah[i], bh[j], acc[i][j], 0, 0, 0);
        if constexpr (SB)
          acc[i][j] = __builtin_amdgcn_mfma_f32_16x16x32_bf16(ah[i], bl[j], acc[i][j], 0, 0, 0);
        if constexpr (SA)
          acc[i][j] = __builtin_amdgcn_mfma_f32_16x16x32_bf16(al[i], bh[j], acc[i][j], 0, 0, 0);
      }
  }

  // epilogue: C/D layout col=lane&15, row=quad*4+reg
#pragma unroll
  for (int i = 0; i < 4; i++)
#pragma unroll
    for (int j = 0; j < 4; j++)
#pragma unroll
      for (int r = 0; r < 4; r++) {
        float v = acc[i][j][r];
        int row = m0 + wm + i * 16 + q * 4 + r;
        int col = n0 + wn + j * 16 + fr;
        long long idx = bz * sC + (long long)row * Ncol + col;
        if constexpr (EPI == 0) {
          Co[idx] = v;
        } else if constexpr (EPI == 1) {
          ushort_t h = f2bf(v);
          Toh[idx] = h;
          Tol[idx] = f2bf(v - bf2f(h));
        } else {  // EPI == 5
          float vq = floorf(v * 10000.f) / 10000.f;
          Co[idx] = vq;
          ushort_t h = f2bf(vq);
          Toh[idx] = h;
          Tol[idx] = f2bf(vq - bf2f(h));
        }
      }
}

// ---------- y = dgcn[row] * xw ----------
__global__ void scaley_k(const float* __restrict__ xw, const float* __restrict__ dgcn,
                         float* __restrict__ y, int shift) {
  long long i = (long long)blockIdx.x * 256 + threadIdx.x;
  int rowi = (int)(i >> shift);
  y[i] = dgcn[rowi] * xw[i];
}

// ---------- GCN1 epilogue (full space, relu, mask) ----------
__global__ void epi_k(const float* __restrict__ acc, const float* __restrict__ y,
                      const float* __restrict__ dgcn, const float* __restrict__ diag,
                      const float* __restrict__ bias, const float* __restrict__ mask,
                      float* __restrict__ outx) {
  long long i = (long long)blockIdx.x * 256 + threadIdx.x;
  int rowi = (int)(i >> 7);
  int f = (int)(i & 127);
  float t = dgcn[rowi] * (acc[i] + (1.f - diag[rowi]) * y[i]) + bias[f];
  t *= mask[rowi];
  outx[i] = fmaxf(t, 0.f);
}

// ---------- final epilogue (compact, mask via kmap, no relu), in place ----------
__global__ void epic_k(float* __restrict__ acc, const float* __restrict__ y,
                       const float* __restrict__ dgcn, const float* __restrict__ diag,
                       const float* __restrict__ bias, const float* __restrict__ mask,
                       const int* __restrict__ kmap) {
  long long i = (long long)blockIdx.x * 256 + threadIdx.x;
  int rowi = (int)(i >> 8);
  int f = (int)(i & 255);
  int b = rowi / MPAD;
  int km = kmap[rowi];
  float mv = (km >= 0) ? mask[b * NN + km] : 1.f;
  float t = dgcn[rowi] * (acc[i] + (1.f - diag[rowi]) * y[i]) + bias[f];
  acc[i] = t * mv;
}

// ---------- means ----------
__global__ void mean_k(const float* __restrict__ X, float* __restrict__ out) {
  int b = blockIdx.x, f = threadIdx.x;   // HH threads
  const float* p = X + (long long)b * NN * HH + f;
  float s = 0.f;
  for (int n = 0; n < NN; n++) s += p[(long long)n * HH];
  out[b * (HH + FF) + f] = s * (1.f / NN);
}

__global__ void meanc_k(const float* __restrict__ X, const float* __restrict__ b2,
                        float* __restrict__ out) {
  int b = blockIdx.x, f = threadIdx.x;   // FF threads
  const float* p = X + (long long)b * MPAD * FF + f;
  float s = 0.f;
  for (int n = 0; n < MPAD; n++) s += p[(long long)n * FF];
  out[b * (HH + FF) + HH + f] = s * (1.f / NN) + ((float)(NN - MPAD) / NN) * b2[f];
}

// ---------- fp32 VALU GEMM (feature matmuls) ----------
__global__ __launch_bounds__(256) void gemm_k(const float* __restrict__ A, const float* __restrict__ B,
                                              float* __restrict__ C, int M, int Nw, int Kk,
                                              long long sA, long long sB, long long sC) {
  __shared__ float As[16][128];
  __shared__ float Bs[16][128];
  int tid = threadIdx.x;
  int n0 = blockIdx.x * 128, m0 = blockIdx.y * 128;
  const float* Ab = A + (long long)blockIdx.z * sA;
  const float* Bb = B + (long long)blockIdx.z * sB;
  float* Cb = C + (long long)blockIdx.z * sC;
  float acc[8][8];
#pragma unroll
  for (int i = 0; i < 8; i++)
#pragma unroll
    for (int j = 0; j < 8; j++) acc[i][j] = 0.f;
  int tx = tid & 15, ty = tid >> 4;

  for (int k0 = 0; k0 < Kk; k0 += 16) {
    {
      int r = tid >> 2, c = (tid & 3) << 2;
#pragma unroll
      for (int rr = 0; rr < 2; rr++) {
        int rrow = r + rr * 64;
        float4 v = *(const float4*)(Ab + (long long)(m0 + rrow) * Kk + k0 + c);
        As[c + 0][rrow] = v.x; As[c + 1][rrow] = v.y;
        As[c + 2][rrow] = v.z; As[c + 3][rrow] = v.w;
      }
    }
    {
      int kk = tid >> 5, cc = (tid & 31) << 2;
#pragma unroll
      for (int k2 = 0; k2 < 2; k2++) {
        float4 v = *(const float4*)(Bb + (long long)(k0 + kk + k2 * 8) * Nw + n0 + cc);
        *(float4*)&Bs[kk + k2 * 8][cc] = v;
      }
    }
    __syncthreads();
#pragma unroll
    for (int kk = 0; kk < 16; kk++) {
      float a[8], bb[8];
      *(float4*)&a[0]  = *(float4*)&As[kk][ty * 8];
      *(float4*)&a[4]  = *(float4*)&As[kk][ty * 8 + 4];
      *(float4*)&bb[0] = *(float4*)&Bs[kk][tx * 8];
      *(float4*)&bb[4] = *(float4*)&Bs[kk][tx * 8 + 4];
#pragma unroll
      for (int i = 0; i < 8; i++)
#pragma unroll
        for (int j = 0; j < 8; j++) acc[i][j] += a[i] * bb[j];
    }
    __syncthreads();
  }
#pragma unroll
  for (int i = 0; i < 8; i++) {
    float* cp = Cb + (long long)(m0 + ty * 8 + i) * Nw + n0 + tx * 8;
    *(float4*)cp = *(float4*)&acc[i][0];
    *(float4*)(cp + 4) = *(float4*)&acc[i][4];
  }
}

extern "C" void kernel_launch(void* const* d_in, const int* in_sizes, int n_in,
                              void* d_out, int out_size, void* d_ws, size_t ws_size,
                              hipStream_t stream) {
  const float* x    = (const float*)d_in[0];
  const float* adj  = (const float*)d_in[1];
  const float* mask = (const float*)d_in[2];
  const float* W1   = (const float*)d_in[3];
  const float* b1   = (const float*)d_in[4];
  const float* Watt = (const float*)d_in[5];
  const float* batt = (const float*)d_in[6];
  const float* W2   = (const float*)d_in[7];
  const float* b2   = (const float*)d_in[8];
  float* out = (float*)d_out;

  const long long NN2  = (long long)NN * NN;
  const long long CSTR = (long long)MPAD * NN;          // S^T stride (per batch)
  const long long CTOT = (long long)NB * CSTR;          // 18,874,368
  const long long M2   = (long long)MPAD * MPAD;        // compact sq stride
  const long long M2T  = (long long)NB * M2;            // 10,616,832

  // ---- workspace (~255 MB) ----
  float* ws = (float*)d_ws;
  long long off = 0;
  ushort_t* StcH = (ushort_t*)(ws + off); off += CTOT / 2;   // L0 S^T hi; later S2c hi
  ushort_t* StcL = (ushort_t*)(ws + off); off += CTOT / 2;   // L0 S^T lo; later S2c lo
  float* TcF  = ws + off; off += CTOT;                       // big multi-phase region
  float* A2cF = ws + off; off += M2T;                        // A2c / A3c fp32
  ushort_t* A2cH = (ushort_t*)(ws + off); off += M2T / 2;    // splits (quantized)
  ushort_t* A2cL = (ushort_t*)(ws + off); off += M2T / 2;
  float* xa   = ws + off; off += (long long)NROWS * HH;      // x1 full
  float* x2c  = ws + off; off += (long long)MC * HH;         // compact coarse x (L1 in)
  float* x3c  = ws + off; off += (long long)MC * HH;         // compact coarse x (final in)
  float* rowsum = ws + off; off += NROWS;
  float* diag   = ws + off; off += NROWS;
  float* dgcn   = ws + off; off += NROWS;
  float* dnorm  = ws + off; off += NROWS;
  float* rz     = ws + off; off += NROWS;
  float* wv     = ws + off; off += NROWS;
  float* alphav = ws + off; off += (long long)NB * NN;
  float* colwv  = ws + off; off += NROWS;
  float* scalev = ws + off; off += NROWS;
  float* cutv   = ws + off; off += NB;
  int* keepidx  = (int*)(ws + off); off += NB * MPAD;
  int* cntv     = (int*)(ws + off); off += NB;

  // phase-local aliases in TcF
  float* u1 = TcF;                                       // GCN1: xw1 (NROWS*HH)
  float* u2 = TcF + (long long)NROWS * HH;
  ushort_t* y1Th = (ushort_t*)(TcF + 2ll * NROWS * HH);
  ushort_t* y1Tl = y1Th + (long long)NROWS * HH;
  ushort_t* TcH = (ushort_t*)TcF;                        // L0 tmp^T splits (CTOT each)
  ushort_t* TcL = TcH + CTOT;
  ushort_t* xT1h = (ushort_t*)TcF;                       // x1^T splits (after L0-G2)
  ushort_t* xT1l = xT1h + (long long)NROWS * HH;
  ushort_t* Tc2H = (ushort_t*)TcF;                       // L1 tmp2^T splits (M2T each)
  ushort_t* Tc2L = Tc2H + M2T;
  ushort_t* x2Th = (ushort_t*)TcF;                       // x2c^T splits (after L1-G2)
  ushort_t* x2Tl = x2Th + (long long)MC * HH;
  float* u1f = TcF;                                      // final: xw2c / acc / out (MC*FF)
  float* u2f = TcF + (long long)MC * FF;
  ushort_t* y2Th = (ushort_t*)(TcF + 2ll * MC * FF);
  ushort_t* y2Tl = y2Th + (long long)MC * FF;

  // ================= GCN1 (full space) =================
  rowstats_k<<<NROWS / 4, 256, 0, stream>>>(adj, rowsum, diag, NN);
  derive_k<<<NROWS / 256, 256, 0, stream>>>(rowsum, diag, dgcn, dnorm, rz, NROWS);
  gemm_k<<<dim3(1, NROWS / 128, 1), 256, 0, stream>>>(x, W1, u1, NROWS, HH, FF, 0, 0, 0);
  scaley_k<<<(NROWS * HH) / 256, 256, 0, stream>>>(u1, dgcn, u2, 7);
  cvt_xT_k<<<dim3(NN / 32, HH / 32, NB), 256, 0, stream>>>(u2, y1Th, y1Tl, NN, HH);
  mgemm_k<0, 1, 1, 0, 0><<<dim3(1, NN / 128, NB), 256, 0, stream>>>(
      0, 0, adj, y1Th, y1Tl, 0, u1, 0, 0,
      NN, HH, NN, NN2, (long long)HH * NN, (long long)NN * HH);
  epi_k<<<(NROWS * HH) / 256, 256, 0, stream>>>(u1, u2, dgcn, diag, b1, mask, xa);
  mean_k<<<NB, HH, 0, stream>>>(xa, out);

  // ================= coarsen layer 0 (full -> compact) =================
  wvec_k<<<NROWS / 4, 256, 0, stream>>>(xa, Watt, batt, dnorm, wv);
  alpha_k<<<NROWS / 4, 256, 0, stream>>>(adj, wv, dnorm, rz, alphav, NN);
  topcut_k<<<NB, 1024, 0, stream>>>(alphav, cutv);
  keepcolw_k<<<NB, 1024, 0, stream>>>(alphav, cutv, dnorm, rz, colwv, keepidx, cntv);
  scale_k<<<NROWS / 4, 256, 0, stream>>>(adj, colwv, dnorm, rz, scalev, NN);
  writeStc_k<<<(int)(CTOT / 4 / 256), 256, 0, stream>>>(adj, scalev, colwv, keepidx, StcH, StcL);
  // G1: tmp^T = S^T @ adj (adj symmetric, BCVT hi-only exact for binary)
  mgemm_k<1, 0, 0, 1, 1><<<dim3(NN / 128, MPAD / 128, NB), 256, 0, stream>>>(
      StcH, StcL, 0, 0, 0, adj, 0, TcH, TcL,
      MPAD, NN, NN, CSTR, NN2, CSTR);
  // G2: A2c = S^T @ tmp (dense compact, quant + splits)
  mgemm_k<1, 1, 0, 0, 5><<<dim3(MPAD / 128, MPAD / 128, NB), 256, 0, stream>>>(
      StcH, StcL, 0, TcH, TcL, 0, A2cF, A2cH, A2cL,
      MPAD, MPAD, NN, CSTR, CSTR, M2);
  // G3: x2c = S^T @ x1 (dense compact)
  cvt_xT_k<<<dim3(NN / 32, HH / 32, NB), 256, 0, stream>>>(xa, xT1h, xT1l, NN, HH);
  mgemm_k<1, 1, 0, 0, 0><<<dim3(1, MPAD / 128, NB), 256, 0, stream>>>(
      StcH, StcL, 0, xT1h, xT1l, 0, x2c, 0, 0,
      MPAD, HH, NN, CSTR, (long long)HH * NN, (long long)MPAD * HH);

  // ================= coarsen layer 1 (all compact) =================
  rowstats_k<<<MC / 4, 256, 0, stream>>>(A2cF, rowsum, diag, MPAD);
  derive_k<<<MC / 256, 256, 0, stream>>>(rowsum, diag, dgcn, dnorm, rz, MC);
  wvec_k<<<MC / 4, 256, 0, stream>>>(x2c, Watt, batt, dnorm, wv);
  alpha_k<<<MC / 4, 256, 0, stream>>>(A2cF, wv, dnorm, rz, alphav, MPAD);
  padfill_k<<<((NN - MPAD) * NB) / 256, 256, 0, stream>>>(alphav);
  topcut_k<<<NB, 1024, 0, stream>>>(alphav, cutv);
  colwc_k<<<MC / 256, 256, 0, stream>>>(alphav, cutv, dnorm, colwv);
  scale_k<<<MC / 4, 256, 0, stream>>>(A2cF, colwv, dnorm, rz, scalev, MPAD);
  writeS2c_k<<<(int)(M2T / 4 / 256), 256, 0, stream>>>(A2cF, scalev, colwv, StcH, StcL);
  // G1': tmp2^T = S2^T @ A2c
  mgemm_k<1, 1, 0, 0, 1><<<dim3(MPAD / 128, MPAD / 128, NB), 256, 0, stream>>>(
      StcH, StcL, 0, A2cH, A2cL, 0, 0, Tc2H, Tc2L,
      MPAD, MPAD, MPAD, M2, M2, M2);
  // G2': A3c = S2^T @ tmp2 (quant + splits), overwrites A2c buffers
  mgemm_k<1, 1, 0, 0, 5><<<dim3(MPAD / 128, MPAD / 128, NB), 256, 0, stream>>>(
      StcH, StcL, 0, Tc2H, Tc2L, 0, A2cF, A2cH, A2cL,
      MPAD, MPAD, MPAD, M2, M2, M2);
  // G3': x3c = S2^T @ x2c
  cvt_xT_k<<<dim3(MPAD / 32, HH / 32, NB), 256, 0, stream>>>(x2c, x2Th, x2Tl, MPAD, HH);
  mgemm_k<1, 1, 0, 0, 0><<<dim3(1, MPAD / 128, NB), 256, 0, stream>>>(
      StcH, StcL, 0, x2Th, x2Tl, 0, x3c, 0, 0,
      MPAD, HH, MPAD, M2, (long long)HH * MPAD, (long long)MPAD * HH);

  // ================= final GCN (compact) =================
  rowstats_k<<<MC / 4, 256, 0, stream>>>(A2cF, rowsum, diag, MPAD);
  derive_k<<<MC / 256, 256, 0, stream>>>(rowsum, diag, dgcn, dnorm, rz, MC);
  gemm_k<<<dim3(FF / 128, MPAD / 128, NB), 256, 0, stream>>>(
      x3c, W2, u1f, MPAD, FF, HH, (long long)MPAD * HH, 0, (long long)MPAD * FF);
  scaley_k<<<(MC * FF) / 256, 256, 0, stream>>>(u1f, dgcn, u2f, 8);
  cvt_xT_k<<<dim3(MPAD / 32, FF / 32, NB), 256, 0, stream>>>(u2f, y2Th, y2Tl, MPAD, FF);
  mgemm_k<1, 1, 0, 0, 0><<<dim3(FF / 128, MPAD / 128, NB), 256, 0, stream>>>(
      A2cH, A2cL, 0, y2Th, y2Tl, 0, u1f, 0, 0,
      MPAD, FF, MPAD, M2, (long long)FF * MPAD, (long long)MPAD * FF);
  epic_k<<<(MC * FF) / 256, 256, 0, stream>>>(u1f, u2f, dgcn, diag, b2, mask, keepidx);
  meanc_k<<<NB, FF, 0, stream>>>(u1f, b2, out);
}

// Round 5
// 1468.098 us; speedup vs baseline: 5.3505x; 1.1791x over previous
//
#include <hip/hip_runtime.h>
#include <math.h>

#define NN 2048
#define NB 8
#define FF 256
#define HH 128
#define KSEL 1025
#define NROWS (NB*NN)
#define MPAD 1152
#define MC (MPAD*NB)

typedef unsigned short ushort_t;
typedef __attribute__((ext_vector_type(8))) short short8;
typedef __attribute__((ext_vector_type(4))) float f32x4;

__device__ inline ushort_t f2bf(float f) {
  unsigned u = __float_as_uint(f);
  unsigned r = (u + 0x7FFFu + ((u >> 16) & 1u)) >> 16;
  return (ushort_t)r;
}
__device__ inline float bf2f(ushort_t u) {
  unsigned x = ((unsigned)u) << 16;
  return __uint_as_float(x);
}

#define GLDS16(g, l) __builtin_amdgcn_global_load_lds( \
    (const __attribute__((address_space(1))) unsigned int*)(g), \
    (__attribute__((address_space(3))) unsigned int*)(l), 16, 0, 0)

// ---------- row stats (float4), one wave per row ----------
__global__ __launch_bounds__(256) void rowstats_k(const float* __restrict__ A,
                                                  float* __restrict__ rowsum,
                                                  float* __restrict__ diag, int R) {
  int gw = (blockIdx.x * 256 + threadIdx.x) >> 6;
  int lane = threadIdx.x & 63;
  int b = gw / R, i = gw - b * R;
  const float4* row = (const float4*)(A + (long long)gw * R);
  int R4 = R >> 2;
  float s = 0.f;
  for (int j = lane; j < R4; j += 64) {
    float4 v = row[j];
    s += v.x + v.y + v.z + v.w;
  }
  for (int off = 32; off > 0; off >>= 1) s += __shfl_down(s, off);
  if (lane == 0) { rowsum[gw] = s; diag[gw] = A[(long long)gw * R + i]; }
}

__global__ void derive_k(const float* __restrict__ rowsum, const float* __restrict__ diag,
                         float* __restrict__ dgcn, float* __restrict__ dnorm,
                         float* __restrict__ rz, int n) {
  int i = blockIdx.x * 256 + threadIdx.x;
  if (i >= n) return;
  float rs = rowsum[i], dg = diag[i];
  dgcn[i]  = rsqrtf(fmaxf(rs - dg + 1.f, 1.f));
  dnorm[i] = rsqrtf(fmaxf(rs + 1.f, 1.f));
  rz[i]    = rs > 0.f ? 1.f : 0.f;
}

__global__ __launch_bounds__(256) void wvec_k(const float* __restrict__ x,
                                              const float* __restrict__ Watt,
                                              const float* __restrict__ batt,
                                              const float* __restrict__ dnorm,
                                              float* __restrict__ w) {
  int gw = (blockIdx.x * 256 + threadIdx.x) >> 6;
  int lane = threadIdx.x & 63;
  const float* r = x + (long long)gw * HH;
  float s = r[lane] * Watt[lane] + r[lane + 64] * Watt[lane + 64];
  for (int off = 32; off > 0; off >>= 1) s += __shfl_down(s, off);
  if (lane == 0) w[gw] = dnorm[gw] * (s + batt[0]);
}

// ---------- alpha = sigmoid((rz*dnorm*((A+I)@w))^2); out stride NN ----------
__global__ __launch_bounds__(256) void alpha_k(const float* __restrict__ A,
                                               const float* __restrict__ w,
                                               const float* __restrict__ dnorm,
                                               const float* __restrict__ rz,
                                               float* __restrict__ alpha, int R) {
  int gw = (blockIdx.x * 256 + threadIdx.x) >> 6;
  int lane = threadIdx.x & 63;
  int b = gw / R, i = gw - b * R;
  const float4* row = (const float4*)(A + (long long)gw * R);
  const float4* wb4 = (const float4*)(w + (long long)b * R);
  int R4 = R >> 2;
  float s = 0.f;
  for (int j = lane; j < R4; j += 64) {
    float4 a = row[j], ww = wb4[j];
    s += a.x * ww.x + a.y * ww.y + a.z * ww.z + a.w * ww.w;
  }
  for (int off = 32; off > 0; off >>= 1) s += __shfl_down(s, off);
  if (lane == 0) {
    float aa = rz[gw] * dnorm[gw] * (s + w[(long long)b * R + i]);
    aa = aa * aa;
    alpha[(long long)b * NN + i] = 1.f / (1.f + expf(-aa));
  }
}

__global__ void padfill_k(float* __restrict__ alpha) {
  int idx = blockIdx.x * 256 + threadIdx.x;
  int b = idx / (NN - MPAD), j = idx - b * (NN - MPAD);
  alpha[b * NN + MPAD + j] = 0.5f;
}

// ---------- exact k-th largest via bitonic sort ----------
__global__ __launch_bounds__(1024) void topcut_k(const float* __restrict__ alpha, float* __restrict__ cut) {
  __shared__ float a[NN];
  int b = blockIdx.x, t = threadIdx.x;
  a[t] = alpha[b * NN + t];
  a[t + 1024] = alpha[b * NN + t + 1024];
  __syncthreads();
  for (int k = 2; k <= NN; k <<= 1) {
    for (int j = k >> 1; j > 0; j >>= 1) {
      for (int i = t; i < NN; i += 1024) {
        int ixj = i ^ j;
        if (ixj > i) {
          float x = a[i], y = a[ixj];
          bool up = ((i & k) == 0);
          if ((x > y) == up) { a[i] = y; a[ixj] = x; }
        }
      }
      __syncthreads();
    }
  }
  if (t == 0) cut[b] = a[NN - KSEL];
}

// ---------- L0: colw + keep list (fused) ----------
__global__ __launch_bounds__(1024) void keepcolw_k(const float* __restrict__ alpha,
                                                   const float* __restrict__ cut,
                                                   const float* __restrict__ dnorm,
                                                   const float* __restrict__ rz,
                                                   float* __restrict__ colw,
                                                   int* __restrict__ keepidx, int* __restrict__ cnt) {
  __shared__ int ps[NN];
  int b = blockIdx.x, t = threadIdx.x;
  float cu = cut[b];
  float c0 = dnorm[b * NN + t]        * fmaxf(alpha[b * NN + t]        + 1e-7f - cu, 0.f);
  float c1 = dnorm[b * NN + t + 1024] * fmaxf(alpha[b * NN + t + 1024] + 1e-7f - cu, 0.f);
  colw[b * NN + t] = c0;
  colw[b * NN + t + 1024] = c1;
  int f0 = (c0 != 0.f && rz[b * NN + t]        != 0.f) ? 1 : 0;
  int f1 = (c1 != 0.f && rz[b * NN + t + 1024] != 0.f) ? 1 : 0;
  ps[t] = f0; ps[t + 1024] = f1;
  __syncthreads();
  for (int off = 1; off < NN; off <<= 1) {
    int v0 = (t >= off) ? ps[t - off] : 0;
    int v1 = (t + 1024 >= off) ? ps[t + 1024 - off] : 0;
    __syncthreads();
    ps[t] += v0; ps[t + 1024] += v1;
    __syncthreads();
  }
  if (t < MPAD) keepidx[b * MPAD + t] = -1;
  if (t + 1024 < MPAD) keepidx[b * MPAD + t + 1024] = -1;
  __syncthreads();
  if (f0 && ps[t] - 1 < MPAD) keepidx[b * MPAD + ps[t] - 1] = t;
  if (f1 && ps[t + 1024] - 1 < MPAD) keepidx[b * MPAD + ps[t + 1024] - 1] = t + 1024;
  if (t == 0) cnt[b] = ps[NN - 1];
}

// ---------- L1: colw only ----------
__global__ void colwc_k(const float* __restrict__ alpha, const float* __restrict__ cut,
                        const float* __restrict__ dnorm, float* __restrict__ colw) {
  int i = blockIdx.x * 256 + threadIdx.x;
  int b = i / MPAD, ii = i - b * MPAD;
  float c = fmaxf(alpha[b * NN + ii] + 1e-7f - cut[b], 0.f);
  colw[i] = dnorm[i] * c;
}

// ---------- scale_n ----------
__global__ __launch_bounds__(256) void scale_k(const float* __restrict__ A,
                                               const float* __restrict__ colw,
                                               const float* __restrict__ dnorm,
                                               const float* __restrict__ rz,
                                               float* __restrict__ scale, int R) {
  int gw = (blockIdx.x * 256 + threadIdx.x) >> 6;
  int lane = threadIdx.x & 63;
  int b = gw / R, i = gw - b * R;
  const float4* row = (const float4*)(A + (long long)gw * R);
  const float4* cw4 = (const float4*)(colw + (long long)b * R);
  int R4 = R >> 2;
  float s = 0.f;
  for (int j = lane; j < R4; j += 64) {
    float4 a = row[j], c = cw4[j];
    s += a.x * c.x + a.y * c.y + a.z * c.z + a.w * c.w;
  }
  for (int off = 32; off > 0; off >>= 1) s += __shfl_down(s, off);
  if (lane == 0) {
    float rsum = rz[gw] * dnorm[gw] * (s + colw[(long long)b * R + i]);
    scale[gw] = rz[gw] * dnorm[gw] / fmaxf(rsum, 1e-12f);
  }
}

// ---------- L0 compact S^T rows, split bf16 ----------
__global__ void writeStc_k(const float* __restrict__ adj, const float* __restrict__ scale,
                           const float* __restrict__ colw, const int* __restrict__ keepidx,
                           ushort_t* __restrict__ Sh, ushort_t* __restrict__ Sl) {
  long long g = (long long)blockIdx.x * 256 + threadIdx.x;
  int bi = (int)(g >> 9);
  int n = (int)(g & 511) * 4;
  int b = bi / MPAD;
  long long o = (long long)bi * NN + n;
  int row = keepidx[bi];
  if (row < 0) {
    *(uint2*)&Sh[o] = make_uint2(0, 0);
    *(uint2*)&Sl[o] = make_uint2(0, 0);
    return;
  }
  float cw = colw[b * NN + row];
  float4 sc = *(const float4*)(scale + b * NN + n);
  float4 av = *(const float4*)(adj + ((long long)b * NN + row) * NN + n);
  float v0 = sc.x * (av.x + (float)(n     == row)) * cw;
  float v1 = sc.y * (av.y + (float)(n + 1 == row)) * cw;
  float v2 = sc.z * (av.z + (float)(n + 2 == row)) * cw;
  float v3 = sc.w * (av.w + (float)(n + 3 == row)) * cw;
  ushort_t h0 = f2bf(v0), h1 = f2bf(v1), h2 = f2bf(v2), h3 = f2bf(v3);
  *(uint2*)&Sh[o] = make_uint2((unsigned)h0 | ((unsigned)h1 << 16),
                               (unsigned)h2 | ((unsigned)h3 << 16));
  ushort_t l0 = f2bf(v0 - bf2f(h0)), l1 = f2bf(v1 - bf2f(h1));
  ushort_t l2 = f2bf(v2 - bf2f(h2)), l3 = f2bf(v3 - bf2f(h3));
  *(uint2*)&Sl[o] = make_uint2((unsigned)l0 | ((unsigned)l1 << 16),
                               (unsigned)l2 | ((unsigned)l3 << 16));
}

// ---------- L1 compact S2^T ----------
__global__ void writeS2c_k(const float* __restrict__ A2c, const float* __restrict__ scale,
                           const float* __restrict__ colw,
                           ushort_t* __restrict__ Sh, ushort_t* __restrict__ Sl) {
  int g = blockIdx.x * 256 + threadIdx.x;
  int bl = g / (MPAD / 4);
  int k = (g - bl * (MPAD / 4)) * 4;
  int b = bl / MPAD, l = bl - b * MPAD;
  long long o = (long long)bl * MPAD + k;
  float cw = colw[b * MPAD + l];
  float4 sc = *(const float4*)(scale + b * MPAD + k);
  float4 av = *(const float4*)(A2c + o);
  float v0 = sc.x * (av.x + (float)(k     == l)) * cw;
  float v1 = sc.y * (av.y + (float)(k + 1 == l)) * cw;
  float v2 = sc.z * (av.z + (float)(k + 2 == l)) * cw;
  float v3 = sc.w * (av.w + (float)(k + 3 == l)) * cw;
  ushort_t h0 = f2bf(v0), h1 = f2bf(v1), h2 = f2bf(v2), h3 = f2bf(v3);
  *(uint2*)&Sh[o] = make_uint2((unsigned)h0 | ((unsigned)h1 << 16),
                               (unsigned)h2 | ((unsigned)h3 << 16));
  ushort_t l0 = f2bf(v0 - bf2f(h0)), l1 = f2bf(v1 - bf2f(h1));
  ushort_t l2 = f2bf(v2 - bf2f(h2)), l3 = f2bf(v3 - bf2f(h3));
  *(uint2*)&Sl[o] = make_uint2((unsigned)l0 | ((unsigned)l1 << 16),
                               (unsigned)l2 | ((unsigned)l3 << 16));
}

// ---------- transpose + split, optional per-row scale: T[b][f][n] = s(n)*X[b][n][f] ----------
__global__ __launch_bounds__(256) void cvt_xT_k(const float* __restrict__ X,
                                                const float* __restrict__ rsc,
                                                ushort_t* __restrict__ Th, ushort_t* __restrict__ Tl,
                                                int Nn, int Fd) {
  __shared__ float t[32][33];
  int b = blockIdx.z;
  int n0 = blockIdx.x * 32, f0 = blockIdx.y * 32;
  int tx = threadIdx.x & 31, ty = threadIdx.x >> 5;
  const float* Xb = X + ((long long)b * Nn + n0) * Fd + f0;
  for (int r = ty; r < 32; r += 8) {
    float sc = rsc ? rsc[(long long)b * Nn + n0 + r] : 1.f;
    t[r][tx] = sc * Xb[(long long)r * Fd + tx];
  }
  __syncthreads();
  for (int r = ty; r < 32; r += 8) {
    float v = t[tx][r];
    ushort_t h = f2bf(v);
    long long idx = ((long long)b * Fd + f0 + r) * Nn + n0 + tx;
    Th[idx] = h;
    Tl[idx] = f2bf(v - bf2f(h));
  }
}

// ============ MFMA split-bf16 GEMM, batch->XCD swizzled ============
// grid = gx*gy*NB linear; batch = id&7 pins batch b to XCD b (round-robin heuristic).
// C[m][n] = sum_k A[m][k]*B[n][k].  Products: Ah*Bh (+Ah*Bl if SB) (+Al*Bh if SA).
template<int SA, int SB, int ACVT, int BCVT, int EPI>
__global__ __launch_bounds__(256) void mgemm_k(
    const ushort_t* __restrict__ Ah, const ushort_t* __restrict__ Al,
    const float* __restrict__ Af,
    const ushort_t* __restrict__ Bh, const ushort_t* __restrict__ Bl,
    const float* __restrict__ Bf,
    float* __restrict__ Co, ushort_t* __restrict__ Toh, ushort_t* __restrict__ Tol,
    int M, int Ncol, int K, long long sA, long long sB, long long sC, int gx) {
  __shared__ ushort_t Ahs[128 * 32];
  __shared__ ushort_t Bhs[128 * 32];
  __shared__ ushort_t Als[SA ? 128 * 32 : 64];
  __shared__ ushort_t Bls[SB ? 128 * 32 : 64];

  int tid = threadIdx.x;
  int id = blockIdx.x;
  long long bz = id & 7;              // batch -> XCD pin (NB==8)
  int t0 = id >> 3;
  int tn = t0 % gx, tm = t0 / gx;
  int n0 = tn * 128, m0 = tm * 128;
  const ushort_t* Ahb = (!ACVT) ? (Ah + bz * sA) : (const ushort_t*)0;
  const ushort_t* Alb = (!ACVT && SA) ? (Al + bz * sA) : (const ushort_t*)0;
  const float*    Afb = ACVT ? (Af + bz * sA) : (const float*)0;
  const ushort_t* Bhb = (!BCVT) ? (Bh + bz * sB) : (const ushort_t*)0;
  const ushort_t* Blb = (!BCVT && SB) ? (Bl + bz * sB) : (const ushort_t*)0;
  const float*    Bfb = BCVT ? (Bf + bz * sB) : (const float*)0;

  int sr = tid >> 2;
  int sc = (tid & 3) * 8;
  int br = tid >> 1, bc = (tid & 1) * 16;
  int lane = tid & 63, w = tid >> 6;
  int wm = (w >> 1) * 64, wn = (w & 1) * 64;
  int fr = lane & 15;
  int fo = (lane >> 4) * 8;
  int q = lane >> 4;

  f32x4 acc[4][4];
  f32x4 zz = {0.f, 0.f, 0.f, 0.f};
#pragma unroll
  for (int i = 0; i < 4; i++)
#pragma unroll
    for (int j = 0; j < 4; j++) acc[i][j] = zz;

  for (int k0 = 0; k0 < K; k0 += 32) {
    __syncthreads();
    if constexpr (!ACVT) {
#pragma unroll
      for (int r = 0; r < 128; r += 64) {
        GLDS16(Ahb + (long long)(m0 + sr + r) * K + k0 + sc, &Ahs[(r + sr) * 32 + sc]);
        if constexpr (SA) {
          GLDS16(Alb + (long long)(m0 + sr + r) * K + k0 + sc, &Als[(r + sr) * 32 + sc]);
        }
      }
    } else {
      const float* g = Afb + (long long)(m0 + br) * K + k0 + bc;
      float vv[16];
      *(float4*)&vv[0]  = *(const float4*)(g);
      *(float4*)&vv[4]  = *(const float4*)(g + 4);
      *(float4*)&vv[8]  = *(const float4*)(g + 8);
      *(float4*)&vv[12] = *(const float4*)(g + 12);
      unsigned ph[8];
#pragma unroll
      for (int t = 0; t < 8; t++) {
        ushort_t h0 = f2bf(vv[2 * t]), h1 = f2bf(vv[2 * t + 1]);
        ph[t] = (unsigned)h0 | ((unsigned)h1 << 16);
      }
      *(uint4*)&Ahs[br * 32 + bc]     = make_uint4(ph[0], ph[1], ph[2], ph[3]);
      *(uint4*)&Ahs[br * 32 + bc + 8] = make_uint4(ph[4], ph[5], ph[6], ph[7]);
    }
    if constexpr (!BCVT) {
#pragma unroll
      for (int r = 0; r < 128; r += 64) {
        GLDS16(Bhb + (long long)(n0 + sr + r) * K + k0 + sc, &Bhs[(r + sr) * 32 + sc]);
        if constexpr (SB) {
          GLDS16(Blb + (long long)(n0 + sr + r) * K + k0 + sc, &Bls[(r + sr) * 32 + sc]);
        }
      }
    } else {
      const float* g = Bfb + (long long)(n0 + br) * K + k0 + bc;
      float vv[16];
      *(float4*)&vv[0]  = *(const float4*)(g);
      *(float4*)&vv[4]  = *(const float4*)(g + 4);
      *(float4*)&vv[8]  = *(const float4*)(g + 8);
      *(float4*)&vv[12] = *(const float4*)(g + 12);
      unsigned ph[8], pl[8];
#pragma unroll
      for (int t = 0; t < 8; t++) {
        ushort_t h0 = f2bf(vv[2 * t]), h1 = f2bf(vv[2 * t + 1]);
        ph[t] = (unsigned)h0 | ((unsigned)h1 << 16);
        if constexpr (SB) {
          ushort_t l0 = f2bf(vv[2 * t] - bf2f(h0)), l1 = f2bf(vv[2 * t + 1] - bf2f(h1));
          pl[t] = (unsigned)l0 | ((unsigned)l1 << 16);
        }
      }
      *(uint4*)&Bhs[br * 32 + bc]     = make_uint4(ph[0], ph[1], ph[2], ph[3]);
      *(uint4*)&Bhs[br * 32 + bc + 8] = make_uint4(ph[4], ph[5], ph[6], ph[7]);
      if constexpr (SB) {
        *(uint4*)&Bls[br * 32 + bc]     = make_uint4(pl[0], pl[1], pl[2], pl[3]);
        *(uint4*)&Bls[br * 32 + bc + 8] = make_uint4(pl[4], pl[5], pl[6], pl[7]);
      }
    }
    __syncthreads();

    short8 ah[4], al[4], bh[4], bl[4];
#pragma unroll
    for (int i = 0; i < 4; i++) {
      ah[i] = *(const short8*)&Ahs[(wm + i * 16 + fr) * 32 + fo];
      if constexpr (SA) al[i] = *(const short8*)&Als[(wm + i * 16 + fr) * 32 + fo];
    }
#pragma unroll
    for (int j = 0; j < 4; j++) {
      bh[j] = *(const short8*)&Bhs[(wn + j * 16 + fr) * 32 + fo];
      if constexpr (SB) bl[j] = *(const short8*)&Bls[(wn + j * 16 + fr) * 32 + fo];
    }
#pragma unroll
    for (int i = 0; i < 4; i++)
#pragma unroll
      for (int j = 0; j < 4; j++) {
        acc[i][j] = __builtin_amdgcn_mfma_f32_16x16x32_bf16(ah[i], bh[j], acc[i][j], 0, 0, 0);
        if constexpr (SB)
          acc[i][j] = __builtin_amdgcn_mfma_f32_16x16x32_bf16(ah[i], bl[j], acc[i][j], 0, 0, 0);
        if constexpr (SA)
          acc[i][j] = __builtin_amdgcn_mfma_f32_16x16x32_bf16(al[i], bh[j], acc[i][j], 0, 0, 0);
      }
  }

  // epilogue: C/D layout col=lane&15, row=quad*4+reg
#pragma unroll
  for (int i = 0; i < 4; i++)
#pragma unroll
    for (int j = 0; j < 4; j++)
#pragma unroll
      for (int r = 0; r < 4; r++) {
        float v = acc[i][j][r];
        int row = m0 + wm + i * 16 + q * 4 + r;
        int col = n0 + wn + j * 16 + fr;
        long long idx = bz * sC + (long long)row * Ncol + col;
        if constexpr (EPI == 0) {
          Co[idx] = v;
        } else if constexpr (EPI == 1) {
          ushort_t h = f2bf(v);
          Toh[idx] = h;
          Tol[idx] = f2bf(v - bf2f(h));
        } else {  // EPI == 5
          float vq = floorf(v * 10000.f) / 10000.f;
          Co[idx] = vq;
          ushort_t h = f2bf(vq);
          Toh[idx] = h;
          Tol[idx] = f2bf(vq - bf2f(h));
        }
      }
}

// ---------- GCN1 epilogue (full space, relu, mask); y computed inline from xw ----------
__global__ void epi_k(const float* __restrict__ acc, const float* __restrict__ xw,
                      const float* __restrict__ dgcn, const float* __restrict__ diag,
                      const float* __restrict__ bias, const float* __restrict__ mask,
                      float* __restrict__ outx) {
  long long i = (long long)blockIdx.x * 256 + threadIdx.x;
  int rowi = (int)(i >> 7);
  int f = (int)(i & 127);
  float d = dgcn[rowi];
  float t = d * (acc[i] + (1.f - diag[rowi]) * d * xw[i]) + bias[f];
  t *= mask[rowi];
  outx[i] = fmaxf(t, 0.f);
}

// ---------- final epilogue (compact, mask via kmap, no relu) ----------
__global__ void epic_k(float* __restrict__ acc, const float* __restrict__ xw,
                       const float* __restrict__ dgcn, const float* __restrict__ diag,
                       const float* __restrict__ bias, const float* __restrict__ mask,
                       const int* __restrict__ kmap) {
  long long i = (long long)blockIdx.x * 256 + threadIdx.x;
  int rowi = (int)(i >> 8);
  int f = (int)(i & 255);
  int b = rowi / MPAD;
  int km = kmap[rowi];
  float mv = (km >= 0) ? mask[b * NN + km] : 1.f;
  float d = dgcn[rowi];
  float t = d * (acc[i] + (1.f - diag[rowi]) * d * xw[i]) + bias[f];
  acc[i] = t * mv;
}

// ---------- means ----------
__global__ void mean_k(const float* __restrict__ X, float* __restrict__ out) {
  int b = blockIdx.x, f = threadIdx.x;
  const float* p = X + (long long)b * NN * HH + f;
  float s = 0.f;
  for (int n = 0; n < NN; n++) s += p[(long long)n * HH];
  out[b * (HH + FF) + f] = s * (1.f / NN);
}

__global__ void meanc_k(const float* __restrict__ X, const float* __restrict__ b2,
                        float* __restrict__ out) {
  int b = blockIdx.x, f = threadIdx.x;
  const float* p = X + (long long)b * MPAD * FF + f;
  float s = 0.f;
  for (int n = 0; n < MPAD; n++) s += p[(long long)n * FF];
  out[b * (HH + FF) + HH + f] = s * (1.f / NN) + ((float)(NN - MPAD) / NN) * b2[f];
}

// ---------- fp32 VALU GEMM (feature matmuls) ----------
__global__ __launch_bounds__(256) void gemm_k(const float* __restrict__ A, const float* __restrict__ B,
                                              float* __restrict__ C, int M, int Nw, int Kk,
                                              long long sA, long long sB, long long sC) {
  __shared__ float As[16][128];
  __shared__ float Bs[16][128];
  int tid = threadIdx.x;
  int n0 = blockIdx.x * 128, m0 = blockIdx.y * 128;
  const float* Ab = A + (long long)blockIdx.z * sA;
  const float* Bb = B + (long long)blockIdx.z * sB;
  float* Cb = C + (long long)blockIdx.z * sC;
  float acc[8][8];
#pragma unroll
  for (int i = 0; i < 8; i++)
#pragma unroll
    for (int j = 0; j < 8; j++) acc[i][j] = 0.f;
  int tx = tid & 15, ty = tid >> 4;

  for (int k0 = 0; k0 < Kk; k0 += 16) {
    {
      int r = tid >> 2, c = (tid & 3) << 2;
#pragma unroll
      for (int rr = 0; rr < 2; rr++) {
        int rrow = r + rr * 64;
        float4 v = *(const float4*)(Ab + (long long)(m0 + rrow) * Kk + k0 + c);
        As[c + 0][rrow] = v.x; As[c + 1][rrow] = v.y;
        As[c + 2][rrow] = v.z; As[c + 3][rrow] = v.w;
      }
    }
    {
      int kk = tid >> 5, cc = (tid & 31) << 2;
#pragma unroll
      for (int k2 = 0; k2 < 2; k2++) {
        float4 v = *(const float4*)(Bb + (long long)(k0 + kk + k2 * 8) * Nw + n0 + cc);
        *(float4*)&Bs[kk + k2 * 8][cc] = v;
      }
    }
    __syncthreads();
#pragma unroll
    for (int kk = 0; kk < 16; kk++) {
      float a[8], bb[8];
      *(float4*)&a[0]  = *(float4*)&As[kk][ty * 8];
      *(float4*)&a[4]  = *(float4*)&As[kk][ty * 8 + 4];
      *(float4*)&bb[0] = *(float4*)&Bs[kk][tx * 8];
      *(float4*)&bb[4] = *(float4*)&Bs[kk][tx * 8 + 4];
#pragma unroll
      for (int i = 0; i < 8; i++)
#pragma unroll
        for (int j = 0; j < 8; j++) acc[i][j] += a[i] * bb[j];
    }
    __syncthreads();
  }
#pragma unroll
  for (int i = 0; i < 8; i++) {
    float* cp = Cb + (long long)(m0 + ty * 8 + i) * Nw + n0 + tx * 8;
    *(float4*)cp = *(float4*)&acc[i][0];
    *(float4*)(cp + 4) = *(float4*)&acc[i][4];
  }
}

extern "C" void kernel_launch(void* const* d_in, const int* in_sizes, int n_in,
                              void* d_out, int out_size, void* d_ws, size_t ws_size,
                              hipStream_t stream) {
  const float* x    = (const float*)d_in[0];
  const float* adj  = (const float*)d_in[1];
  const float* mask = (const float*)d_in[2];
  const float* W1   = (const float*)d_in[3];
  const float* b1   = (const float*)d_in[4];
  const float* Watt = (const float*)d_in[5];
  const float* batt = (const float*)d_in[6];
  const float* W2   = (const float*)d_in[7];
  const float* b2   = (const float*)d_in[8];
  float* out = (float*)d_out;

  const long long NN2  = (long long)NN * NN;
  const long long CSTR = (long long)MPAD * NN;
  const long long CTOT = (long long)NB * CSTR;
  const long long M2   = (long long)MPAD * MPAD;
  const long long M2T  = (long long)NB * M2;

  // ---- workspace ----
  float* ws = (float*)d_ws;
  long long off = 0;
  ushort_t* StcH = (ushort_t*)(ws + off); off += CTOT / 2;
  ushort_t* StcL = (ushort_t*)(ws + off); off += CTOT / 2;
  float* TcF  = ws + off; off += CTOT;
  float* A2cF = ws + off; off += M2T;
  ushort_t* A2cH = (ushort_t*)(ws + off); off += M2T / 2;
  ushort_t* A2cL = (ushort_t*)(ws + off); off += M2T / 2;
  float* xa   = ws + off; off += (long long)NROWS * HH;
  float* x2c  = ws + off; off += (long long)MC * HH;
  float* x3c  = ws + off; off += (long long)MC * HH;
  float* rowsum = ws + off; off += NROWS;
  float* diag   = ws + off; off += NROWS;
  float* dgcn   = ws + off; off += NROWS;
  float* dnorm  = ws + off; off += NROWS;
  float* rz     = ws + off; off += NROWS;
  float* wv     = ws + off; off += NROWS;
  float* alphav = ws + off; off += (long long)NB * NN;
  float* colwv  = ws + off; off += NROWS;
  float* scalev = ws + off; off += NROWS;
  float* cutv   = ws + off; off += NB;
  int* keepidx  = (int*)(ws + off); off += NB * MPAD;
  int* cntv     = (int*)(ws + off); off += NB;

  // phase-local aliases in TcF
  float* u1 = TcF;                                       // GCN1: xw1
  float* u2 = TcF + (long long)NROWS * HH;               // acc1
  ushort_t* y1Th = (ushort_t*)(TcF + 2ll * NROWS * HH);
  ushort_t* y1Tl = y1Th + (long long)NROWS * HH;
  ushort_t* TcH = (ushort_t*)TcF;                        // L0 tmp^T splits
  ushort_t* TcL = TcH + CTOT;
  ushort_t* xT1h = (ushort_t*)TcF;                       // x1^T splits
  ushort_t* xT1l = xT1h + (long long)NROWS * HH;
  ushort_t* Tc2H = (ushort_t*)TcF;                       // L1 tmp2^T splits
  ushort_t* Tc2L = Tc2H + M2T;
  ushort_t* x2Th = (ushort_t*)TcF;                       // x2c^T splits
  ushort_t* x2Tl = x2Th + (long long)MC * HH;
  float* u1f = TcF;                                      // final: xw2c
  float* u2f = TcF + (long long)MC * FF;                 // final acc / out
  ushort_t* y2Th = (ushort_t*)(TcF + 2ll * MC * FF);
  ushort_t* y2Tl = y2Th + (long long)MC * FF;

  // ================= GCN1 (full space) =================
  rowstats_k<<<NROWS / 4, 256, 0, stream>>>(adj, rowsum, diag, NN);
  derive_k<<<NROWS / 256, 256, 0, stream>>>(rowsum, diag, dgcn, dnorm, rz, NROWS);
  gemm_k<<<dim3(1, NROWS / 128, 1), 256, 0, stream>>>(x, W1, u1, NROWS, HH, FF, 0, 0, 0);
  cvt_xT_k<<<dim3(NN / 32, HH / 32, NB), 256, 0, stream>>>(u1, dgcn, y1Th, y1Tl, NN, HH);
  mgemm_k<0, 1, 1, 0, 0><<<1 * (NN / 128) * NB, 256, 0, stream>>>(
      0, 0, adj, y1Th, y1Tl, 0, u2, 0, 0,
      NN, HH, NN, NN2, (long long)HH * NN, (long long)NN * HH, 1);
  epi_k<<<(NROWS * HH) / 256, 256, 0, stream>>>(u2, u1, dgcn, diag, b1, mask, xa);
  mean_k<<<NB, HH, 0, stream>>>(xa, out);

  // ================= coarsen layer 0 (full -> compact) =================
  wvec_k<<<NROWS / 4, 256, 0, stream>>>(xa, Watt, batt, dnorm, wv);
  alpha_k<<<NROWS / 4, 256, 0, stream>>>(adj, wv, dnorm, rz, alphav, NN);
  topcut_k<<<NB, 1024, 0, stream>>>(alphav, cutv);
  keepcolw_k<<<NB, 1024, 0, stream>>>(alphav, cutv, dnorm, rz, colwv, keepidx, cntv);
  scale_k<<<NROWS / 4, 256, 0, stream>>>(adj, colwv, dnorm, rz, scalev, NN);
  writeStc_k<<<(int)(CTOT / 4 / 256), 256, 0, stream>>>(adj, scalev, colwv, keepidx, StcH, StcL);
  // G1: tmp^T = S^T @ adj
  mgemm_k<1, 0, 0, 1, 1><<<(NN / 128) * (MPAD / 128) * NB, 256, 0, stream>>>(
      StcH, StcL, 0, 0, 0, adj, 0, TcH, TcL,
      MPAD, NN, NN, CSTR, NN2, CSTR, NN / 128);
  // G2: A2c = S^T @ tmp (quant + splits)
  mgemm_k<1, 1, 0, 0, 5><<<(MPAD / 128) * (MPAD / 128) * NB, 256, 0, stream>>>(
      StcH, StcL, 0, TcH, TcL, 0, A2cF, A2cH, A2cL,
      MPAD, MPAD, NN, CSTR, CSTR, M2, MPAD / 128);
  // G3: x2c = S^T @ x1
  cvt_xT_k<<<dim3(NN / 32, HH / 32, NB), 256, 0, stream>>>(xa, 0, xT1h, xT1l, NN, HH);
  mgemm_k<1, 1, 0, 0, 0><<<1 * (MPAD / 128) * NB, 256, 0, stream>>>(
      StcH, StcL, 0, xT1h, xT1l, 0, x2c, 0, 0,
      MPAD, HH, NN, CSTR, (long long)HH * NN, (long long)MPAD * HH, 1);

  // ================= coarsen layer 1 (all compact) =================
  rowstats_k<<<MC / 4, 256, 0, stream>>>(A2cF, rowsum, diag, MPAD);
  derive_k<<<MC / 256, 256, 0, stream>>>(rowsum, diag, dgcn, dnorm, rz, MC);
  wvec_k<<<MC / 4, 256, 0, stream>>>(x2c, Watt, batt, dnorm, wv);
  alpha_k<<<MC / 4, 256, 0, stream>>>(A2cF, wv, dnorm, rz, alphav, MPAD);
  padfill_k<<<((NN - MPAD) * NB) / 256, 256, 0, stream>>>(alphav);
  topcut_k<<<NB, 1024, 0, stream>>>(alphav, cutv);
  colwc_k<<<MC / 256, 256, 0, stream>>>(alphav, cutv, dnorm, colwv);
  scale_k<<<MC / 4, 256, 0, stream>>>(A2cF, colwv, dnorm, rz, scalev, MPAD);
  writeS2c_k<<<(int)(M2T / 4 / 256), 256, 0, stream>>>(A2cF, scalev, colwv, StcH, StcL);
  // G1': tmp2^T = S2^T @ A2c
  mgemm_k<1, 1, 0, 0, 1><<<(MPAD / 128) * (MPAD / 128) * NB, 256, 0, stream>>>(
      StcH, StcL, 0, A2cH, A2cL, 0, 0, Tc2H, Tc2L,
      MPAD, MPAD, MPAD, M2, M2, M2, MPAD / 128);
  // G2': A3c = S2^T @ tmp2 (quant + splits)
  mgemm_k<1, 1, 0, 0, 5><<<(MPAD / 128) * (MPAD / 128) * NB, 256, 0, stream>>>(
      StcH, StcL, 0, Tc2H, Tc2L, 0, A2cF, A2cH, A2cL,
      MPAD, MPAD, MPAD, M2, M2, M2, MPAD / 128);
  // G3': x3c = S2^T @ x2c
  cvt_xT_k<<<dim3(MPAD / 32, HH / 32, NB), 256, 0, stream>>>(x2c, 0, x2Th, x2Tl, MPAD, HH);
  mgemm_k<1, 1, 0, 0, 0><<<1 * (MPAD / 128) * NB, 256, 0, stream>>>(
      StcH, StcL, 0, x2Th, x2Tl, 0, x3c, 0, 0,
      MPAD, HH, MPAD, M2, (long long)HH * MPAD, (long long)MPAD * HH, 1);

  // ================= final GCN (compact) =================
  rowstats_k<<<MC / 4, 256, 0, stream>>>(A2cF, rowsum, diag, MPAD);
  derive_k<<<MC / 256, 256, 0, stream>>>(rowsum, diag, dgcn, dnorm, rz, MC);
  gemm_k<<<dim3(FF / 128, MPAD / 128, NB), 256, 0, stream>>>(
      x3c, W2, u1f, MPAD, FF, HH, (long long)MPAD * HH, 0, (long long)MPAD * FF);
  cvt_xT_k<<<dim3(MPAD / 32, FF / 32, NB), 256, 0, stream>>>(u1f, dgcn, y2Th, y2Tl, MPAD, FF);
  mgemm_k<1, 1, 0, 0, 0><<<(FF / 128) * (MPAD / 128) * NB, 256, 0, stream>>>(
      A2cH, A2cL, 0, y2Th, y2Tl, 0, u2f, 0, 0,
      MPAD, FF, MPAD, M2, (long long)FF * MPAD, (long long)MPAD * FF, FF / 128);
  epic_k<<<(MC * FF) / 256, 256, 0, stream>>>(u2f, u1f, dgcn, diag, b2, mask, keepidx);
  meanc_k<<<NB, FF, 0, stream>>>(u2f, b2, out);
}

// Round 6
// 1366.609 us; speedup vs baseline: 5.7478x; 1.0743x over previous
//
#include <hip/hip_runtime.h>
#include <math.h>

#define NN 2048
#define NB 8
#define FF 256
#define HH 128
#define KSEL 1025
#define NROWS (NB*NN)
#define MPAD 1152
#define MC (MPAD*NB)

typedef unsigned short ushort_t;
typedef __attribute__((ext_vector_type(8))) short short8;
typedef __attribute__((ext_vector_type(4))) float f32x4;

__device__ inline ushort_t f2bf(float f) {
  unsigned u = __float_as_uint(f);
  unsigned r = (u + 0x7FFFu + ((u >> 16) & 1u)) >> 16;
  return (ushort_t)r;
}
__device__ inline float bf2f(ushort_t u) {
  unsigned x = ((unsigned)u) << 16;
  return __uint_as_float(x);
}

#define GLDS16(g, l) __builtin_amdgcn_global_load_lds( \
    (const __attribute__((address_space(1))) unsigned int*)(g), \
    (__attribute__((address_space(3))) unsigned int*)(l), 16, 0, 0)

// ---------- row stats + derive fused (float4), one wave per row ----------
__global__ __launch_bounds__(256) void rowstats_k(const float* __restrict__ A,
                                                  float* __restrict__ diag,
                                                  float* __restrict__ dgcn,
                                                  float* __restrict__ dnorm,
                                                  float* __restrict__ rz, int R) {
  int gw = (blockIdx.x * 256 + threadIdx.x) >> 6;
  int lane = threadIdx.x & 63;
  int b = gw / R, i = gw - b * R;
  const float4* row = (const float4*)(A + (long long)gw * R);
  int R4 = R >> 2;
  float s = 0.f;
  for (int j = lane; j < R4; j += 64) {
    float4 v = row[j];
    s += v.x + v.y + v.z + v.w;
  }
  for (int off = 32; off > 0; off >>= 1) s += __shfl_down(s, off);
  if (lane == 0) {
    float dg = A[(long long)gw * R + i];
    diag[gw] = dg;
    dgcn[gw]  = rsqrtf(fmaxf(s - dg + 1.f, 1.f));
    dnorm[gw] = rsqrtf(fmaxf(s + 1.f, 1.f));
    rz[gw]    = s > 0.f ? 1.f : 0.f;
  }
}

// ---------- adj (binary fp32) -> bf16 (exact) ----------
__global__ void cvtadjh_k(const float* __restrict__ A, ushort_t* __restrict__ H) {
  long long i4 = ((long long)blockIdx.x * 256 + threadIdx.x) * 4;
  float4 v = *(const float4*)(A + i4);
  ushort_t h0 = f2bf(v.x), h1 = f2bf(v.y), h2 = f2bf(v.z), h3 = f2bf(v.w);
  *(uint2*)&H[i4] = make_uint2((unsigned)h0 | ((unsigned)h1 << 16),
                               (unsigned)h2 | ((unsigned)h3 << 16));
}

__global__ __launch_bounds__(256) void wvec_k(const float* __restrict__ x,
                                              const float* __restrict__ Watt,
                                              const float* __restrict__ batt,
                                              const float* __restrict__ dnorm,
                                              float* __restrict__ w) {
  int gw = (blockIdx.x * 256 + threadIdx.x) >> 6;
  int lane = threadIdx.x & 63;
  const float* r = x + (long long)gw * HH;
  float s = r[lane] * Watt[lane] + r[lane + 64] * Watt[lane + 64];
  for (int off = 32; off > 0; off >>= 1) s += __shfl_down(s, off);
  if (lane == 0) w[gw] = dnorm[gw] * (s + batt[0]);
}

// ---------- alpha = sigmoid((rz*dnorm*((A+I)@w))^2); out stride NN ----------
__global__ __launch_bounds__(256) void alpha_k(const float* __restrict__ A,
                                               const float* __restrict__ w,
                                               const float* __restrict__ dnorm,
                                               const float* __restrict__ rz,
                                               float* __restrict__ alpha, int R) {
  int gw = (blockIdx.x * 256 + threadIdx.x) >> 6;
  int lane = threadIdx.x & 63;
  int b = gw / R, i = gw - b * R;
  const float4* row = (const float4*)(A + (long long)gw * R);
  const float4* wb4 = (const float4*)(w + (long long)b * R);
  int R4 = R >> 2;
  float s = 0.f;
  for (int j = lane; j < R4; j += 64) {
    float4 a = row[j], ww = wb4[j];
    s += a.x * ww.x + a.y * ww.y + a.z * ww.z + a.w * ww.w;
  }
  for (int off = 32; off > 0; off >>= 1) s += __shfl_down(s, off);
  if (lane == 0) {
    float aa = rz[gw] * dnorm[gw] * (s + w[(long long)b * R + i]);
    aa = aa * aa;
    alpha[(long long)b * NN + i] = 1.f / (1.f + expf(-aa));
  }
}

__global__ void padfill_k(float* __restrict__ alpha) {
  int idx = blockIdx.x * 256 + threadIdx.x;
  int b = idx / (NN - MPAD), j = idx - b * (NN - MPAD);
  alpha[b * NN + MPAD + j] = 0.5f;
}

// ---------- L0: bitonic top-k cut + colw + keep list, one block/batch ----------
__global__ __launch_bounds__(1024) void topkeep_k(const float* __restrict__ alpha,
                                                  const float* __restrict__ dnorm,
                                                  const float* __restrict__ rz,
                                                  float* __restrict__ colw,
                                                  int* __restrict__ keepidx) {
  __shared__ float a[NN];
  __shared__ int ps[NN];
  int b = blockIdx.x, t = threadIdx.x;
  a[t] = alpha[b * NN + t];
  a[t + 1024] = alpha[b * NN + t + 1024];
  __syncthreads();
  for (int k = 2; k <= NN; k <<= 1) {
    for (int j = k >> 1; j > 0; j >>= 1) {
      for (int i = t; i < NN; i += 1024) {
        int ixj = i ^ j;
        if (ixj > i) {
          float x = a[i], y = a[ixj];
          bool up = ((i & k) == 0);
          if ((x > y) == up) { a[i] = y; a[ixj] = x; }
        }
      }
      __syncthreads();
    }
  }
  float cu = a[NN - KSEL];
  __syncthreads();
  float c0 = dnorm[b * NN + t]        * fmaxf(alpha[b * NN + t]        + 1e-7f - cu, 0.f);
  float c1 = dnorm[b * NN + t + 1024] * fmaxf(alpha[b * NN + t + 1024] + 1e-7f - cu, 0.f);
  colw[b * NN + t] = c0;
  colw[b * NN + t + 1024] = c1;
  int f0 = (c0 != 0.f && rz[b * NN + t]        != 0.f) ? 1 : 0;
  int f1 = (c1 != 0.f && rz[b * NN + t + 1024] != 0.f) ? 1 : 0;
  ps[t] = f0; ps[t + 1024] = f1;
  __syncthreads();
  for (int off = 1; off < NN; off <<= 1) {
    int v0 = (t >= off) ? ps[t - off] : 0;
    int v1 = (t + 1024 >= off) ? ps[t + 1024 - off] : 0;
    __syncthreads();
    ps[t] += v0; ps[t + 1024] += v1;
    __syncthreads();
  }
  if (t < MPAD) keepidx[b * MPAD + t] = -1;
  if (t + 1024 < MPAD) keepidx[b * MPAD + t + 1024] = -1;
  __syncthreads();
  if (f0 && ps[t] - 1 < MPAD) keepidx[b * MPAD + ps[t] - 1] = t;
  if (f1 && ps[t + 1024] - 1 < MPAD) keepidx[b * MPAD + ps[t + 1024] - 1] = t + 1024;
}

// ---------- L1: bitonic cut + compact colw, one block/batch ----------
__global__ __launch_bounds__(1024) void topcolw_k(const float* __restrict__ alpha,
                                                  const float* __restrict__ dnorm,
                                                  float* __restrict__ colw) {
  __shared__ float a[NN];
  int b = blockIdx.x, t = threadIdx.x;
  a[t] = alpha[b * NN + t];
  a[t + 1024] = alpha[b * NN + t + 1024];
  __syncthreads();
  for (int k = 2; k <= NN; k <<= 1) {
    for (int j = k >> 1; j > 0; j >>= 1) {
      for (int i = t; i < NN; i += 1024) {
        int ixj = i ^ j;
        if (ixj > i) {
          float x = a[i], y = a[ixj];
          bool up = ((i & k) == 0);
          if ((x > y) == up) { a[i] = y; a[ixj] = x; }
        }
      }
      __syncthreads();
    }
  }
  float cu = a[NN - KSEL];
  for (int ii = t; ii < MPAD; ii += 1024) {
    float c = fmaxf(alpha[b * NN + ii] + 1e-7f - cu, 0.f);
    colw[b * MPAD + ii] = dnorm[b * MPAD + ii] * c;
  }
}

// ---------- scale_n ----------
__global__ __launch_bounds__(256) void scale_k(const float* __restrict__ A,
                                               const float* __restrict__ colw,
                                               const float* __restrict__ dnorm,
                                               const float* __restrict__ rz,
                                               float* __restrict__ scale, int R) {
  int gw = (blockIdx.x * 256 + threadIdx.x) >> 6;
  int lane = threadIdx.x & 63;
  int b = gw / R, i = gw - b * R;
  const float4* row = (const float4*)(A + (long long)gw * R);
  const float4* cw4 = (const float4*)(colw + (long long)b * R);
  int R4 = R >> 2;
  float s = 0.f;
  for (int j = lane; j < R4; j += 64) {
    float4 a = row[j], c = cw4[j];
    s += a.x * c.x + a.y * c.y + a.z * c.z + a.w * c.w;
  }
  for (int off = 32; off > 0; off >>= 1) s += __shfl_down(s, off);
  if (lane == 0) {
    float rsum = rz[gw] * dnorm[gw] * (s + colw[(long long)b * R + i]);
    scale[gw] = rz[gw] * dnorm[gw] / fmaxf(rsum, 1e-12f);
  }
}

// ---------- L0 compact S^T rows, split bf16 ----------
__global__ void writeStc_k(const float* __restrict__ adj, const float* __restrict__ scale,
                           const float* __restrict__ colw, const int* __restrict__ keepidx,
                           ushort_t* __restrict__ Sh, ushort_t* __restrict__ Sl) {
  long long g = (long long)blockIdx.x * 256 + threadIdx.x;
  int bi = (int)(g >> 9);
  int n = (int)(g & 511) * 4;
  int b = bi / MPAD;
  long long o = (long long)bi * NN + n;
  int row = keepidx[bi];
  if (row < 0) {
    *(uint2*)&Sh[o] = make_uint2(0, 0);
    *(uint2*)&Sl[o] = make_uint2(0, 0);
    return;
  }
  float cw = colw[b * NN + row];
  float4 sc = *(const float4*)(scale + b * NN + n);
  float4 av = *(const float4*)(adj + ((long long)b * NN + row) * NN + n);
  float v0 = sc.x * (av.x + (float)(n     == row)) * cw;
  float v1 = sc.y * (av.y + (float)(n + 1 == row)) * cw;
  float v2 = sc.z * (av.z + (float)(n + 2 == row)) * cw;
  float v3 = sc.w * (av.w + (float)(n + 3 == row)) * cw;
  ushort_t h0 = f2bf(v0), h1 = f2bf(v1), h2 = f2bf(v2), h3 = f2bf(v3);
  *(uint2*)&Sh[o] = make_uint2((unsigned)h0 | ((unsigned)h1 << 16),
                               (unsigned)h2 | ((unsigned)h3 << 16));
  ushort_t l0 = f2bf(v0 - bf2f(h0)), l1 = f2bf(v1 - bf2f(h1));
  ushort_t l2 = f2bf(v2 - bf2f(h2)), l3 = f2bf(v3 - bf2f(h3));
  *(uint2*)&Sl[o] = make_uint2((unsigned)l0 | ((unsigned)l1 << 16),
                               (unsigned)l2 | ((unsigned)l3 << 16));
}

// ---------- L1 compact S2^T ----------
__global__ void writeS2c_k(const float* __restrict__ A2c, const float* __restrict__ scale,
                           const float* __restrict__ colw,
                           ushort_t* __restrict__ Sh, ushort_t* __restrict__ Sl) {
  int g = blockIdx.x * 256 + threadIdx.x;
  int bl = g / (MPAD / 4);
  int k = (g - bl * (MPAD / 4)) * 4;
  int b = bl / MPAD, l = bl - b * MPAD;
  long long o = (long long)bl * MPAD + k;
  float cw = colw[b * MPAD + l];
  float4 sc = *(const float4*)(scale + b * MPAD + k);
  float4 av = *(const float4*)(A2c + o);
  float v0 = sc.x * (av.x + (float)(k     == l)) * cw;
  float v1 = sc.y * (av.y + (float)(k + 1 == l)) * cw;
  float v2 = sc.z * (av.z + (float)(k + 2 == l)) * cw;
  float v3 = sc.w * (av.w + (float)(k + 3 == l)) * cw;
  ushort_t h0 = f2bf(v0), h1 = f2bf(v1), h2 = f2bf(v2), h3 = f2bf(v3);
  *(uint2*)&Sh[o] = make_uint2((unsigned)h0 | ((unsigned)h1 << 16),
                               (unsigned)h2 | ((unsigned)h3 << 16));
  ushort_t l0 = f2bf(v0 - bf2f(h0)), l1 = f2bf(v1 - bf2f(h1));
  ushort_t l2 = f2bf(v2 - bf2f(h2)), l3 = f2bf(v3 - bf2f(h3));
  *(uint2*)&Sl[o] = make_uint2((unsigned)l0 | ((unsigned)l1 << 16),
                               (unsigned)l2 | ((unsigned)l3 << 16));
}

// ---------- transpose + split, optional per-row scale ----------
__global__ __launch_bounds__(256) void cvt_xT_k(const float* __restrict__ X,
                                                const float* __restrict__ rsc,
                                                ushort_t* __restrict__ Th, ushort_t* __restrict__ Tl,
                                                int Nn, int Fd) {
  __shared__ float t[32][33];
  int b = blockIdx.z;
  int n0 = blockIdx.x * 32, f0 = blockIdx.y * 32;
  int tx = threadIdx.x & 31, ty = threadIdx.x >> 5;
  const float* Xb = X + ((long long)b * Nn + n0) * Fd + f0;
  for (int r = ty; r < 32; r += 8) {
    float sc = rsc ? rsc[(long long)b * Nn + n0 + r] : 1.f;
    t[r][tx] = sc * Xb[(long long)r * Fd + tx];
  }
  __syncthreads();
  for (int r = ty; r < 32; r += 8) {
    float v = t[tx][r];
    ushort_t h = f2bf(v);
    long long idx = ((long long)b * Fd + f0 + r) * Nn + n0 + tx;
    Th[idx] = h;
    Tl[idx] = f2bf(v - bf2f(h));
  }
}

// ============ MFMA split-bf16 GEMM, batch->XCD swizzled ============
template<int SA, int SB, int ACVT, int BCVT, int EPI>
__global__ __launch_bounds__(256) void mgemm_k(
    const ushort_t* __restrict__ Ah, const ushort_t* __restrict__ Al,
    const float* __restrict__ Af,
    const ushort_t* __restrict__ Bh, const ushort_t* __restrict__ Bl,
    const float* __restrict__ Bf,
    float* __restrict__ Co, ushort_t* __restrict__ Toh, ushort_t* __restrict__ Tol,
    int M, int Ncol, int K, long long sA, long long sB, long long sC, int gx) {
  __shared__ ushort_t Ahs[128 * 32];
  __shared__ ushort_t Bhs[128 * 32];
  __shared__ ushort_t Als[SA ? 128 * 32 : 64];
  __shared__ ushort_t Bls[SB ? 128 * 32 : 64];

  int tid = threadIdx.x;
  int id = blockIdx.x;
  long long bz = id & 7;
  int t0 = id >> 3;
  int tn = t0 % gx, tm = t0 / gx;
  int n0 = tn * 128, m0 = tm * 128;
  const ushort_t* Ahb = (!ACVT) ? (Ah + bz * sA) : (const ushort_t*)0;
  const ushort_t* Alb = (!ACVT && SA) ? (Al + bz * sA) : (const ushort_t*)0;
  const float*    Afb = ACVT ? (Af + bz * sA) : (const float*)0;
  const ushort_t* Bhb = (!BCVT) ? (Bh + bz * sB) : (const ushort_t*)0;
  const ushort_t* Blb = (!BCVT && SB) ? (Bl + bz * sB) : (const ushort_t*)0;
  const float*    Bfb = BCVT ? (Bf + bz * sB) : (const float*)0;

  int sr = tid >> 2;
  int sc = (tid & 3) * 8;
  int br = tid >> 1, bc = (tid & 1) * 16;
  int lane = tid & 63, w = tid >> 6;
  int wm = (w >> 1) * 64, wn = (w & 1) * 64;
  int fr = lane & 15;
  int fo = (lane >> 4) * 8;
  int q = lane >> 4;

  f32x4 acc[4][4];
  f32x4 zz = {0.f, 0.f, 0.f, 0.f};
#pragma unroll
  for (int i = 0; i < 4; i++)
#pragma unroll
    for (int j = 0; j < 4; j++) acc[i][j] = zz;

  for (int k0 = 0; k0 < K; k0 += 32) {
    __syncthreads();
    if constexpr (!ACVT) {
#pragma unroll
      for (int r = 0; r < 128; r += 64) {
        GLDS16(Ahb + (long long)(m0 + sr + r) * K + k0 + sc, &Ahs[(r + sr) * 32 + sc]);
        if constexpr (SA) {
          GLDS16(Alb + (long long)(m0 + sr + r) * K + k0 + sc, &Als[(r + sr) * 32 + sc]);
        }
      }
    } else {
      const float* g = Afb + (long long)(m0 + br) * K + k0 + bc;
      float vv[16];
      *(float4*)&vv[0]  = *(const float4*)(g);
      *(float4*)&vv[4]  = *(const float4*)(g + 4);
      *(float4*)&vv[8]  = *(const float4*)(g + 8);
      *(float4*)&vv[12] = *(const float4*)(g + 12);
      unsigned ph[8];
#pragma unroll
      for (int t = 0; t < 8; t++) {
        ushort_t h0 = f2bf(vv[2 * t]), h1 = f2bf(vv[2 * t + 1]);
        ph[t] = (unsigned)h0 | ((unsigned)h1 << 16);
      }
      *(uint4*)&Ahs[br * 32 + bc]     = make_uint4(ph[0], ph[1], ph[2], ph[3]);
      *(uint4*)&Ahs[br * 32 + bc + 8] = make_uint4(ph[4], ph[5], ph[6], ph[7]);
    }
    if constexpr (!BCVT) {
#pragma unroll
      for (int r = 0; r < 128; r += 64) {
        GLDS16(Bhb + (long long)(n0 + sr + r) * K + k0 + sc, &Bhs[(r + sr) * 32 + sc]);
        if constexpr (SB) {
          GLDS16(Blb + (long long)(n0 + sr + r) * K + k0 + sc, &Bls[(r + sr) * 32 + sc]);
        }
      }
    } else {
      const float* g = Bfb + (long long)(n0 + br) * K + k0 + bc;
      float vv[16];
      *(float4*)&vv[0]  = *(const float4*)(g);
      *(float4*)&vv[4]  = *(const float4*)(g + 4);
      *(float4*)&vv[8]  = *(const float4*)(g + 8);
      *(float4*)&vv[12] = *(const float4*)(g + 12);
      unsigned ph[8], pl[8];
#pragma unroll
      for (int t = 0; t < 8; t++) {
        ushort_t h0 = f2bf(vv[2 * t]), h1 = f2bf(vv[2 * t + 1]);
        ph[t] = (unsigned)h0 | ((unsigned)h1 << 16);
        if constexpr (SB) {
          ushort_t l0 = f2bf(vv[2 * t] - bf2f(h0)), l1 = f2bf(vv[2 * t + 1] - bf2f(h1));
          pl[t] = (unsigned)l0 | ((unsigned)l1 << 16);
        }
      }
      *(uint4*)&Bhs[br * 32 + bc]     = make_uint4(ph[0], ph[1], ph[2], ph[3]);
      *(uint4*)&Bhs[br * 32 + bc + 8] = make_uint4(ph[4], ph[5], ph[6], ph[7]);
      if constexpr (SB) {
        *(uint4*)&Bls[br * 32 + bc]     = make_uint4(pl[0], pl[1], pl[2], pl[3]);
        *(uint4*)&Bls[br * 32 + bc + 8] = make_uint4(pl[4], pl[5], pl[6], pl[7]);
      }
    }
    __syncthreads();

    short8 ah[4], al[4], bh[4], bl[4];
#pragma unroll
    for (int i = 0; i < 4; i++) {
      ah[i] = *(const short8*)&Ahs[(wm + i * 16 + fr) * 32 + fo];
      if constexpr (SA) al[i] = *(const short8*)&Als[(wm + i * 16 + fr) * 32 + fo];
    }
#pragma unroll
    for (int j = 0; j < 4; j++) {
      bh[j] = *(const short8*)&Bhs[(wn + j * 16 + fr) * 32 + fo];
      if constexpr (SB) bl[j] = *(const short8*)&Bls[(wn + j * 16 + fr) * 32 + fo];
    }
#pragma unroll
    for (int i = 0; i < 4; i++)
#pragma unroll
      for (int j = 0; j < 4; j++) {
        acc[i][j] = __builtin_amdgcn_mfma_f32_16x16x32_bf16(ah[i], bh[j], acc[i][j], 0, 0, 0);
        if constexpr (SB)
          acc[i][j] = __builtin_amdgcn_mfma_f32_16x16x32_bf16(ah[i], bl[j], acc[i][j], 0, 0, 0);
        if constexpr (SA)
          acc[i][j] = __builtin_amdgcn_mfma_f32_16x16x32_bf16(al[i], bh[j], acc[i][j], 0, 0, 0);
      }
  }

#pragma unroll
  for (int i = 0; i < 4; i++)
#pragma unroll
    for (int j = 0; j < 4; j++)
#pragma unroll
      for (int r = 0; r < 4; r++) {
        float v = acc[i][j][r];
        int row = m0 + wm + i * 16 + q * 4 + r;
        int col = n0 + wn + j * 16 + fr;
        long long idx = bz * sC + (long long)row * Ncol + col;
        if constexpr (EPI == 0) {
          Co[idx] = v;
        } else if constexpr (EPI == 1) {
          ushort_t h = f2bf(v);
          Toh[idx] = h;
          Tol[idx] = f2bf(v - bf2f(h));
        } else {  // EPI == 5
          float vq = floorf(v * 10000.f) / 10000.f;
          Co[idx] = vq;
          ushort_t h = f2bf(vq);
          Toh[idx] = h;
          Tol[idx] = f2bf(vq - bf2f(h));
        }
      }
}

// ---------- GCN1 epilogue ----------
__global__ void epi_k(const float* __restrict__ acc, const float* __restrict__ xw,
                      const float* __restrict__ dgcn, const float* __restrict__ diag,
                      const float* __restrict__ bias, const float* __restrict__ mask,
                      float* __restrict__ outx) {
  long long i = (long long)blockIdx.x * 256 + threadIdx.x;
  int rowi = (int)(i >> 7);
  int f = (int)(i & 127);
  float d = dgcn[rowi];
  float t = d * (acc[i] + (1.f - diag[rowi]) * d * xw[i]) + bias[f];
  t *= mask[rowi];
  outx[i] = fmaxf(t, 0.f);
}

// ---------- final epilogue (compact) ----------
__global__ void epic_k(float* __restrict__ acc, const float* __restrict__ xw,
                       const float* __restrict__ dgcn, const float* __restrict__ diag,
                       const float* __restrict__ bias, const float* __restrict__ mask,
                       const int* __restrict__ kmap) {
  long long i = (long long)blockIdx.x * 256 + threadIdx.x;
  int rowi = (int)(i >> 8);
  int f = (int)(i & 255);
  int b = rowi / MPAD;
  int km = kmap[rowi];
  float mv = (km >= 0) ? mask[b * NN + km] : 1.f;
  float d = dgcn[rowi];
  float t = d * (acc[i] + (1.f - diag[rowi]) * d * xw[i]) + bias[f];
  acc[i] = t * mv;
}

// ---------- two-stage column means ----------
__global__ void pmean_k(const float* __restrict__ X, float* __restrict__ part,
                        int Nn, int Fd, int rpc) {
  int b = blockIdx.y, c = blockIdx.x, f = threadIdx.x;
  const float* p = X + ((long long)b * Nn + (long long)c * rpc) * Fd + f;
  float s = 0.f;
  for (int r = 0; r < rpc; r++) s += p[(long long)r * Fd];
  part[((long long)b * gridDim.x + c) * Fd + f] = s;
}

__global__ void fmean_k(const float* __restrict__ part, int nch, int Fd, float corr,
                        const float* __restrict__ bias, float* __restrict__ out, int outoff) {
  int b = blockIdx.x, f = threadIdx.x;
  float s = 0.f;
  for (int c = 0; c < nch; c++) s += part[((long long)b * nch + c) * Fd + f];
  float cv = bias ? corr * bias[f] : 0.f;
  out[b * (HH + FF) + outoff + f] = s * (1.f / NN) + cv;
}

// ---------- fp32 VALU GEMM (feature matmuls) ----------
__global__ __launch_bounds__(256) void gemm_k(const float* __restrict__ A, const float* __restrict__ B,
                                              float* __restrict__ C, int M, int Nw, int Kk,
                                              long long sA, long long sB, long long sC) {
  __shared__ float As[16][128];
  __shared__ float Bs[16][128];
  int tid = threadIdx.x;
  int n0 = blockIdx.x * 128, m0 = blockIdx.y * 128;
  const float* Ab = A + (long long)blockIdx.z * sA;
  const float* Bb = B + (long long)blockIdx.z * sB;
  float* Cb = C + (long long)blockIdx.z * sC;
  float acc[8][8];
#pragma unroll
  for (int i = 0; i < 8; i++)
#pragma unroll
    for (int j = 0; j < 8; j++) acc[i][j] = 0.f;
  int tx = tid & 15, ty = tid >> 4;

  for (int k0 = 0; k0 < Kk; k0 += 16) {
    {
      int r = tid >> 2, c = (tid & 3) << 2;
#pragma unroll
      for (int rr = 0; rr < 2; rr++) {
        int rrow = r + rr * 64;
        float4 v = *(const float4*)(Ab + (long long)(m0 + rrow) * Kk + k0 + c);
        As[c + 0][rrow] = v.x; As[c + 1][rrow] = v.y;
        As[c + 2][rrow] = v.z; As[c + 3][rrow] = v.w;
      }
    }
    {
      int kk = tid >> 5, cc = (tid & 31) << 2;
#pragma unroll
      for (int k2 = 0; k2 < 2; k2++) {
        float4 v = *(const float4*)(Bb + (long long)(k0 + kk + k2 * 8) * Nw + n0 + cc);
        *(float4*)&Bs[kk + k2 * 8][cc] = v;
      }
    }
    __syncthreads();
#pragma unroll
    for (int kk = 0; kk < 16; kk++) {
      float a[8], bb[8];
      *(float4*)&a[0]  = *(float4*)&As[kk][ty * 8];
      *(float4*)&a[4]  = *(float4*)&As[kk][ty * 8 + 4];
      *(float4*)&bb[0] = *(float4*)&Bs[kk][tx * 8];
      *(float4*)&bb[4] = *(float4*)&Bs[kk][tx * 8 + 4];
#pragma unroll
      for (int i = 0; i < 8; i++)
#pragma unroll
        for (int j = 0; j < 8; j++) acc[i][j] += a[i] * bb[j];
    }
    __syncthreads();
  }
#pragma unroll
  for (int i = 0; i < 8; i++) {
    float* cp = Cb + (long long)(m0 + ty * 8 + i) * Nw + n0 + tx * 8;
    *(float4*)cp = *(float4*)&acc[i][0];
    *(float4*)(cp + 4) = *(float4*)&acc[i][4];
  }
}

extern "C" void kernel_launch(void* const* d_in, const int* in_sizes, int n_in,
                              void* d_out, int out_size, void* d_ws, size_t ws_size,
                              hipStream_t stream) {
  const float* x    = (const float*)d_in[0];
  const float* adj  = (const float*)d_in[1];
  const float* mask = (const float*)d_in[2];
  const float* W1   = (const float*)d_in[3];
  const float* b1   = (const float*)d_in[4];
  const float* Watt = (const float*)d_in[5];
  const float* batt = (const float*)d_in[6];
  const float* W2   = (const float*)d_in[7];
  const float* b2   = (const float*)d_in[8];
  float* out = (float*)d_out;

  const long long NN2  = (long long)NN * NN;
  const long long BIG  = (long long)NB * NN2;
  const long long CSTR = (long long)MPAD * NN;
  const long long CTOT = (long long)NB * CSTR;
  const long long M2   = (long long)MPAD * MPAD;
  const long long M2T  = (long long)NB * M2;

  // ---- workspace ----
  float* ws = (float*)d_ws;
  long long off = 0;
  ushort_t* StcH = (ushort_t*)(ws + off); off += CTOT / 2;
  ushort_t* StcL = (ushort_t*)(ws + off); off += CTOT / 2;
  float* TcF  = ws + off; off += CTOT;
  float* A2cF = ws + off; off += M2T;                       // also hosts AdjH early
  ushort_t* A2cH = (ushort_t*)(ws + off); off += M2T / 2;
  ushort_t* A2cL = (ushort_t*)(ws + off); off += M2T / 2;
  float* xa   = ws + off; off += (long long)NROWS * HH;
  float* x2c  = ws + off; off += (long long)MC * HH;
  float* x3c  = ws + off; off += (long long)MC * HH;
  float* diag   = ws + off; off += NROWS;
  float* dgcn   = ws + off; off += NROWS;
  float* dnorm  = ws + off; off += NROWS;
  float* rz     = ws + off; off += NROWS;
  float* wv     = ws + off; off += NROWS;
  float* alphav = ws + off; off += (long long)NB * NN;
  float* colwv  = ws + off; off += NROWS;
  float* scalev = ws + off; off += NROWS;
  int* keepidx  = (int*)(ws + off); off += NB * MPAD;
  float* partm  = ws + off; off += NB * 16 * FF;            // mean partials

  // AdjH aliases A2cF..A2cL (16.8M ushort-pairs fit in 21.2M floats); dead after L0-G1
  ushort_t* AdjH = (ushort_t*)A2cF;

  // phase-local aliases in TcF
  float* u1 = TcF;
  float* u2 = TcF + (long long)NROWS * HH;
  ushort_t* y1Th = (ushort_t*)(TcF + 2ll * NROWS * HH);
  ushort_t* y1Tl = y1Th + (long long)NROWS * HH;
  ushort_t* TcH = (ushort_t*)TcF;
  ushort_t* TcL = TcH + CTOT;
  ushort_t* xT1h = (ushort_t*)TcF;
  ushort_t* xT1l = xT1h + (long long)NROWS * HH;
  ushort_t* Tc2H = (ushort_t*)TcF;
  ushort_t* Tc2L = Tc2H + M2T;
  ushort_t* x2Th = (ushort_t*)TcF;
  ushort_t* x2Tl = x2Th + (long long)MC * HH;
  float* u1f = TcF;
  float* u2f = TcF + (long long)MC * FF;
  ushort_t* y2Th = (ushort_t*)(TcF + 2ll * MC * FF);
  ushort_t* y2Tl = y2Th + (long long)MC * FF;

  // ================= GCN1 (full space) =================
  rowstats_k<<<NROWS / 4, 256, 0, stream>>>(adj, diag, dgcn, dnorm, rz, NN);
  cvtadjh_k<<<(int)(BIG / 4 / 256), 256, 0, stream>>>(adj, AdjH);
  gemm_k<<<dim3(1, NROWS / 128, 1), 256, 0, stream>>>(x, W1, u1, NROWS, HH, FF, 0, 0, 0);
  cvt_xT_k<<<dim3(NN / 32, HH / 32, NB), 256, 0, stream>>>(u1, dgcn, y1Th, y1Tl, NN, HH);
  mgemm_k<0, 1, 0, 0, 0><<<1 * (NN / 128) * NB, 256, 0, stream>>>(
      AdjH, 0, 0, y1Th, y1Tl, 0, u2, 0, 0,
      NN, HH, NN, NN2, (long long)HH * NN, (long long)NN * HH, 1);
  epi_k<<<(NROWS * HH) / 256, 256, 0, stream>>>(u2, u1, dgcn, diag, b1, mask, xa);
  pmean_k<<<dim3(16, NB), HH, 0, stream>>>(xa, partm, NN, HH, 128);
  fmean_k<<<NB, HH, 0, stream>>>(partm, 16, HH, 0.f, 0, out, 0);

  // ================= coarsen layer 0 =================
  wvec_k<<<NROWS / 4, 256, 0, stream>>>(xa, Watt, batt, dnorm, wv);
  alpha_k<<<NROWS / 4, 256, 0, stream>>>(adj, wv, dnorm, rz, alphav, NN);
  topkeep_k<<<NB, 1024, 0, stream>>>(alphav, dnorm, rz, colwv, keepidx);
  scale_k<<<NROWS / 4, 256, 0, stream>>>(adj, colwv, dnorm, rz, scalev, NN);
  writeStc_k<<<(int)(CTOT / 4 / 256), 256, 0, stream>>>(adj, scalev, colwv, keepidx, StcH, StcL);
  // G1: tmp^T = S^T @ adj  (B = AdjH, exact bf16, pure GLDS)
  mgemm_k<1, 0, 0, 0, 1><<<(NN / 128) * (MPAD / 128) * NB, 256, 0, stream>>>(
      StcH, StcL, 0, AdjH, 0, 0, 0, TcH, TcL,
      MPAD, NN, NN, CSTR, NN2, CSTR, NN / 128);
  // G2: A2c = S^T @ tmp (quant + splits)  — overwrites AdjH region (dead now)
  mgemm_k<1, 1, 0, 0, 5><<<(MPAD / 128) * (MPAD / 128) * NB, 256, 0, stream>>>(
      StcH, StcL, 0, TcH, TcL, 0, A2cF, A2cH, A2cL,
      MPAD, MPAD, NN, CSTR, CSTR, M2, MPAD / 128);
  // G3: x2c = S^T @ x1
  cvt_xT_k<<<dim3(NN / 32, HH / 32, NB), 256, 0, stream>>>(xa, 0, xT1h, xT1l, NN, HH);
  mgemm_k<1, 1, 0, 0, 0><<<1 * (MPAD / 128) * NB, 256, 0, stream>>>(
      StcH, StcL, 0, xT1h, xT1l, 0, x2c, 0, 0,
      MPAD, HH, NN, CSTR, (long long)HH * NN, (long long)MPAD * HH, 1);

  // ================= coarsen layer 1 (all compact) =================
  rowstats_k<<<MC / 4, 256, 0, stream>>>(A2cF, diag, dgcn, dnorm, rz, MPAD);
  wvec_k<<<MC / 4, 256, 0, stream>>>(x2c, Watt, batt, dnorm, wv);
  alpha_k<<<MC / 4, 256, 0, stream>>>(A2cF, wv, dnorm, rz, alphav, MPAD);
  padfill_k<<<((NN - MPAD) * NB) / 256, 256, 0, stream>>>(alphav);
  topcolw_k<<<NB, 1024, 0, stream>>>(alphav, dnorm, colwv);
  scale_k<<<MC / 4, 256, 0, stream>>>(A2cF, colwv, dnorm, rz, scalev, MPAD);
  writeS2c_k<<<(int)(M2T / 4 / 256), 256, 0, stream>>>(A2cF, scalev, colwv, StcH, StcL);
  // G1': tmp2^T = S2^T @ A2c
  mgemm_k<1, 1, 0, 0, 1><<<(MPAD / 128) * (MPAD / 128) * NB, 256, 0, stream>>>(
      StcH, StcL, 0, A2cH, A2cL, 0, 0, Tc2H, Tc2L,
      MPAD, MPAD, MPAD, M2, M2, M2, MPAD / 128);
  // G2': A3c = S2^T @ tmp2 (quant + splits)
  mgemm_k<1, 1, 0, 0, 5><<<(MPAD / 128) * (MPAD / 128) * NB, 256, 0, stream>>>(
      StcH, StcL, 0, Tc2H, Tc2L, 0, A2cF, A2cH, A2cL,
      MPAD, MPAD, MPAD, M2, M2, M2, MPAD / 128);
  // G3': x3c = S2^T @ x2c
  cvt_xT_k<<<dim3(MPAD / 32, HH / 32, NB), 256, 0, stream>>>(x2c, 0, x2Th, x2Tl, MPAD, HH);
  mgemm_k<1, 1, 0, 0, 0><<<1 * (MPAD / 128) * NB, 256, 0, stream>>>(
      StcH, StcL, 0, x2Th, x2Tl, 0, x3c, 0, 0,
      MPAD, HH, MPAD, M2, (long long)HH * MPAD, (long long)MPAD * HH, 1);

  // ================= final GCN (compact) =================
  rowstats_k<<<MC / 4, 256, 0, stream>>>(A2cF, diag, dgcn, dnorm, rz, MPAD);
  gemm_k<<<dim3(FF / 128, MPAD / 128, NB), 256, 0, stream>>>(
      x3c, W2, u1f, MPAD, FF, HH, (long long)MPAD * HH, 0, (long long)MPAD * FF);
  cvt_xT_k<<<dim3(MPAD / 32, FF / 32, NB), 256, 0, stream>>>(u1f, dgcn, y2Th, y2Tl, MPAD, FF);
  mgemm_k<1, 1, 0, 0, 0><<<(FF / 128) * (MPAD / 128) * NB, 256, 0, stream>>>(
      A2cH, A2cL, 0, y2Th, y2Tl, 0, u2f, 0, 0,
      MPAD, FF, MPAD, M2, (long long)FF * MPAD, (long long)MPAD * FF, FF / 128);
  epic_k<<<(MC * FF) / 256, 256, 0, stream>>>(u2f, u1f, dgcn, diag, b2, mask, keepidx);
  pmean_k<<<dim3(9, NB), FF, 0, stream>>>(u2f, partm, MPAD, FF, 128);
  fmean_k<<<NB, FF, 0, stream>>>(partm, 9, FF, (float)(NN - MPAD) / NN, b2, out, HH);
}

// Round 8
// 1320.153 us; speedup vs baseline: 5.9501x; 1.0352x over previous
//
#include <hip/hip_runtime.h>
#include <math.h>

#define NN 2048
#define NB 8
#define FF 256
#define HH 128
#define KSEL 1025
#define NROWS (NB*NN)
#define MPAD 1152
#define MC (MPAD*NB)

typedef unsigned short ushort_t;
typedef __attribute__((ext_vector_type(8))) short short8;
typedef __attribute__((ext_vector_type(4))) float f32x4;

__device__ inline ushort_t f2bf(float f) {
  unsigned u = __float_as_uint(f);
  unsigned r = (u + 0x7FFFu + ((u >> 16) & 1u)) >> 16;
  return (ushort_t)r;
}
__device__ inline float bf2f(ushort_t u) {
  unsigned x = ((unsigned)u) << 16;
  return __uint_as_float(x);
}

#define GLDS16(g, l) __builtin_amdgcn_global_load_lds( \
    (const __attribute__((address_space(1))) unsigned int*)(g), \
    (__attribute__((address_space(3))) unsigned int*)(l), 16, 0, 0)

// ---------- row stats + derive fused; optional fused adj->bf16 conversion ----------
__global__ __launch_bounds__(256) void rowstats_k(const float* __restrict__ A,
                                                  ushort_t* __restrict__ H,
                                                  float* __restrict__ diag,
                                                  float* __restrict__ dgcn,
                                                  float* __restrict__ dnorm,
                                                  float* __restrict__ rz, int R) {
  int gw = (blockIdx.x * 256 + threadIdx.x) >> 6;
  int lane = threadIdx.x & 63;
  int b = gw / R, i = gw - b * R;
  const float4* row = (const float4*)(A + (long long)gw * R);
  int R4 = R >> 2;
  float s = 0.f;
  for (int j = lane; j < R4; j += 64) {
    float4 v = row[j];
    s += v.x + v.y + v.z + v.w;
    if (H) {
      ushort_t h0 = f2bf(v.x), h1 = f2bf(v.y), h2 = f2bf(v.z), h3 = f2bf(v.w);
      *(uint2*)&H[(long long)gw * R + j * 4] =
          make_uint2((unsigned)h0 | ((unsigned)h1 << 16), (unsigned)h2 | ((unsigned)h3 << 16));
    }
  }
  for (int off = 32; off > 0; off >>= 1) s += __shfl_down(s, off);
  if (lane == 0) {
    float dg = A[(long long)gw * R + i];
    diag[gw] = dg;
    dgcn[gw]  = rsqrtf(fmaxf(s - dg + 1.f, 1.f));
    dnorm[gw] = rsqrtf(fmaxf(s + 1.f, 1.f));
    rz[gw]    = s > 0.f ? 1.f : 0.f;
  }
}

__global__ __launch_bounds__(256) void wvec_k(const float* __restrict__ x,
                                              const float* __restrict__ Watt,
                                              const float* __restrict__ batt,
                                              const float* __restrict__ dnorm,
                                              float* __restrict__ w) {
  int gw = (blockIdx.x * 256 + threadIdx.x) >> 6;
  int lane = threadIdx.x & 63;
  const float* r = x + (long long)gw * HH;
  float s = r[lane] * Watt[lane] + r[lane + 64] * Watt[lane + 64];
  for (int off = 32; off > 0; off >>= 1) s += __shfl_down(s, off);
  if (lane == 0) w[gw] = dnorm[gw] * (s + batt[0]);
}

// ---------- alpha = sigmoid((rz*dnorm*((A+I)@w))^2); out stride NN ----------
__global__ __launch_bounds__(256) void alpha_k(const float* __restrict__ A,
                                               const float* __restrict__ w,
                                               const float* __restrict__ dnorm,
                                               const float* __restrict__ rz,
                                               float* __restrict__ alpha, int R) {
  int gw = (blockIdx.x * 256 + threadIdx.x) >> 6;
  int lane = threadIdx.x & 63;
  int b = gw / R, i = gw - b * R;
  const float4* row = (const float4*)(A + (long long)gw * R);
  const float4* wb4 = (const float4*)(w + (long long)b * R);
  int R4 = R >> 2;
  float s = 0.f;
  for (int j = lane; j < R4; j += 64) {
    float4 a = row[j], ww = wb4[j];
    s += a.x * ww.x + a.y * ww.y + a.z * ww.z + a.w * ww.w;
  }
  for (int off = 32; off > 0; off >>= 1) s += __shfl_down(s, off);
  if (lane == 0) {
    float aa = rz[gw] * dnorm[gw] * (s + w[(long long)b * R + i]);
    aa = aa * aa;
    alpha[(long long)b * NN + i] = 1.f / (1.f + expf(-aa));
  }
}

__global__ void padfill_k(float* __restrict__ alpha) {
  int idx = blockIdx.x * 256 + threadIdx.x;
  int b = idx / (NN - MPAD), j = idx - b * (NN - MPAD);
  alpha[b * NN + MPAD + j] = 0.5f;
}

// ---------- exact k-th largest via 4-round radix select (alpha > 0, uint order = float order) ----------
// L0 variant: + colw + keep list (ballot scan)
__global__ __launch_bounds__(1024) void topkeep_k(const float* __restrict__ alpha,
                                                  const float* __restrict__ dnorm,
                                                  const float* __restrict__ rz,
                                                  float* __restrict__ colw,
                                                  int* __restrict__ keepidx) {
  __shared__ unsigned vals[NN];
  __shared__ int hist[256];
  __shared__ int wsum[32];
  __shared__ unsigned selp_s;
  __shared__ int selr_s;
  int b = blockIdx.x, t = threadIdx.x;
  vals[t] = __float_as_uint(alpha[b * NN + t]);
  vals[t + 1024] = __float_as_uint(alpha[b * NN + t + 1024]);
  if (t == 0) { selp_s = 0u; selr_s = KSEL; }
  __syncthreads();
  for (int shift = 24; shift >= 0; shift -= 8) {
    if (t < 256) hist[t] = 0;
    __syncthreads();
    unsigned pre = selp_s; int rank = selr_s;
    unsigned hm = (shift == 24) ? 0u : (0xFFFFFFFFu << (shift + 8));
    for (int e = t; e < NN; e += 1024) {
      unsigned v = vals[e];
      if ((v & hm) == (pre & hm)) atomicAdd(&hist[(v >> shift) & 255], 1);
    }
    __syncthreads();
    for (int off2 = 1; off2 < 256; off2 <<= 1) {
      int v = 0;
      if (t < 256 - off2) v = hist[t + off2];
      __syncthreads();
      if (t < 256 - off2) hist[t] += v;
      __syncthreads();
    }
    if (t < 256) {
      int cge = hist[t];
      int cgt = (t == 255) ? 0 : hist[t + 1];
      if (cge >= rank && cgt < rank) {
        selp_s = pre | ((unsigned)t << shift);
        selr_s = rank - cgt;
      }
    }
    __syncthreads();
  }
  float cu = __uint_as_float(selp_s);
  float a0 = __uint_as_float(vals[t]);
  float a1 = __uint_as_float(vals[t + 1024]);
  float c0 = dnorm[b * NN + t]        * fmaxf(a0 + 1e-7f - cu, 0.f);
  float c1 = dnorm[b * NN + t + 1024] * fmaxf(a1 + 1e-7f - cu, 0.f);
  colw[b * NN + t] = c0;
  colw[b * NN + t + 1024] = c1;
  int f0 = (c0 != 0.f && rz[b * NN + t]        != 0.f) ? 1 : 0;
  int f1 = (c1 != 0.f && rz[b * NN + t + 1024] != 0.f) ? 1 : 0;
  int lane = t & 63, wid = t >> 6;
  unsigned long long m0 = __ballot(f0);
  unsigned long long m1 = __ballot(f1);
  if (lane == 0) { wsum[wid] = __popcll(m0); wsum[16 + wid] = __popcll(m1); }
  __syncthreads();
  if (t == 0) { int run = 0; for (int i2 = 0; i2 < 32; i2++) { int v = wsum[i2]; wsum[i2] = run; run += v; } }
  __syncthreads();
  unsigned long long lm = (1ull << lane) - 1ull;
  int p0 = wsum[wid] + __popcll(m0 & lm);
  int p1 = wsum[16 + wid] + __popcll(m1 & lm);
  if (t < MPAD) keepidx[b * MPAD + t] = -1;
  if (t + 1024 < MPAD) keepidx[b * MPAD + t + 1024] = -1;
  __syncthreads();
  if (f0 && p0 < MPAD) keepidx[b * MPAD + p0] = t;
  if (f1 && p1 < MPAD) keepidx[b * MPAD + p1] = t + 1024;
}

// L1 variant: radix select + compact colw only
__global__ __launch_bounds__(1024) void topcolw_k(const float* __restrict__ alpha,
                                                  const float* __restrict__ dnorm,
                                                  float* __restrict__ colw) {
  __shared__ unsigned vals[NN];
  __shared__ int hist[256];
  __shared__ unsigned selp_s;
  __shared__ int selr_s;
  int b = blockIdx.x, t = threadIdx.x;
  vals[t] = __float_as_uint(alpha[b * NN + t]);
  vals[t + 1024] = __float_as_uint(alpha[b * NN + t + 1024]);
  if (t == 0) { selp_s = 0u; selr_s = KSEL; }
  __syncthreads();
  for (int shift = 24; shift >= 0; shift -= 8) {
    if (t < 256) hist[t] = 0;
    __syncthreads();
    unsigned pre = selp_s; int rank = selr_s;
    unsigned hm = (shift == 24) ? 0u : (0xFFFFFFFFu << (shift + 8));
    for (int e = t; e < NN; e += 1024) {
      unsigned v = vals[e];
      if ((v & hm) == (pre & hm)) atomicAdd(&hist[(v >> shift) & 255], 1);
    }
    __syncthreads();
    for (int off2 = 1; off2 < 256; off2 <<= 1) {
      int v = 0;
      if (t < 256 - off2) v = hist[t + off2];
      __syncthreads();
      if (t < 256 - off2) hist[t] += v;
      __syncthreads();
    }
    if (t < 256) {
      int cge = hist[t];
      int cgt = (t == 255) ? 0 : hist[t + 1];
      if (cge >= rank && cgt < rank) {
        selp_s = pre | ((unsigned)t << shift);
        selr_s = rank - cgt;
      }
    }
    __syncthreads();
  }
  float cu = __uint_as_float(selp_s);
  for (int ii = t; ii < MPAD; ii += 1024) {
    float c = fmaxf(__uint_as_float(vals[ii]) + 1e-7f - cu, 0.f);
    colw[b * MPAD + ii] = dnorm[b * MPAD + ii] * c;
  }
}

// ---------- scale_n ----------
__global__ __launch_bounds__(256) void scale_k(const float* __restrict__ A,
                                               const float* __restrict__ colw,
                                               const float* __restrict__ dnorm,
                                               const float* __restrict__ rz,
                                               float* __restrict__ scale, int R) {
  int gw = (blockIdx.x * 256 + threadIdx.x) >> 6;
  int lane = threadIdx.x & 63;
  int b = gw / R, i = gw - b * R;
  const float4* row = (const float4*)(A + (long long)gw * R);
  const float4* cw4 = (const float4*)(colw + (long long)b * R);
  int R4 = R >> 2;
  float s = 0.f;
  for (int j = lane; j < R4; j += 64) {
    float4 a = row[j], c = cw4[j];
    s += a.x * c.x + a.y * c.y + a.z * c.z + a.w * c.w;
  }
  for (int off = 32; off > 0; off >>= 1) s += __shfl_down(s, off);
  if (lane == 0) {
    float rsum = rz[gw] * dnorm[gw] * (s + colw[(long long)b * R + i]);
    scale[gw] = rz[gw] * dnorm[gw] / fmaxf(rsum, 1e-12f);
  }
}

// ---------- Q[n][m] = scale_n * scale_m * adj[n][m], split bf16 ----------
__global__ void writeQ_k(const float* __restrict__ adj, const float* __restrict__ scale,
                         ushort_t* __restrict__ Qh, ushort_t* __restrict__ Ql) {
  long long i4 = ((long long)blockIdx.x * 256 + threadIdx.x) * 4;
  int bn = (int)(i4 >> 11);
  int b = bn >> 11;
  int m = (int)(i4 & (NN - 1));
  float sn = scale[bn];
  float4 sm = *(const float4*)(scale + b * NN + m);
  float4 av = *(const float4*)(adj + i4);
  float v0 = sn * sm.x * av.x;
  float v1 = sn * sm.y * av.y;
  float v2 = sn * sm.z * av.z;
  float v3 = sn * sm.w * av.w;
  ushort_t h0 = f2bf(v0), h1 = f2bf(v1), h2 = f2bf(v2), h3 = f2bf(v3);
  *(uint2*)&Qh[i4] = make_uint2((unsigned)h0 | ((unsigned)h1 << 16),
                                (unsigned)h2 | ((unsigned)h3 << 16));
  ushort_t l0 = f2bf(v0 - bf2f(h0)), l1 = f2bf(v1 - bf2f(h1));
  ushort_t l2 = f2bf(v2 - bf2f(h2)), l3 = f2bf(v3 - bf2f(h3));
  *(uint2*)&Ql[i4] = make_uint2((unsigned)l0 | ((unsigned)l1 << 16),
                                (unsigned)l2 | ((unsigned)l3 << 16));
}

// ---------- Abin[i][n] = adj[keep_i][n] + delta (exact bf16); cwk[i] = colw[keep_i] ----------
__global__ void writeAbin_k(const float* __restrict__ adj, const int* __restrict__ keepidx,
                            const float* __restrict__ colw,
                            ushort_t* __restrict__ Abin, float* __restrict__ cwk) {
  long long g = (long long)blockIdx.x * 256 + threadIdx.x;
  int bi = (int)(g >> 9);
  int n = (int)(g & 511) * 4;
  int b = bi / MPAD;
  long long o = (long long)bi * NN + n;
  int row = keepidx[bi];
  if (row < 0) {
    *(uint2*)&Abin[o] = make_uint2(0, 0);
    if (n == 0) cwk[bi] = 0.f;
    return;
  }
  float4 av = *(const float4*)(adj + ((long long)b * NN + row) * NN + n);
  ushort_t h0 = f2bf(av.x + (float)(n     == row));
  ushort_t h1 = f2bf(av.y + (float)(n + 1 == row));
  ushort_t h2 = f2bf(av.z + (float)(n + 2 == row));
  ushort_t h3 = f2bf(av.w + (float)(n + 3 == row));
  *(uint2*)&Abin[o] = make_uint2((unsigned)h0 | ((unsigned)h1 << 16),
                                 (unsigned)h2 | ((unsigned)h3 << 16));
  if (n == 0) cwk[bi] = colw[b * NN + row];
}

// ---------- L1 compact S2^T ----------
__global__ void writeS2c_k(const float* __restrict__ A2c, const float* __restrict__ scale,
                           const float* __restrict__ colw,
                           ushort_t* __restrict__ Sh, ushort_t* __restrict__ Sl) {
  int g = blockIdx.x * 256 + threadIdx.x;
  int bl = g / (MPAD / 4);
  int k = (g - bl * (MPAD / 4)) * 4;
  int b = bl / MPAD, l = bl - b * MPAD;
  long long o = (long long)bl * MPAD + k;
  float cw = colw[b * MPAD + l];
  float4 sc = *(const float4*)(scale + b * MPAD + k);
  float4 av = *(const float4*)(A2c + o);
  float v0 = sc.x * (av.x + (float)(k     == l)) * cw;
  float v1 = sc.y * (av.y + (float)(k + 1 == l)) * cw;
  float v2 = sc.z * (av.z + (float)(k + 2 == l)) * cw;
  float v3 = sc.w * (av.w + (float)(k + 3 == l)) * cw;
  ushort_t h0 = f2bf(v0), h1 = f2bf(v1), h2 = f2bf(v2), h3 = f2bf(v3);
  *(uint2*)&Sh[o] = make_uint2((unsigned)h0 | ((unsigned)h1 << 16),
                               (unsigned)h2 | ((unsigned)h3 << 16));
  ushort_t l0 = f2bf(v0 - bf2f(h0)), l1 = f2bf(v1 - bf2f(h1));
  ushort_t l2 = f2bf(v2 - bf2f(h2)), l3 = f2bf(v3 - bf2f(h3));
  *(uint2*)&Sl[o] = make_uint2((unsigned)l0 | ((unsigned)l1 << 16),
                               (unsigned)l2 | ((unsigned)l3 << 16));
}

// ---------- transpose + split, optional per-row scale ----------
__global__ __launch_bounds__(256) void cvt_xT_k(const float* __restrict__ X,
                                                const float* __restrict__ rsc,
                                                ushort_t* __restrict__ Th, ushort_t* __restrict__ Tl,
                                                int Nn, int Fd) {
  __shared__ float t[32][33];
  int b = blockIdx.z;
  int n0 = blockIdx.x * 32, f0 = blockIdx.y * 32;
  int tx = threadIdx.x & 31, ty = threadIdx.x >> 5;
  const float* Xb = X + ((long long)b * Nn + n0) * Fd + f0;
  for (int r = ty; r < 32; r += 8) {
    float sc = rsc ? rsc[(long long)b * Nn + n0 + r] : 1.f;
    t[r][tx] = sc * Xb[(long long)r * Fd + tx];
  }
  __syncthreads();
  for (int r = ty; r < 32; r += 8) {
    float v = t[tx][r];
    ushort_t h = f2bf(v);
    long long idx = ((long long)b * Fd + f0 + r) * Nn + n0 + tx;
    Th[idx] = h;
    Tl[idx] = f2bf(v - bf2f(h));
  }
}

// ============ MFMA split-bf16 GEMM, batch->XCD swizzled ============
// EPI: 0 fp32; 1 split store; 5 quant+splits; 6 row-scale fp32 (cwv[row]*v);
//      7 cwv[row]*cwv[col]*v -> floor-quant fp32 + splits.
template<int SA, int SB, int EPI>
__global__ __launch_bounds__(256) void mgemm_k(
    const ushort_t* __restrict__ Ah, const ushort_t* __restrict__ Al,
    const ushort_t* __restrict__ Bh, const ushort_t* __restrict__ Bl,
    float* __restrict__ Co, ushort_t* __restrict__ Toh, ushort_t* __restrict__ Tol,
    int M, int Ncol, int K, long long sA, long long sB, long long sC,
    const float* __restrict__ cwv, int gx) {
  __shared__ ushort_t Ahs[128 * 32];
  __shared__ ushort_t Bhs[128 * 32];
  __shared__ ushort_t Als[SA ? 128 * 32 : 64];
  __shared__ ushort_t Bls[SB ? 128 * 32 : 64];

  int tid = threadIdx.x;
  int id = blockIdx.x;
  long long bz = id & 7;
  int t0 = id >> 3;
  int tn = t0 % gx, tm = t0 / gx;
  int n0 = tn * 128, m0 = tm * 128;
  const ushort_t* Ahb = Ah + bz * sA;
  const ushort_t* Alb = SA ? (Al + bz * sA) : Ah;
  const ushort_t* Bhb = Bh + bz * sB;
  const ushort_t* Blb = SB ? (Bl + bz * sB) : Bh;

  int sr = tid >> 2;
  int sc = (tid & 3) * 8;
  int lane = tid & 63, w = tid >> 6;
  int wm = (w >> 1) * 64, wn = (w & 1) * 64;
  int fr = lane & 15;
  int fo = (lane >> 4) * 8;
  int q = lane >> 4;

  f32x4 acc[4][4];
  f32x4 zz = {0.f, 0.f, 0.f, 0.f};
#pragma unroll
  for (int i = 0; i < 4; i++)
#pragma unroll
    for (int j = 0; j < 4; j++) acc[i][j] = zz;

  for (int k0 = 0; k0 < K; k0 += 32) {
    __syncthreads();
#pragma unroll
    for (int r = 0; r < 128; r += 64) {
      GLDS16(Ahb + (long long)(m0 + sr + r) * K + k0 + sc, &Ahs[(r + sr) * 32 + sc]);
      if constexpr (SA) {
        GLDS16(Alb + (long long)(m0 + sr + r) * K + k0 + sc, &Als[(r + sr) * 32 + sc]);
      }
    }
#pragma unroll
    for (int r = 0; r < 128; r += 64) {
      GLDS16(Bhb + (long long)(n0 + sr + r) * K + k0 + sc, &Bhs[(r + sr) * 32 + sc]);
      if constexpr (SB) {
        GLDS16(Blb + (long long)(n0 + sr + r) * K + k0 + sc, &Bls[(r + sr) * 32 + sc]);
      }
    }
    __syncthreads();

    short8 ah[4], al[4], bh[4], bl[4];
#pragma unroll
    for (int i = 0; i < 4; i++) {
      ah[i] = *(const short8*)&Ahs[(wm + i * 16 + fr) * 32 + fo];
      if constexpr (SA) al[i] = *(const short8*)&Als[(wm + i * 16 + fr) * 32 + fo];
    }
#pragma unroll
    for (int j = 0; j < 4; j++) {
      bh[j] = *(const short8*)&Bhs[(wn + j * 16 + fr) * 32 + fo];
      if constexpr (SB) bl[j] = *(const short8*)&Bls[(wn + j * 16 + fr) * 32 + fo];
    }
#pragma unroll
    for (int i = 0; i < 4; i++)
#pragma unroll
      for (int j = 0; j < 4; j++) {
        acc[i][j] = __builtin_amdgcn_mfma_f32_16x16x32_bf16(ah[i], bh[j], acc[i][j], 0, 0, 0);
        if constexpr (SB)
          acc[i][j] = __builtin_amdgcn_mfma_f32_16x16x32_bf16(ah[i], bl[j], acc[i][j], 0, 0, 0);
        if constexpr (SA)
          acc[i][j] = __builtin_amdgcn_mfma_f32_16x16x32_bf16(al[i], bh[j], acc[i][j], 0, 0, 0);
      }
  }

#pragma unroll
  for (int i = 0; i < 4; i++)
#pragma unroll
    for (int j = 0; j < 4; j++)
#pragma unroll
      for (int r = 0; r < 4; r++) {
        float v = acc[i][j][r];
        int row = m0 + wm + i * 16 + q * 4 + r;
        int col = n0 + wn + j * 16 + fr;
        long long idx = bz * sC + (long long)row * Ncol + col;
        if constexpr (EPI == 0) {
          Co[idx] = v;
        } else if constexpr (EPI == 1) {
          ushort_t h = f2bf(v);
          Toh[idx] = h;
          Tol[idx] = f2bf(v - bf2f(h));
        } else if constexpr (EPI == 5) {
          float vq = floorf(v * 10000.f) / 10000.f;
          Co[idx] = vq;
          ushort_t h = f2bf(vq);
          Toh[idx] = h;
          Tol[idx] = f2bf(vq - bf2f(h));
        } else if constexpr (EPI == 6) {
          Co[idx] = cwv[bz * MPAD + row] * v;
        } else {  // EPI == 7
          float vs = cwv[bz * MPAD + row] * cwv[bz * MPAD + col] * v;
          float vq = floorf(vs * 10000.f) / 10000.f;
          Co[idx] = vq;
          ushort_t h = f2bf(vq);
          Toh[idx] = h;
          Tol[idx] = f2bf(vq - bf2f(h));
        }
      }
}

// ---------- GCN1 epilogue ----------
__global__ void epi_k(const float* __restrict__ acc, const float* __restrict__ xw,
                      const float* __restrict__ dgcn, const float* __restrict__ diag,
                      const float* __restrict__ bias, const float* __restrict__ mask,
                      float* __restrict__ outx) {
  long long i = (long long)blockIdx.x * 256 + threadIdx.x;
  int rowi = (int)(i >> 7);
  int f = (int)(i & 127);
  float d = dgcn[rowi];
  float t = d * (acc[i] + (1.f - diag[rowi]) * d * xw[i]) + bias[f];
  t *= mask[rowi];
  outx[i] = fmaxf(t, 0.f);
}

// ---------- final epilogue (compact) ----------
__global__ void epic_k(float* __restrict__ acc, const float* __restrict__ xw,
                       const float* __restrict__ dgcn, const float* __restrict__ diag,
                       const float* __restrict__ bias, const float* __restrict__ mask,
                       const int* __restrict__ kmap) {
  long long i = (long long)blockIdx.x * 256 + threadIdx.x;
  int rowi = (int)(i >> 8);
  int f = (int)(i & 255);
  int b = rowi / MPAD;
  int km = kmap[rowi];
  float mv = (km >= 0) ? mask[b * NN + km] : 1.f;
  float d = dgcn[rowi];
  float t = d * (acc[i] + (1.f - diag[rowi]) * d * xw[i]) + bias[f];
  acc[i] = t * mv;
}

// ---------- two-stage column means ----------
__global__ void pmean_k(const float* __restrict__ X, float* __restrict__ part,
                        int Nn, int Fd, int rpc) {
  int b = blockIdx.y, c = blockIdx.x, f = threadIdx.x;
  const float* p = X + ((long long)b * Nn + (long long)c * rpc) * Fd + f;
  float s = 0.f;
  for (int r = 0; r < rpc; r++) s += p[(long long)r * Fd];
  part[((long long)b * gridDim.x + c) * Fd + f] = s;
}

__global__ void fmean_k(const float* __restrict__ part, int nch, int Fd, float corr,
                        const float* __restrict__ bias, float* __restrict__ out, int outoff) {
  int b = blockIdx.x, f = threadIdx.x;
  float s = 0.f;
  for (int c = 0; c < nch; c++) s += part[((long long)b * nch + c) * Fd + f];
  float cv = bias ? corr * bias[f] : 0.f;
  out[b * (HH + FF) + outoff + f] = s * (1.f / NN) + cv;
}

// ---------- fp32 VALU GEMM (feature matmuls) ----------
__global__ __launch_bounds__(256) void gemm_k(const float* __restrict__ A, const float* __restrict__ B,
                                              float* __restrict__ C, int M, int Nw, int Kk,
                                              long long sA, long long sB, long long sC) {
  __shared__ float As[16][128];
  __shared__ float Bs[16][128];
  int tid = threadIdx.x;
  int n0 = blockIdx.x * 128, m0 = blockIdx.y * 128;
  const float* Ab = A + (long long)blockIdx.z * sA;
  const float* Bb = B + (long long)blockIdx.z * sB;
  float* Cb = C + (long long)blockIdx.z * sC;
  float acc[8][8];
#pragma unroll
  for (int i = 0; i < 8; i++)
#pragma unroll
    for (int j = 0; j < 8; j++) acc[i][j] = 0.f;
  int tx = tid & 15, ty = tid >> 4;

  for (int k0 = 0; k0 < Kk; k0 += 16) {
    {
      int r = tid >> 2, c = (tid & 3) << 2;
#pragma unroll
      for (int rr = 0; rr < 2; rr++) {
        int rrow = r + rr * 64;
        float4 v = *(const float4*)(Ab + (long long)(m0 + rrow) * Kk + k0 + c);
        As[c + 0][rrow] = v.x; As[c + 1][rrow] = v.y;
        As[c + 2][rrow] = v.z; As[c + 3][rrow] = v.w;
      }
    }
    {
      int kk = tid >> 5, cc = (tid & 31) << 2;
#pragma unroll
      for (int k2 = 0; k2 < 2; k2++) {
        float4 v = *(const float4*)(Bb + (long long)(k0 + kk + k2 * 8) * Nw + n0 + cc);
        *(float4*)&Bs[kk + k2 * 8][cc] = v;
      }
    }
    __syncthreads();
#pragma unroll
    for (int kk = 0; kk < 16; kk++) {
      float a[8], bb[8];
      *(float4*)&a[0]  = *(float4*)&As[kk][ty * 8];
      *(float4*)&a[4]  = *(float4*)&As[kk][ty * 8 + 4];
      *(float4*)&bb[0] = *(float4*)&Bs[kk][tx * 8];
      *(float4*)&bb[4] = *(float4*)&Bs[kk][tx * 8 + 4];
#pragma unroll
      for (int i = 0; i < 8; i++)
#pragma unroll
        for (int j = 0; j < 8; j++) acc[i][j] += a[i] * bb[j];
    }
    __syncthreads();
  }
#pragma unroll
  for (int i = 0; i < 8; i++) {
    float* cp = Cb + (long long)(m0 + ty * 8 + i) * Nw + n0 + tx * 8;
    *(float4*)cp = *(float4*)&acc[i][0];
    *(float4*)(cp + 4) = *(float4*)&acc[i][4];
  }
}

extern "C" void kernel_launch(void* const* d_in, const int* in_sizes, int n_in,
                              void* d_out, int out_size, void* d_ws, size_t ws_size,
                              hipStream_t stream) {
  const float* x    = (const float*)d_in[0];
  const float* adj  = (const float*)d_in[1];
  const float* mask = (const float*)d_in[2];
  const float* W1   = (const float*)d_in[3];
  const float* b1   = (const float*)d_in[4];
  const float* Watt = (const float*)d_in[5];
  const float* batt = (const float*)d_in[6];
  const float* W2   = (const float*)d_in[7];
  const float* b2   = (const float*)d_in[8];
  float* out = (float*)d_out;

  const long long NN2  = (long long)NN * NN;
  const long long BIG  = (long long)NB * NN2;
  const long long CSTR = (long long)MPAD * NN;
  const long long CTOT = (long long)NB * CSTR;
  const long long M2   = (long long)MPAD * MPAD;
  const long long M2T  = (long long)NB * M2;

  // ---- workspace (~284 MB; round-2 used 285.8 MB successfully) ----
  float* ws = (float*)d_ws;
  long long off = 0;
  ushort_t* Qh = (ushort_t*)(ws + off); off += BIG / 2;     // Q hi (BIG ushorts); later S2cH/S2cL
  float* A2CR = ws + off; off += M2T * 2;                   // union: AdjH / Ql / A2cF+H+L
  float* TcF  = ws + off; off += CTOT;                      // union: GCN1 scratch / R splits / Tc2 / final scratch
  ushort_t* Abin = (ushort_t*)(ws + off); off += CTOT / 2;  // CTOT ushorts (FIXED: was CTOT/4)
  float* xa   = ws + off; off += (long long)NROWS * HH;
  float* x2c  = ws + off; off += (long long)MC * HH;
  float* x3c  = ws + off; off += (long long)MC * HH;
  float* diag   = ws + off; off += NROWS;
  float* dgcn   = ws + off; off += NROWS;
  float* dnorm  = ws + off; off += NROWS;
  float* rz     = ws + off; off += NROWS;
  float* wv     = ws + off; off += NROWS;
  float* alphav = ws + off; off += (long long)NB * NN;
  float* colwv  = ws + off; off += NROWS;
  float* scalev = ws + off; off += NROWS;
  int* keepidx  = (int*)(ws + off); off += NB * MPAD;
  float* cwk    = ws + off; off += MC;
  float* partm  = ws + off; off += NB * 16 * FF;

  // A2CR union: AdjH (BIG ushorts, GCN1) -> Ql (BIG ushorts, writeQ..G1n) -> A2cF/H/L (G2n..)
  ushort_t* AdjH = (ushort_t*)A2CR;
  ushort_t* Ql   = (ushort_t*)A2CR;
  float* A2cF = A2CR;
  ushort_t* A2cH = (ushort_t*)(A2CR + M2T);
  ushort_t* A2cL = A2cH + M2T;
  // S2c splits live in Qh region (2*M2T ushorts <= BIG ushorts)
  ushort_t* S2cH = Qh;
  ushort_t* S2cL = Qh + M2T;

  // TcF phase aliases
  float* u1 = TcF;
  float* u2 = TcF + (long long)NROWS * HH;
  ushort_t* y1Th = (ushort_t*)(TcF + 2ll * NROWS * HH);
  ushort_t* y1Tl = y1Th + (long long)NROWS * HH;
  ushort_t* Rh = (ushort_t*)TcF;                          // R = Abin*Q splits (CTOT each)
  ushort_t* Rl = Rh + CTOT;
  ushort_t* xT1h = (ushort_t*)TcF;
  ushort_t* xT1l = xT1h + (long long)NROWS * HH;
  ushort_t* Tc2H = (ushort_t*)TcF;
  ushort_t* Tc2L = Tc2H + M2T;
  ushort_t* x2Th = (ushort_t*)TcF;
  ushort_t* x2Tl = x2Th + (long long)MC * HH;
  float* u1f = TcF;
  float* u2f = TcF + (long long)MC * FF;
  ushort_t* y2Th = (ushort_t*)(TcF + 2ll * MC * FF);
  ushort_t* y2Tl = y2Th + (long long)MC * FF;

  // ================= GCN1 (full space) =================
  rowstats_k<<<NROWS / 4, 256, 0, stream>>>(adj, AdjH, diag, dgcn, dnorm, rz, NN);
  gemm_k<<<dim3(1, NROWS / 128, 1), 256, 0, stream>>>(x, W1, u1, NROWS, HH, FF, 0, 0, 0);
  cvt_xT_k<<<dim3(NN / 32, HH / 32, NB), 256, 0, stream>>>(u1, dgcn, y1Th, y1Tl, NN, HH);
  mgemm_k<0, 1, 0><<<1 * (NN / 128) * NB, 256, 0, stream>>>(
      AdjH, 0, y1Th, y1Tl, u2, 0, 0,
      NN, HH, NN, NN2, (long long)HH * NN, (long long)NN * HH, 0, 1);
  epi_k<<<(NROWS * HH) / 256, 256, 0, stream>>>(u2, u1, dgcn, diag, b1, mask, xa);
  pmean_k<<<dim3(16, NB), HH, 0, stream>>>(xa, partm, NN, HH, 128);
  fmean_k<<<NB, HH, 0, stream>>>(partm, 16, HH, 0.f, 0, out, 0);

  // ================= coarsen layer 0 =================
  wvec_k<<<NROWS / 4, 256, 0, stream>>>(xa, Watt, batt, dnorm, wv);
  alpha_k<<<NROWS / 4, 256, 0, stream>>>(adj, wv, dnorm, rz, alphav, NN);
  topkeep_k<<<NB, 1024, 0, stream>>>(alphav, dnorm, rz, colwv, keepidx);
  scale_k<<<NROWS / 4, 256, 0, stream>>>(adj, colwv, dnorm, rz, scalev, NN);
  writeQ_k<<<(int)(BIG / 4 / 256), 256, 0, stream>>>(adj, scalev, Qh, Ql);   // overwrites AdjH (dead)
  writeAbin_k<<<(int)(CTOT / 4 / 256), 256, 0, stream>>>(adj, keepidx, colwv, Abin, cwk);
  // G1n: R = Abin @ Q (A exact, B split -> 2 products), split store
  mgemm_k<0, 1, 1><<<(NN / 128) * (MPAD / 128) * NB, 256, 0, stream>>>(
      Abin, 0, Qh, Ql, 0, Rh, Rl,
      MPAD, NN, NN, CSTR, NN2, CSTR, 0, NN / 128);
  // G2n: A2c = cw*cw*(R @ Abin^T) quantized (A split, B exact -> 2 products)
  mgemm_k<1, 0, 7><<<(MPAD / 128) * (MPAD / 128) * NB, 256, 0, stream>>>(
      Rh, Rl, Abin, 0, A2cF, A2cH, A2cL,
      MPAD, MPAD, NN, CSTR, CSTR, M2, cwk, MPAD / 128);
  // G3n: x2c = cw * (Abin @ (scale*x1)) (A exact, B split -> 2 products)
  cvt_xT_k<<<dim3(NN / 32, HH / 32, NB), 256, 0, stream>>>(xa, scalev, xT1h, xT1l, NN, HH);
  mgemm_k<0, 1, 6><<<1 * (MPAD / 128) * NB, 256, 0, stream>>>(
      Abin, 0, xT1h, xT1l, x2c, 0, 0,
      MPAD, HH, NN, CSTR, (long long)HH * NN, (long long)MPAD * HH, cwk, 1);

  // ================= coarsen layer 1 (all compact) =================
  rowstats_k<<<MC / 4, 256, 0, stream>>>(A2cF, 0, diag, dgcn, dnorm, rz, MPAD);
  wvec_k<<<MC / 4, 256, 0, stream>>>(x2c, Watt, batt, dnorm, wv);
  alpha_k<<<MC / 4, 256, 0, stream>>>(A2cF, wv, dnorm, rz, alphav, MPAD);
  padfill_k<<<((NN - MPAD) * NB) / 256, 256, 0, stream>>>(alphav);
  topcolw_k<<<NB, 1024, 0, stream>>>(alphav, dnorm, colwv);
  scale_k<<<MC / 4, 256, 0, stream>>>(A2cF, colwv, dnorm, rz, scalev, MPAD);
  writeS2c_k<<<(int)(M2T / 4 / 256), 256, 0, stream>>>(A2cF, scalev, colwv, S2cH, S2cL);
  // G1': tmp2^T = S2^T @ A2c
  mgemm_k<1, 1, 1><<<(MPAD / 128) * (MPAD / 128) * NB, 256, 0, stream>>>(
      S2cH, S2cL, A2cH, A2cL, 0, Tc2H, Tc2L,
      MPAD, MPAD, MPAD, M2, M2, M2, 0, MPAD / 128);
  // G2': A3c = S2^T @ tmp2 (quant + splits)
  mgemm_k<1, 1, 5><<<(MPAD / 128) * (MPAD / 128) * NB, 256, 0, stream>>>(
      S2cH, S2cL, Tc2H, Tc2L, A2cF, A2cH, A2cL,
      MPAD, MPAD, MPAD, M2, M2, M2, 0, MPAD / 128);
  // G3': x3c = S2^T @ x2c
  cvt_xT_k<<<dim3(MPAD / 32, HH / 32, NB), 256, 0, stream>>>(x2c, 0, x2Th, x2Tl, MPAD, HH);
  mgemm_k<1, 1, 0><<<1 * (MPAD / 128) * NB, 256, 0, stream>>>(
      S2cH, S2cL, x2Th, x2Tl, x3c, 0, 0,
      MPAD, HH, MPAD, M2, (long long)HH * MPAD, (long long)MPAD * HH, 0, 1);

  // ================= final GCN (compact) =================
  rowstats_k<<<MC / 4, 256, 0, stream>>>(A2cF, 0, diag, dgcn, dnorm, rz, MPAD);
  gemm_k<<<dim3(FF / 128, MPAD / 128, NB), 256, 0, stream>>>(
      x3c, W2, u1f, MPAD, FF, HH, (long long)MPAD * HH, 0, (long long)MPAD * FF);
  cvt_xT_k<<<dim3(MPAD / 32, FF / 32, NB), 256, 0, stream>>>(u1f, dgcn, y2Th, y2Tl, MPAD, FF);
  mgemm_k<1, 1, 0><<<(FF / 128) * (MPAD / 128) * NB, 256, 0, stream>>>(
      A2cH, A2cL, y2Th, y2Tl, u2f, 0, 0,
      MPAD, FF, MPAD, M2, (long long)FF * MPAD, (long long)MPAD * FF, 0, FF / 128);
  epic_k<<<(MC * FF) / 256, 256, 0, stream>>>(u2f, u1f, dgcn, diag, b2, mask, keepidx);
  pmean_k<<<dim3(9, NB), FF, 0, stream>>>(u2f, partm, MPAD, FF, 128);
  fmean_k<<<NB, FF, 0, stream>>>(partm, 9, FF, (float)(NN - MPAD) / NN, b2, out, HH);
}

// Round 9
// 1267.767 us; speedup vs baseline: 6.1959x; 1.0413x over previous
//
#include <hip/hip_runtime.h>
#include <math.h>

#define NN 2048
#define NB 8
#define FF 256
#define HH 128
#define KSEL 1025
#define NROWS (NB*NN)
#define MPAD 1152
#define MC (MPAD*NB)

typedef unsigned short ushort_t;
typedef __attribute__((ext_vector_type(8))) short short8;
typedef __attribute__((ext_vector_type(4))) float f32x4;

__device__ inline ushort_t f2bf(float f) {
  unsigned u = __float_as_uint(f);
  unsigned r = (u + 0x7FFFu + ((u >> 16) & 1u)) >> 16;
  return (ushort_t)r;
}
__device__ inline float bf2f(ushort_t u) {
  unsigned x = ((unsigned)u) << 16;
  return __uint_as_float(x);
}

#define GLDS16(g, l) __builtin_amdgcn_global_load_lds( \
    (const __attribute__((address_space(1))) unsigned int*)(g), \
    (__attribute__((address_space(3))) unsigned int*)(l), 16, 0, 0)

// ---------- row stats + derive fused; optional fused adj->bf16 conversion ----------
__global__ __launch_bounds__(256) void rowstats_k(const float* __restrict__ A,
                                                  ushort_t* __restrict__ H,
                                                  float* __restrict__ diag,
                                                  float* __restrict__ dgcn,
                                                  float* __restrict__ dnorm,
                                                  float* __restrict__ rz, int R) {
  int gw = (blockIdx.x * 256 + threadIdx.x) >> 6;
  int lane = threadIdx.x & 63;
  int b = gw / R, i = gw - b * R;
  const float4* row = (const float4*)(A + (long long)gw * R);
  int R4 = R >> 2;
  float s = 0.f;
  for (int j = lane; j < R4; j += 64) {
    float4 v = row[j];
    s += v.x + v.y + v.z + v.w;
    if (H) {
      ushort_t h0 = f2bf(v.x), h1 = f2bf(v.y), h2 = f2bf(v.z), h3 = f2bf(v.w);
      *(uint2*)&H[(long long)gw * R + j * 4] =
          make_uint2((unsigned)h0 | ((unsigned)h1 << 16), (unsigned)h2 | ((unsigned)h3 << 16));
    }
  }
  for (int off = 32; off > 0; off >>= 1) s += __shfl_down(s, off);
  if (lane == 0) {
    float dg = A[(long long)gw * R + i];
    diag[gw] = dg;
    dgcn[gw]  = rsqrtf(fmaxf(s - dg + 1.f, 1.f));
    dnorm[gw] = rsqrtf(fmaxf(s + 1.f, 1.f));
    rz[gw]    = s > 0.f ? 1.f : 0.f;
  }
}

__global__ __launch_bounds__(256) void wvec_k(const float* __restrict__ x,
                                              const float* __restrict__ Watt,
                                              const float* __restrict__ batt,
                                              const float* __restrict__ dnorm,
                                              float* __restrict__ w) {
  int gw = (blockIdx.x * 256 + threadIdx.x) >> 6;
  int lane = threadIdx.x & 63;
  const float* r = x + (long long)gw * HH;
  float s = r[lane] * Watt[lane] + r[lane + 64] * Watt[lane + 64];
  for (int off = 32; off > 0; off >>= 1) s += __shfl_down(s, off);
  if (lane == 0) w[gw] = dnorm[gw] * (s + batt[0]);
}

// ---------- L0 alpha from binary AdjH (exact select-adds) ----------
__global__ __launch_bounds__(256) void alphaB_k(const ushort_t* __restrict__ H,
                                                const float* __restrict__ w,
                                                const float* __restrict__ dnorm,
                                                const float* __restrict__ rz,
                                                float* __restrict__ alpha) {
  int gw = (blockIdx.x * 256 + threadIdx.x) >> 6;
  int lane = threadIdx.x & 63;
  int b = gw >> 11, i = gw & (NN - 1);
  const uint4* rowH = (const uint4*)(H + (long long)gw * NN);
  const float4* w4 = (const float4*)(w + (long long)b * NN);
  float s = 0.f;
  for (int j = lane; j < NN / 8; j += 64) {
    uint4 av = rowH[j];
    float4 wa = w4[2 * j], wb = w4[2 * j + 1];
    if (av.x & 0xFFFFu) s += wa.x;  if (av.x >> 16) s += wa.y;
    if (av.y & 0xFFFFu) s += wa.z;  if (av.y >> 16) s += wa.w;
    if (av.z & 0xFFFFu) s += wb.x;  if (av.z >> 16) s += wb.y;
    if (av.w & 0xFFFFu) s += wb.z;  if (av.w >> 16) s += wb.w;
  }
  for (int off = 32; off > 0; off >>= 1) s += __shfl_down(s, off);
  if (lane == 0) {
    float aa = rz[gw] * dnorm[gw] * (s + w[(long long)b * NN + i]);
    aa = aa * aa;
    alpha[(long long)b * NN + i] = 1.f / (1.f + expf(-aa));
  }
}

// ---------- L1 alpha (fp32 A) ----------
__global__ __launch_bounds__(256) void alpha_k(const float* __restrict__ A,
                                               const float* __restrict__ w,
                                               const float* __restrict__ dnorm,
                                               const float* __restrict__ rz,
                                               float* __restrict__ alpha, int R) {
  int gw = (blockIdx.x * 256 + threadIdx.x) >> 6;
  int lane = threadIdx.x & 63;
  int b = gw / R, i = gw - b * R;
  const float4* row = (const float4*)(A + (long long)gw * R);
  const float4* wb4 = (const float4*)(w + (long long)b * R);
  int R4 = R >> 2;
  float s = 0.f;
  for (int j = lane; j < R4; j += 64) {
    float4 a = row[j], ww = wb4[j];
    s += a.x * ww.x + a.y * ww.y + a.z * ww.z + a.w * ww.w;
  }
  for (int off = 32; off > 0; off >>= 1) s += __shfl_down(s, off);
  if (lane == 0) {
    float aa = rz[gw] * dnorm[gw] * (s + w[(long long)b * R + i]);
    aa = aa * aa;
    alpha[(long long)b * NN + i] = 1.f / (1.f + expf(-aa));
  }
}

__global__ void padfill_k(float* __restrict__ alpha) {
  int idx = blockIdx.x * 256 + threadIdx.x;
  int b = idx / (NN - MPAD), j = idx - b * (NN - MPAD);
  alpha[b * NN + MPAD + j] = 0.5f;
}

// ---------- exact k-th largest via 4-round radix select ----------
__global__ __launch_bounds__(1024) void topkeep_k(const float* __restrict__ alpha,
                                                  const float* __restrict__ dnorm,
                                                  const float* __restrict__ rz,
                                                  float* __restrict__ colw,
                                                  int* __restrict__ keepidx) {
  __shared__ unsigned vals[NN];
  __shared__ int hist[256];
  __shared__ int wsum[32];
  __shared__ unsigned selp_s;
  __shared__ int selr_s;
  int b = blockIdx.x, t = threadIdx.x;
  vals[t] = __float_as_uint(alpha[b * NN + t]);
  vals[t + 1024] = __float_as_uint(alpha[b * NN + t + 1024]);
  if (t == 0) { selp_s = 0u; selr_s = KSEL; }
  __syncthreads();
  for (int shift = 24; shift >= 0; shift -= 8) {
    if (t < 256) hist[t] = 0;
    __syncthreads();
    unsigned pre = selp_s; int rank = selr_s;
    unsigned hm = (shift == 24) ? 0u : (0xFFFFFFFFu << (shift + 8));
    for (int e = t; e < NN; e += 1024) {
      unsigned v = vals[e];
      if ((v & hm) == (pre & hm)) atomicAdd(&hist[(v >> shift) & 255], 1);
    }
    __syncthreads();
    for (int off2 = 1; off2 < 256; off2 <<= 1) {
      int v = 0;
      if (t < 256 - off2) v = hist[t + off2];
      __syncthreads();
      if (t < 256 - off2) hist[t] += v;
      __syncthreads();
    }
    if (t < 256) {
      int cge = hist[t];
      int cgt = (t == 255) ? 0 : hist[t + 1];
      if (cge >= rank && cgt < rank) {
        selp_s = pre | ((unsigned)t << shift);
        selr_s = rank - cgt;
      }
    }
    __syncthreads();
  }
  float cu = __uint_as_float(selp_s);
  float a0 = __uint_as_float(vals[t]);
  float a1 = __uint_as_float(vals[t + 1024]);
  float c0 = dnorm[b * NN + t]        * fmaxf(a0 + 1e-7f - cu, 0.f);
  float c1 = dnorm[b * NN + t + 1024] * fmaxf(a1 + 1e-7f - cu, 0.f);
  colw[b * NN + t] = c0;
  colw[b * NN + t + 1024] = c1;
  int f0 = (c0 != 0.f && rz[b * NN + t]        != 0.f) ? 1 : 0;
  int f1 = (c1 != 0.f && rz[b * NN + t + 1024] != 0.f) ? 1 : 0;
  int lane = t & 63, wid = t >> 6;
  unsigned long long m0 = __ballot(f0);
  unsigned long long m1 = __ballot(f1);
  if (lane == 0) { wsum[wid] = __popcll(m0); wsum[16 + wid] = __popcll(m1); }
  __syncthreads();
  if (t == 0) { int run = 0; for (int i2 = 0; i2 < 32; i2++) { int v = wsum[i2]; wsum[i2] = run; run += v; } }
  __syncthreads();
  unsigned long long lm = (1ull << lane) - 1ull;
  int p0 = wsum[wid] + __popcll(m0 & lm);
  int p1 = wsum[16 + wid] + __popcll(m1 & lm);
  if (t < MPAD) keepidx[b * MPAD + t] = -1;
  if (t + 1024 < MPAD) keepidx[b * MPAD + t + 1024] = -1;
  __syncthreads();
  if (f0 && p0 < MPAD) keepidx[b * MPAD + p0] = t;
  if (f1 && p1 < MPAD) keepidx[b * MPAD + p1] = t + 1024;
}

// L1 variant: radix select + compact colw only
__global__ __launch_bounds__(1024) void topcolw_k(const float* __restrict__ alpha,
                                                  const float* __restrict__ dnorm,
                                                  float* __restrict__ colw) {
  __shared__ unsigned vals[NN];
  __shared__ int hist[256];
  __shared__ unsigned selp_s;
  __shared__ int selr_s;
  int b = blockIdx.x, t = threadIdx.x;
  vals[t] = __float_as_uint(alpha[b * NN + t]);
  vals[t + 1024] = __float_as_uint(alpha[b * NN + t + 1024]);
  if (t == 0) { selp_s = 0u; selr_s = KSEL; }
  __syncthreads();
  for (int shift = 24; shift >= 0; shift -= 8) {
    if (t < 256) hist[t] = 0;
    __syncthreads();
    unsigned pre = selp_s; int rank = selr_s;
    unsigned hm = (shift == 24) ? 0u : (0xFFFFFFFFu << (shift + 8));
    for (int e = t; e < NN; e += 1024) {
      unsigned v = vals[e];
      if ((v & hm) == (pre & hm)) atomicAdd(&hist[(v >> shift) & 255], 1);
    }
    __syncthreads();
    for (int off2 = 1; off2 < 256; off2 <<= 1) {
      int v = 0;
      if (t < 256 - off2) v = hist[t + off2];
      __syncthreads();
      if (t < 256 - off2) hist[t] += v;
      __syncthreads();
    }
    if (t < 256) {
      int cge = hist[t];
      int cgt = (t == 255) ? 0 : hist[t + 1];
      if (cge >= rank && cgt < rank) {
        selp_s = pre | ((unsigned)t << shift);
        selr_s = rank - cgt;
      }
    }
    __syncthreads();
  }
  float cu = __uint_as_float(selp_s);
  for (int ii = t; ii < MPAD; ii += 1024) {
    float c = fmaxf(__uint_as_float(vals[ii]) + 1e-7f - cu, 0.f);
    colw[b * MPAD + ii] = dnorm[b * MPAD + ii] * c;
  }
}

// ---------- L0 scale from binary AdjH + scale bf16-splits ----------
__global__ __launch_bounds__(256) void scaleB_k(const ushort_t* __restrict__ H,
                                                const float* __restrict__ colw,
                                                const float* __restrict__ dnorm,
                                                const float* __restrict__ rz,
                                                float* __restrict__ scale,
                                                ushort_t* __restrict__ sH,
                                                ushort_t* __restrict__ sL) {
  int gw = (blockIdx.x * 256 + threadIdx.x) >> 6;
  int lane = threadIdx.x & 63;
  int b = gw >> 11, i = gw & (NN - 1);
  const uint4* rowH = (const uint4*)(H + (long long)gw * NN);
  const float4* c4 = (const float4*)(colw + (long long)b * NN);
  float s = 0.f;
  for (int j = lane; j < NN / 8; j += 64) {
    uint4 av = rowH[j];
    float4 ca = c4[2 * j], cb = c4[2 * j + 1];
    if (av.x & 0xFFFFu) s += ca.x;  if (av.x >> 16) s += ca.y;
    if (av.y & 0xFFFFu) s += ca.z;  if (av.y >> 16) s += ca.w;
    if (av.z & 0xFFFFu) s += cb.x;  if (av.z >> 16) s += cb.y;
    if (av.w & 0xFFFFu) s += cb.z;  if (av.w >> 16) s += cb.w;
  }
  for (int off = 32; off > 0; off >>= 1) s += __shfl_down(s, off);
  if (lane == 0) {
    float rsum = rz[gw] * dnorm[gw] * (s + colw[(long long)b * NN + i]);
    float sc = rz[gw] * dnorm[gw] / fmaxf(rsum, 1e-12f);
    scale[gw] = sc;
    ushort_t h = f2bf(sc);
    sH[gw] = h;
    sL[gw] = f2bf(sc - bf2f(h));
  }
}

// ---------- L1 scale (fp32 A) ----------
__global__ __launch_bounds__(256) void scale_k(const float* __restrict__ A,
                                               const float* __restrict__ colw,
                                               const float* __restrict__ dnorm,
                                               const float* __restrict__ rz,
                                               float* __restrict__ scale, int R) {
  int gw = (blockIdx.x * 256 + threadIdx.x) >> 6;
  int lane = threadIdx.x & 63;
  int b = gw / R, i = gw - b * R;
  const float4* row = (const float4*)(A + (long long)gw * R);
  const float4* cw4 = (const float4*)(colw + (long long)b * R);
  int R4 = R >> 2;
  float s = 0.f;
  for (int j = lane; j < R4; j += 64) {
    float4 a = row[j], c = cw4[j];
    s += a.x * c.x + a.y * c.y + a.z * c.z + a.w * c.w;
  }
  for (int off = 32; off > 0; off >>= 1) s += __shfl_down(s, off);
  if (lane == 0) {
    float rsum = rz[gw] * dnorm[gw] * (s + colw[(long long)b * R + i]);
    scale[gw] = rz[gw] * dnorm[gw] / fmaxf(rsum, 1e-12f);
  }
}

// ---------- Abin[i][n] = AdjH[keep_i][n] + delta (exact bf16); cwk[i] = colw[keep_i] ----------
__global__ void writeAbin_k(const ushort_t* __restrict__ H, const int* __restrict__ keepidx,
                            const float* __restrict__ colw,
                            ushort_t* __restrict__ Abin, float* __restrict__ cwk) {
  long long g = (long long)blockIdx.x * 256 + threadIdx.x;
  int bi = (int)(g >> 9);
  int n = (int)(g & 511) * 4;
  int b = bi / MPAD;
  long long o = (long long)bi * NN + n;
  int row = keepidx[bi];
  if (row < 0) {
    *(uint2*)&Abin[o] = make_uint2(0, 0);
    if (n == 0) cwk[bi] = 0.f;
    return;
  }
  uint2 av = *(const uint2*)(H + ((long long)b * NN + row) * NN + n);
  ushort_t e0 = (ushort_t)(av.x & 0xFFFFu), e1 = (ushort_t)(av.x >> 16);
  ushort_t e2 = (ushort_t)(av.y & 0xFFFFu), e3 = (ushort_t)(av.y >> 16);
  if (n     == row) e0 = f2bf(bf2f(e0) + 1.f);
  if (n + 1 == row) e1 = f2bf(bf2f(e1) + 1.f);
  if (n + 2 == row) e2 = f2bf(bf2f(e2) + 1.f);
  if (n + 3 == row) e3 = f2bf(bf2f(e3) + 1.f);
  *(uint2*)&Abin[o] = make_uint2((unsigned)e0 | ((unsigned)e1 << 16),
                                 (unsigned)e2 | ((unsigned)e3 << 16));
  if (n == 0) cwk[bi] = colw[b * NN + row];
}

// ---------- L1 compact S2^T ----------
__global__ void writeS2c_k(const float* __restrict__ A2c, const float* __restrict__ scale,
                           const float* __restrict__ colw,
                           ushort_t* __restrict__ Sh, ushort_t* __restrict__ Sl) {
  int g = blockIdx.x * 256 + threadIdx.x;
  int bl = g / (MPAD / 4);
  int k = (g - bl * (MPAD / 4)) * 4;
  int b = bl / MPAD, l = bl - b * MPAD;
  long long o = (long long)bl * MPAD + k;
  float cw = colw[b * MPAD + l];
  float4 sc = *(const float4*)(scale + b * MPAD + k);
  float4 av = *(const float4*)(A2c + o);
  float v0 = sc.x * (av.x + (float)(k     == l)) * cw;
  float v1 = sc.y * (av.y + (float)(k + 1 == l)) * cw;
  float v2 = sc.z * (av.z + (float)(k + 2 == l)) * cw;
  float v3 = sc.w * (av.w + (float)(k + 3 == l)) * cw;
  ushort_t h0 = f2bf(v0), h1 = f2bf(v1), h2 = f2bf(v2), h3 = f2bf(v3);
  *(uint2*)&Sh[o] = make_uint2((unsigned)h0 | ((unsigned)h1 << 16),
                               (unsigned)h2 | ((unsigned)h3 << 16));
  ushort_t l0 = f2bf(v0 - bf2f(h0)), l1 = f2bf(v1 - bf2f(h1));
  ushort_t l2 = f2bf(v2 - bf2f(h2)), l3 = f2bf(v3 - bf2f(h3));
  *(uint2*)&Sl[o] = make_uint2((unsigned)l0 | ((unsigned)l1 << 16),
                               (unsigned)l2 | ((unsigned)l3 << 16));
}

// ---------- transpose + split, optional per-row scale ----------
__global__ __launch_bounds__(256) void cvt_xT_k(const float* __restrict__ X,
                                                const float* __restrict__ rsc,
                                                ushort_t* __restrict__ Th, ushort_t* __restrict__ Tl,
                                                int Nn, int Fd) {
  __shared__ float t[32][33];
  int b = blockIdx.z;
  int n0 = blockIdx.x * 32, f0 = blockIdx.y * 32;
  int tx = threadIdx.x & 31, ty = threadIdx.x >> 5;
  const float* Xb = X + ((long long)b * Nn + n0) * Fd + f0;
  for (int r = ty; r < 32; r += 8) {
    float sc = rsc ? rsc[(long long)b * Nn + n0 + r] : 1.f;
    t[r][tx] = sc * Xb[(long long)r * Fd + tx];
  }
  __syncthreads();
  for (int r = ty; r < 32; r += 8) {
    float v = t[tx][r];
    ushort_t h = f2bf(v);
    long long idx = ((long long)b * Fd + f0 + r) * Nn + n0 + tx;
    Th[idx] = h;
    Tl[idx] = f2bf(v - bf2f(h));
  }
}

// ============ MFMA split-bf16 GEMM, batch->XCD swizzled ============
// BSEL: stage B from binary AdjH x scale-splits (B row k' of scale_n*adjbin[k'][n]).
// SYMM: lower-triangle tiles only; EPI 5/7 mirror-write (skipped on diagonal tiles).
// EPI: 0 fp32; 1 split; 5 quant+splits; 6 cwv[row]*v (MPAD stride);
//      7 cwv[row]*cwv[col]*v quant+splits; 8 cwv[col]*v (NN stride) split store.
template<int SA, int SB, int BSEL, int SYMM, int EPI>
__global__ __launch_bounds__(256) void mgemm_k(
    const ushort_t* __restrict__ Ah, const ushort_t* __restrict__ Al,
    const ushort_t* __restrict__ Bh, const ushort_t* __restrict__ Bl,
    const ushort_t* __restrict__ bsH, const ushort_t* __restrict__ bsL,
    float* __restrict__ Co, ushort_t* __restrict__ Toh, ushort_t* __restrict__ Tol,
    int M, int Ncol, int K, long long sA, long long sB, long long sC,
    const float* __restrict__ cwv, int gx) {
  __shared__ ushort_t Ahs[128 * 32];
  __shared__ ushort_t Bhs[128 * 32];
  __shared__ ushort_t Als[SA ? 128 * 32 : 64];
  __shared__ ushort_t Bls[SB ? 128 * 32 : 64];

  int tid = threadIdx.x;
  int id = blockIdx.x;
  long long bz = id & 7;
  int t0 = id >> 3;
  int tm, tn;
  if constexpr (SYMM) {
    tm = 0; int base = 0;
    while (base + tm + 1 <= t0) { base += tm + 1; tm++; }
    tn = t0 - base;
  } else {
    tn = t0 % gx; tm = t0 / gx;
  }
  int n0 = tn * 128, m0 = tm * 128;
  const ushort_t* Ahb = Ah + bz * sA;
  const ushort_t* Alb = SA ? (Al + bz * sA) : Ah;
  const ushort_t* Bhb = Bh + bz * sB;
  const ushort_t* Blb = (SB && !BSEL) ? (Bl + bz * sB) : Bh;
  const ushort_t* bsHb = BSEL ? (bsH + bz * NN) : (const ushort_t*)0;
  const ushort_t* bsLb = BSEL ? (bsL + bz * NN) : (const ushort_t*)0;

  int sr = tid >> 2;
  int sc = (tid & 3) * 8;
  int lane = tid & 63, w = tid >> 6;
  int wm = (w >> 1) * 64, wn = (w & 1) * 64;
  int fr = lane & 15;
  int fo = (lane >> 4) * 8;
  int q = lane >> 4;

  f32x4 acc[4][4];
  f32x4 zz = {0.f, 0.f, 0.f, 0.f};
#pragma unroll
  for (int i = 0; i < 4; i++)
#pragma unroll
    for (int j = 0; j < 4; j++) acc[i][j] = zz;

  for (int k0 = 0; k0 < K; k0 += 32) {
    __syncthreads();
#pragma unroll
    for (int r = 0; r < 128; r += 64) {
      GLDS16(Ahb + (long long)(m0 + sr + r) * K + k0 + sc, &Ahs[(r + sr) * 32 + sc]);
      if constexpr (SA) {
        GLDS16(Alb + (long long)(m0 + sr + r) * K + k0 + sc, &Als[(r + sr) * 32 + sc]);
      }
    }
    if constexpr (BSEL) {
      uint4 shv = *(const uint4*)(bsHb + k0 + sc);
      uint4 slv = *(const uint4*)(bsLb + k0 + sc);
      const unsigned* shp = (const unsigned*)&shv;
      const unsigned* slp = (const unsigned*)&slv;
#pragma unroll
      for (int r = 0; r < 128; r += 64) {
        uint4 av = *(const uint4*)(Bhb + (long long)(n0 + sr + r) * K + k0 + sc);
        const unsigned* ap = (const unsigned*)&av;
        uint4 oh, ol;
        unsigned* ohp = (unsigned*)&oh;
        unsigned* olp = (unsigned*)&ol;
#pragma unroll
        for (int q2 = 0; q2 < 4; q2++) {
          unsigned a = ap[q2];
          unsigned msk = ((a & 0xFFFFu) ? 0xFFFFu : 0u) | ((a >> 16) ? 0xFFFF0000u : 0u);
          ohp[q2] = shp[q2] & msk;
          olp[q2] = slp[q2] & msk;
        }
        *(uint4*)&Bhs[(sr + r) * 32 + sc] = oh;
        *(uint4*)&Bls[(sr + r) * 32 + sc] = ol;
      }
    } else {
#pragma unroll
      for (int r = 0; r < 128; r += 64) {
        GLDS16(Bhb + (long long)(n0 + sr + r) * K + k0 + sc, &Bhs[(r + sr) * 32 + sc]);
        if constexpr (SB) {
          GLDS16(Blb + (long long)(n0 + sr + r) * K + k0 + sc, &Bls[(r + sr) * 32 + sc]);
        }
      }
    }
    __syncthreads();

    short8 ah[4], al[4], bh[4], bl[4];
#pragma unroll
    for (int i = 0; i < 4; i++) {
      ah[i] = *(const short8*)&Ahs[(wm + i * 16 + fr) * 32 + fo];
      if constexpr (SA) al[i] = *(const short8*)&Als[(wm + i * 16 + fr) * 32 + fo];
    }
#pragma unroll
    for (int j = 0; j < 4; j++) {
      bh[j] = *(const short8*)&Bhs[(wn + j * 16 + fr) * 32 + fo];
      if constexpr (SB) bl[j] = *(const short8*)&Bls[(wn + j * 16 + fr) * 32 + fo];
    }
#pragma unroll
    for (int i = 0; i < 4; i++)
#pragma unroll
      for (int j = 0; j < 4; j++) {
        acc[i][j] = __builtin_amdgcn_mfma_f32_16x16x32_bf16(ah[i], bh[j], acc[i][j], 0, 0, 0);
        if constexpr (SB)
          acc[i][j] = __builtin_amdgcn_mfma_f32_16x16x32_bf16(ah[i], bl[j], acc[i][j], 0, 0, 0);
        if constexpr (SA)
          acc[i][j] = __builtin_amdgcn_mfma_f32_16x16x32_bf16(al[i], bh[j], acc[i][j], 0, 0, 0);
      }
  }

#pragma unroll
  for (int i = 0; i < 4; i++)
#pragma unroll
    for (int j = 0; j < 4; j++)
#pragma unroll
      for (int r = 0; r < 4; r++) {
        float v = acc[i][j][r];
        int row = m0 + wm + i * 16 + q * 4 + r;
        int col = n0 + wn + j * 16 + fr;
        long long idx = bz * sC + (long long)row * Ncol + col;
        if constexpr (EPI == 0) {
          Co[idx] = v;
        } else if constexpr (EPI == 1) {
          ushort_t h = f2bf(v);
          Toh[idx] = h;
          Tol[idx] = f2bf(v - bf2f(h));
        } else if constexpr (EPI == 5) {
          float vq = floorf(v * 10000.f) / 10000.f;
          ushort_t h = f2bf(vq);
          ushort_t lo = f2bf(vq - bf2f(h));
          Co[idx] = vq; Toh[idx] = h; Tol[idx] = lo;
          if constexpr (SYMM) {
            if (tm != tn) {
              long long idxT = bz * sC + (long long)col * Ncol + row;
              Co[idxT] = vq; Toh[idxT] = h; Tol[idxT] = lo;
            }
          }
        } else if constexpr (EPI == 6) {
          Co[idx] = cwv[bz * MPAD + row] * v;
        } else if constexpr (EPI == 7) {
          float vs = cwv[bz * MPAD + row] * cwv[bz * MPAD + col] * v;
          float vq = floorf(vs * 10000.f) / 10000.f;
          ushort_t h = f2bf(vq);
          ushort_t lo = f2bf(vq - bf2f(h));
          Co[idx] = vq; Toh[idx] = h; Tol[idx] = lo;
          if constexpr (SYMM) {
            if (tm != tn) {
              long long idxT = bz * sC + (long long)col * Ncol + row;
              Co[idxT] = vq; Toh[idxT] = h; Tol[idxT] = lo;
            }
          }
        } else {  // EPI == 8
          float vs = v * cwv[bz * NN + col];
          ushort_t h = f2bf(vs);
          Toh[idx] = h;
          Tol[idx] = f2bf(vs - bf2f(h));
        }
      }
}

// ---------- GCN1 epilogue ----------
__global__ void epi_k(const float* __restrict__ acc, const float* __restrict__ xw,
                      const float* __restrict__ dgcn, const float* __restrict__ diag,
                      const float* __restrict__ bias, const float* __restrict__ mask,
                      float* __restrict__ outx) {
  long long i = (long long)blockIdx.x * 256 + threadIdx.x;
  int rowi = (int)(i >> 7);
  int f = (int)(i & 127);
  float d = dgcn[rowi];
  float t = d * (acc[i] + (1.f - diag[rowi]) * d * xw[i]) + bias[f];
  t *= mask[rowi];
  outx[i] = fmaxf(t, 0.f);
}

// ---------- final epilogue (compact) ----------
__global__ void epic_k(float* __restrict__ acc, const float* __restrict__ xw,
                       const float* __restrict__ dgcn, const float* __restrict__ diag,
                       const float* __restrict__ bias, const float* __restrict__ mask,
                       const int* __restrict__ kmap) {
  long long i = (long long)blockIdx.x * 256 + threadIdx.x;
  int rowi = (int)(i >> 8);
  int f = (int)(i & 255);
  int b = rowi / MPAD;
  int km = kmap[rowi];
  float mv = (km >= 0) ? mask[b * NN + km] : 1.f;
  float d = dgcn[rowi];
  float t = d * (acc[i] + (1.f - diag[rowi]) * d * xw[i]) + bias[f];
  acc[i] = t * mv;
}

// ---------- two-stage column means ----------
__global__ void pmean_k(const float* __restrict__ X, float* __restrict__ part,
                        int Nn, int Fd, int rpc) {
  int b = blockIdx.y, c = blockIdx.x, f = threadIdx.x;
  const float* p = X + ((long long)b * Nn + (long long)c * rpc) * Fd + f;
  float s = 0.f;
  for (int r = 0; r < rpc; r++) s += p[(long long)r * Fd];
  part[((long long)b * gridDim.x + c) * Fd + f] = s;
}

__global__ void fmean_k(const float* __restrict__ part, int nch, int Fd, float corr,
                        const float* __restrict__ bias, float* __restrict__ out, int outoff) {
  int b = blockIdx.x, f = threadIdx.x;
  float s = 0.f;
  for (int c = 0; c < nch; c++) s += part[((long long)b * nch + c) * Fd + f];
  float cv = bias ? corr * bias[f] : 0.f;
  out[b * (HH + FF) + outoff + f] = s * (1.f / NN) + cv;
}

// ---------- fp32 VALU GEMM (feature matmuls) ----------
__global__ __launch_bounds__(256) void gemm_k(const float* __restrict__ A, const float* __restrict__ B,
                                              float* __restrict__ C, int M, int Nw, int Kk,
                                              long long sA, long long sB, long long sC) {
  __shared__ float As[16][128];
  __shared__ float Bs[16][128];
  int tid = threadIdx.x;
  int n0 = blockIdx.x * 128, m0 = blockIdx.y * 128;
  const float* Ab = A + (long long)blockIdx.z * sA;
  const float* Bb = B + (long long)blockIdx.z * sB;
  float* Cb = C + (long long)blockIdx.z * sC;
  float acc[8][8];
#pragma unroll
  for (int i = 0; i < 8; i++)
#pragma unroll
    for (int j = 0; j < 8; j++) acc[i][j] = 0.f;
  int tx = tid & 15, ty = tid >> 4;

  for (int k0 = 0; k0 < Kk; k0 += 16) {
    {
      int r = tid >> 2, c = (tid & 3) << 2;
#pragma unroll
      for (int rr = 0; rr < 2; rr++) {
        int rrow = r + rr * 64;
        float4 v = *(const float4*)(Ab + (long long)(m0 + rrow) * Kk + k0 + c);
        As[c + 0][rrow] = v.x; As[c + 1][rrow] = v.y;
        As[c + 2][rrow] = v.z; As[c + 3][rrow] = v.w;
      }
    }
    {
      int kk = tid >> 5, cc = (tid & 31) << 2;
#pragma unroll
      for (int k2 = 0; k2 < 2; k2++) {
        float4 v = *(const float4*)(Bb + (long long)(k0 + kk + k2 * 8) * Nw + n0 + cc);
        *(float4*)&Bs[kk + k2 * 8][cc] = v;
      }
    }
    __syncthreads();
#pragma unroll
    for (int kk = 0; kk < 16; kk++) {
      float a[8], bb[8];
      *(float4*)&a[0]  = *(float4*)&As[kk][ty * 8];
      *(float4*)&a[4]  = *(float4*)&As[kk][ty * 8 + 4];
      *(float4*)&bb[0] = *(float4*)&Bs[kk][tx * 8];
      *(float4*)&bb[4] = *(float4*)&Bs[kk][tx * 8 + 4];
#pragma unroll
      for (int i = 0; i < 8; i++)
#pragma unroll
        for (int j = 0; j < 8; j++) acc[i][j] += a[i] * bb[j];
    }
    __syncthreads();
  }
#pragma unroll
  for (int i = 0; i < 8; i++) {
    float* cp = Cb + (long long)(m0 + ty * 8 + i) * Nw + n0 + tx * 8;
    *(float4*)cp = *(float4*)&acc[i][0];
    *(float4*)(cp + 4) = *(float4*)&acc[i][4];
  }
}

extern "C" void kernel_launch(void* const* d_in, const int* in_sizes, int n_in,
                              void* d_out, int out_size, void* d_ws, size_t ws_size,
                              hipStream_t stream) {
  const float* x    = (const float*)d_in[0];
  const float* adj  = (const float*)d_in[1];
  const float* mask = (const float*)d_in[2];
  const float* W1   = (const float*)d_in[3];
  const float* b1   = (const float*)d_in[4];
  const float* Watt = (const float*)d_in[5];
  const float* batt = (const float*)d_in[6];
  const float* W2   = (const float*)d_in[7];
  const float* b2   = (const float*)d_in[8];
  float* out = (float*)d_out;

  const long long NN2  = (long long)NN * NN;
  const long long CSTR = (long long)MPAD * NN;
  const long long CTOT = (long long)NB * CSTR;
  const long long M2   = (long long)MPAD * MPAD;
  const long long M2T  = (long long)NB * M2;

  // ---- workspace (~260 MB) ----
  float* ws = (float*)d_ws;
  long long off = 0;
  ushort_t* S2cH = (ushort_t*)(ws + off); off += M2T;       // 2*M2T ushorts (S2c splits, L1)
  float* A2CR = ws + off; off += M2T * 2;                   // union: AdjH / A2cF+H+L
  float* TcF  = ws + off; off += CTOT;                      // multi-phase scratch
  ushort_t* Abin = (ushort_t*)(ws + off); off += CTOT / 2;  // CTOT ushorts
  float* xa   = ws + off; off += (long long)NROWS * HH;
  float* x2c  = ws + off; off += (long long)MC * HH;
  float* x3c  = ws + off; off += (long long)MC * HH;
  float* diag   = ws + off; off += NROWS;
  float* dgcn   = ws + off; off += NROWS;
  float* dnorm  = ws + off; off += NROWS;
  float* rz     = ws + off; off += NROWS;
  float* wv     = ws + off; off += NROWS;
  float* alphav = ws + off; off += (long long)NB * NN;
  float* colwv  = ws + off; off += NROWS;
  float* scalev = ws + off; off += NROWS;
  ushort_t* sHs = (ushort_t*)(ws + off); off += NROWS / 2;  // scale hi splits
  ushort_t* sLs = (ushort_t*)(ws + off); off += NROWS / 2;  // scale lo splits
  int* keepidx  = (int*)(ws + off); off += NB * MPAD;
  float* cwk    = ws + off; off += MC;
  float* partm  = ws + off; off += NB * 16 * FF;

  ushort_t* S2cL = S2cH + M2T;
  // A2CR union: AdjH (BIG ushorts, GCN1..G1n) -> A2cF/H/L (G2n..)
  ushort_t* AdjH = (ushort_t*)A2CR;
  float* A2cF = A2CR;
  ushort_t* A2cH = (ushort_t*)(A2CR + M2T);
  ushort_t* A2cL = A2cH + M2T;

  // TcF phase aliases
  float* u1 = TcF;
  float* u2 = TcF + (long long)NROWS * HH;
  ushort_t* y1Th = (ushort_t*)(TcF + 2ll * NROWS * HH);
  ushort_t* y1Tl = y1Th + (long long)NROWS * HH;
  ushort_t* Rh = (ushort_t*)TcF;                          // R splits (CTOT each)
  ushort_t* Rl = Rh + CTOT;
  ushort_t* xT1h = (ushort_t*)TcF;
  ushort_t* xT1l = xT1h + (long long)NROWS * HH;
  ushort_t* Tc2H = (ushort_t*)TcF;
  ushort_t* Tc2L = Tc2H + M2T;
  ushort_t* x2Th = (ushort_t*)TcF;
  ushort_t* x2Tl = x2Th + (long long)MC * HH;
  float* u1f = TcF;
  float* u2f = TcF + (long long)MC * FF;
  ushort_t* y2Th = (ushort_t*)(TcF + 2ll * MC * FF);
  ushort_t* y2Tl = y2Th + (long long)MC * FF;

  // ================= GCN1 (full space) =================
  rowstats_k<<<NROWS / 4, 256, 0, stream>>>(adj, AdjH, diag, dgcn, dnorm, rz, NN);
  gemm_k<<<dim3(1, NROWS / 128, 1), 256, 0, stream>>>(x, W1, u1, NROWS, HH, FF, 0, 0, 0);
  cvt_xT_k<<<dim3(NN / 32, HH / 32, NB), 256, 0, stream>>>(u1, dgcn, y1Th, y1Tl, NN, HH);
  mgemm_k<0, 1, 0, 0, 0><<<1 * (NN / 128) * NB, 256, 0, stream>>>(
      AdjH, 0, y1Th, y1Tl, 0, 0, u2, 0, 0,
      NN, HH, NN, NN2, (long long)HH * NN, (long long)NN * HH, 0, 1);
  epi_k<<<(NROWS * HH) / 256, 256, 0, stream>>>(u2, u1, dgcn, diag, b1, mask, xa);
  pmean_k<<<dim3(16, NB), HH, 0, stream>>>(xa, partm, NN, HH, 128);
  fmean_k<<<NB, HH, 0, stream>>>(partm, 16, HH, 0.f, 0, out, 0);

  // ================= coarsen layer 0 =================
  wvec_k<<<NROWS / 4, 256, 0, stream>>>(xa, Watt, batt, dnorm, wv);
  alphaB_k<<<NROWS / 4, 256, 0, stream>>>(AdjH, wv, dnorm, rz, alphav);
  topkeep_k<<<NB, 1024, 0, stream>>>(alphav, dnorm, rz, colwv, keepidx);
  scaleB_k<<<NROWS / 4, 256, 0, stream>>>(AdjH, colwv, dnorm, rz, scalev, sHs, sLs);
  writeAbin_k<<<(int)(CTOT / 4 / 256), 256, 0, stream>>>(AdjH, keepidx, colwv, Abin, cwk);
  // G1n: R = (Abin @ [scale_n * adjbin]) * scale_col  (BSEL staging, EPI8 split store)
  mgemm_k<0, 1, 1, 0, 8><<<(NN / 128) * (MPAD / 128) * NB, 256, 0, stream>>>(
      Abin, 0, AdjH, 0, sHs, sLs, 0, Rh, Rl,
      MPAD, NN, NN, CSTR, NN2, CSTR, scalev, NN / 128);
  // G2n: A2c = cw*cw*(R @ Abin^T) quantized, symmetric lower-triangle + mirror
  mgemm_k<1, 0, 0, 1, 7><<<45 * NB, 256, 0, stream>>>(
      Rh, Rl, Abin, 0, 0, 0, A2cF, A2cH, A2cL,
      MPAD, MPAD, NN, CSTR, CSTR, M2, cwk, MPAD / 128);
  // G3n: x2c = cw * (Abin @ (scale*x1))
  cvt_xT_k<<<dim3(NN / 32, HH / 32, NB), 256, 0, stream>>>(xa, scalev, xT1h, xT1l, NN, HH);
  mgemm_k<0, 1, 0, 0, 6><<<1 * (MPAD / 128) * NB, 256, 0, stream>>>(
      Abin, 0, xT1h, xT1l, 0, 0, x2c, 0, 0,
      MPAD, HH, NN, CSTR, (long long)HH * NN, (long long)MPAD * HH, cwk, 1);

  // ================= coarsen layer 1 (all compact) =================
  rowstats_k<<<MC / 4, 256, 0, stream>>>(A2cF, 0, diag, dgcn, dnorm, rz, MPAD);
  wvec_k<<<MC / 4, 256, 0, stream>>>(x2c, Watt, batt, dnorm, wv);
  alpha_k<<<MC / 4, 256, 0, stream>>>(A2cF, wv, dnorm, rz, alphav, MPAD);
  padfill_k<<<((NN - MPAD) * NB) / 256, 256, 0, stream>>>(alphav);
  topcolw_k<<<NB, 1024, 0, stream>>>(alphav, dnorm, colwv);
  scale_k<<<MC / 4, 256, 0, stream>>>(A2cF, colwv, dnorm, rz, scalev, MPAD);
  writeS2c_k<<<(int)(M2T / 4 / 256), 256, 0, stream>>>(A2cF, scalev, colwv, S2cH, S2cL);
  // G1': tmp2^T = S2^T @ A2c
  mgemm_k<1, 1, 0, 0, 1><<<(MPAD / 128) * (MPAD / 128) * NB, 256, 0, stream>>>(
      S2cH, S2cL, A2cH, A2cL, 0, 0, 0, Tc2H, Tc2L,
      MPAD, MPAD, MPAD, M2, M2, M2, 0, MPAD / 128);
  // G2': A3c = S2^T @ tmp2 quantized, symmetric lower-triangle + mirror
  mgemm_k<1, 1, 0, 1, 5><<<45 * NB, 256, 0, stream>>>(
      S2cH, S2cL, Tc2H, Tc2L, 0, 0, A2cF, A2cH, A2cL,
      MPAD, MPAD, MPAD, M2, M2, M2, 0, MPAD / 128);
  // G3': x3c = S2^T @ x2c
  cvt_xT_k<<<dim3(MPAD / 32, HH / 32, NB), 256, 0, stream>>>(x2c, 0, x2Th, x2Tl, MPAD, HH);
  mgemm_k<1, 1, 0, 0, 0><<<1 * (MPAD / 128) * NB, 256, 0, stream>>>(
      S2cH, S2cL, x2Th, x2Tl, 0, 0, x3c, 0, 0,
      MPAD, HH, MPAD, M2, (long long)HH * MPAD, (long long)MPAD * HH, 0, 1);

  // ================= final GCN (compact) =================
  rowstats_k<<<MC / 4, 256, 0, stream>>>(A2cF, 0, diag, dgcn, dnorm, rz, MPAD);
  gemm_k<<<dim3(FF / 128, MPAD / 128, NB), 256, 0, stream>>>(
      x3c, W2, u1f, MPAD, FF, HH, (long long)MPAD * HH, 0, (long long)MPAD * FF);
  cvt_xT_k<<<dim3(MPAD / 32, FF / 32, NB), 256, 0, stream>>>(u1f, dgcn, y2Th, y2Tl, MPAD, FF);
  mgemm_k<1, 1, 0, 0, 0><<<(FF / 128) * (MPAD / 128) * NB, 256, 0, stream>>>(
      A2cH, A2cL, y2Th, y2Tl, 0, 0, u2f, 0, 0,
      MPAD, FF, MPAD, M2, (long long)FF * MPAD, (long long)MPAD * FF, 0, FF / 128);
  epic_k<<<(MC * FF) / 256, 256, 0, stream>>>(u2f, u1f, dgcn, diag, b2, mask, keepidx);
  pmean_k<<<dim3(9, NB), FF, 0, stream>>>(u2f, partm, MPAD, FF, 128);
  fmean_k<<<NB, FF, 0, stream>>>(partm, 9, FF, (float)(NN - MPAD) / NN, b2, out, HH);
}

// Round 10
// 1177.133 us; speedup vs baseline: 6.6730x; 1.0770x over previous
//
#include <hip/hip_runtime.h>
#include <math.h>

#define NN 2048
#define NB 8
#define FF 256
#define HH 128
#define KSEL 1025
#define NROWS (NB*NN)
#define MPAD 1152
#define MC (MPAD*NB)

typedef unsigned short ushort_t;
typedef __attribute__((ext_vector_type(8))) short short8;
typedef __attribute__((ext_vector_type(4))) float f32x4;

__device__ inline ushort_t f2bf(float f) {
  unsigned u = __float_as_uint(f);
  unsigned r = (u + 0x7FFFu + ((u >> 16) & 1u)) >> 16;
  return (ushort_t)r;
}
__device__ inline float bf2f(ushort_t u) {
  unsigned x = ((unsigned)u) << 16;
  return __uint_as_float(x);
}

#define GLDS16(g, l) __builtin_amdgcn_global_load_lds( \
    (const __attribute__((address_space(1))) unsigned int*)(g), \
    (__attribute__((address_space(3))) unsigned int*)(l), 16, 0, 0)

// ---------- row stats + derive fused; optional fused adj->bf16 conversion ----------
__global__ __launch_bounds__(256) void rowstats_k(const float* __restrict__ A,
                                                  ushort_t* __restrict__ H,
                                                  float* __restrict__ diag,
                                                  float* __restrict__ dgcn,
                                                  float* __restrict__ dnorm,
                                                  float* __restrict__ rz, int R) {
  int gw = (blockIdx.x * 256 + threadIdx.x) >> 6;
  int lane = threadIdx.x & 63;
  int b = gw / R, i = gw - b * R;
  const float4* row = (const float4*)(A + (long long)gw * R);
  int R4 = R >> 2;
  float s = 0.f;
  for (int j = lane; j < R4; j += 64) {
    float4 v = row[j];
    s += v.x + v.y + v.z + v.w;
    if (H) {
      ushort_t h0 = f2bf(v.x), h1 = f2bf(v.y), h2 = f2bf(v.z), h3 = f2bf(v.w);
      *(uint2*)&H[(long long)gw * R + j * 4] =
          make_uint2((unsigned)h0 | ((unsigned)h1 << 16), (unsigned)h2 | ((unsigned)h3 << 16));
    }
  }
  for (int off = 32; off > 0; off >>= 1) s += __shfl_down(s, off);
  if (lane == 0) {
    float dg = A[(long long)gw * R + i];
    diag[gw] = dg;
    dgcn[gw]  = rsqrtf(fmaxf(s - dg + 1.f, 1.f));
    dnorm[gw] = rsqrtf(fmaxf(s + 1.f, 1.f));
    rz[gw]    = s > 0.f ? 1.f : 0.f;
  }
}

// ---------- L1: rowstats + wvec fused (dnorm consumed in-register) ----------
__global__ __launch_bounds__(256) void rowstatsw_k(const float* __restrict__ A,
                                                   const float* __restrict__ X,
                                                   const float* __restrict__ Watt,
                                                   const float* __restrict__ batt,
                                                   float* __restrict__ diag,
                                                   float* __restrict__ dgcn,
                                                   float* __restrict__ dnorm,
                                                   float* __restrict__ rz,
                                                   float* __restrict__ w, int R) {
  int gw = (blockIdx.x * 256 + threadIdx.x) >> 6;
  int lane = threadIdx.x & 63;
  int b = gw / R, i = gw - b * R;
  const float4* row = (const float4*)(A + (long long)gw * R);
  int R4 = R >> 2;
  float s = 0.f;
  for (int j = lane; j < R4; j += 64) {
    float4 v = row[j];
    s += v.x + v.y + v.z + v.w;
  }
  for (int off = 32; off > 0; off >>= 1) s += __shfl_xor(s, off);
  float dn = rsqrtf(fmaxf(s + 1.f, 1.f));
  const float* xr = X + (long long)gw * HH;
  float t = xr[lane] * Watt[lane] + xr[lane + 64] * Watt[lane + 64];
  for (int off = 32; off > 0; off >>= 1) t += __shfl_down(t, off);
  if (lane == 0) {
    float dg = A[(long long)gw * R + i];
    diag[gw] = dg;
    dgcn[gw]  = rsqrtf(fmaxf(s - dg + 1.f, 1.f));
    dnorm[gw] = dn;
    rz[gw]    = s > 0.f ? 1.f : 0.f;
    w[gw] = dn * (t + batt[0]);
  }
}

__global__ __launch_bounds__(256) void wvec_k(const float* __restrict__ x,
                                              const float* __restrict__ Watt,
                                              const float* __restrict__ batt,
                                              const float* __restrict__ dnorm,
                                              float* __restrict__ w) {
  int gw = (blockIdx.x * 256 + threadIdx.x) >> 6;
  int lane = threadIdx.x & 63;
  const float* r = x + (long long)gw * HH;
  float s = r[lane] * Watt[lane] + r[lane + 64] * Watt[lane + 64];
  for (int off = 32; off > 0; off >>= 1) s += __shfl_down(s, off);
  if (lane == 0) w[gw] = dnorm[gw] * (s + batt[0]);
}

// ---------- L0 alpha from binary AdjH ----------
__global__ __launch_bounds__(256) void alphaB_k(const ushort_t* __restrict__ H,
                                                const float* __restrict__ w,
                                                const float* __restrict__ dnorm,
                                                const float* __restrict__ rz,
                                                float* __restrict__ alpha) {
  int gw = (blockIdx.x * 256 + threadIdx.x) >> 6;
  int lane = threadIdx.x & 63;
  int b = gw >> 11, i = gw & (NN - 1);
  const uint4* rowH = (const uint4*)(H + (long long)gw * NN);
  const float4* w4 = (const float4*)(w + (long long)b * NN);
  float s = 0.f;
  for (int j = lane; j < NN / 8; j += 64) {
    uint4 av = rowH[j];
    float4 wa = w4[2 * j], wb = w4[2 * j + 1];
    if (av.x & 0xFFFFu) s += wa.x;  if (av.x >> 16) s += wa.y;
    if (av.y & 0xFFFFu) s += wa.z;  if (av.y >> 16) s += wa.w;
    if (av.z & 0xFFFFu) s += wb.x;  if (av.z >> 16) s += wb.y;
    if (av.w & 0xFFFFu) s += wb.z;  if (av.w >> 16) s += wb.w;
  }
  for (int off = 32; off > 0; off >>= 1) s += __shfl_down(s, off);
  if (lane == 0) {
    float aa = rz[gw] * dnorm[gw] * (s + w[(long long)b * NN + i]);
    aa = aa * aa;
    alpha[(long long)b * NN + i] = 1.f / (1.f + expf(-aa));
  }
}

// ---------- L1 alpha (fp32 A) ----------
__global__ __launch_bounds__(256) void alpha_k(const float* __restrict__ A,
                                               const float* __restrict__ w,
                                               const float* __restrict__ dnorm,
                                               const float* __restrict__ rz,
                                               float* __restrict__ alpha, int R) {
  int gw = (blockIdx.x * 256 + threadIdx.x) >> 6;
  int lane = threadIdx.x & 63;
  int b = gw / R, i = gw - b * R;
  const float4* row = (const float4*)(A + (long long)gw * R);
  const float4* wb4 = (const float4*)(w + (long long)b * R);
  int R4 = R >> 2;
  float s = 0.f;
  for (int j = lane; j < R4; j += 64) {
    float4 a = row[j], ww = wb4[j];
    s += a.x * ww.x + a.y * ww.y + a.z * ww.z + a.w * ww.w;
  }
  for (int off = 32; off > 0; off >>= 1) s += __shfl_down(s, off);
  if (lane == 0) {
    float aa = rz[gw] * dnorm[gw] * (s + w[(long long)b * R + i]);
    aa = aa * aa;
    alpha[(long long)b * NN + i] = 1.f / (1.f + expf(-aa));
  }
}

__global__ void padfill_k(float* __restrict__ alpha) {
  int idx = blockIdx.x * 256 + threadIdx.x;
  int b = idx / (NN - MPAD), j = idx - b * (NN - MPAD);
  alpha[b * NN + MPAD + j] = 0.5f;
}

// ---------- exact k-th largest via 4-round radix select ----------
__global__ __launch_bounds__(1024) void topkeep_k(const float* __restrict__ alpha,
                                                  const float* __restrict__ dnorm,
                                                  const float* __restrict__ rz,
                                                  float* __restrict__ colw,
                                                  int* __restrict__ keepidx) {
  __shared__ unsigned vals[NN];
  __shared__ int hist[256];
  __shared__ int wsum[32];
  __shared__ unsigned selp_s;
  __shared__ int selr_s;
  int b = blockIdx.x, t = threadIdx.x;
  vals[t] = __float_as_uint(alpha[b * NN + t]);
  vals[t + 1024] = __float_as_uint(alpha[b * NN + t + 1024]);
  if (t == 0) { selp_s = 0u; selr_s = KSEL; }
  __syncthreads();
  for (int shift = 24; shift >= 0; shift -= 8) {
    if (t < 256) hist[t] = 0;
    __syncthreads();
    unsigned pre = selp_s; int rank = selr_s;
    unsigned hm = (shift == 24) ? 0u : (0xFFFFFFFFu << (shift + 8));
    for (int e = t; e < NN; e += 1024) {
      unsigned v = vals[e];
      if ((v & hm) == (pre & hm)) atomicAdd(&hist[(v >> shift) & 255], 1);
    }
    __syncthreads();
    for (int off2 = 1; off2 < 256; off2 <<= 1) {
      int v = 0;
      if (t < 256 - off2) v = hist[t + off2];
      __syncthreads();
      if (t < 256 - off2) hist[t] += v;
      __syncthreads();
    }
    if (t < 256) {
      int cge = hist[t];
      int cgt = (t == 255) ? 0 : hist[t + 1];
      if (cge >= rank && cgt < rank) {
        selp_s = pre | ((unsigned)t << shift);
        selr_s = rank - cgt;
      }
    }
    __syncthreads();
  }
  float cu = __uint_as_float(selp_s);
  float a0 = __uint_as_float(vals[t]);
  float a1 = __uint_as_float(vals[t + 1024]);
  float c0 = dnorm[b * NN + t]        * fmaxf(a0 + 1e-7f - cu, 0.f);
  float c1 = dnorm[b * NN + t + 1024] * fmaxf(a1 + 1e-7f - cu, 0.f);
  colw[b * NN + t] = c0;
  colw[b * NN + t + 1024] = c1;
  int f0 = (c0 != 0.f && rz[b * NN + t]        != 0.f) ? 1 : 0;
  int f1 = (c1 != 0.f && rz[b * NN + t + 1024] != 0.f) ? 1 : 0;
  int lane = t & 63, wid = t >> 6;
  unsigned long long m0 = __ballot(f0);
  unsigned long long m1 = __ballot(f1);
  if (lane == 0) { wsum[wid] = __popcll(m0); wsum[16 + wid] = __popcll(m1); }
  __syncthreads();
  if (t == 0) { int run = 0; for (int i2 = 0; i2 < 32; i2++) { int v = wsum[i2]; wsum[i2] = run; run += v; } }
  __syncthreads();
  unsigned long long lm = (1ull << lane) - 1ull;
  int p0 = wsum[wid] + __popcll(m0 & lm);
  int p1 = wsum[16 + wid] + __popcll(m1 & lm);
  if (t < MPAD) keepidx[b * MPAD + t] = -1;
  if (t + 1024 < MPAD) keepidx[b * MPAD + t + 1024] = -1;
  __syncthreads();
  if (f0 && p0 < MPAD) keepidx[b * MPAD + p0] = t;
  if (f1 && p1 < MPAD) keepidx[b * MPAD + p1] = t + 1024;
}

// L1 variant: radix select + compact colw only
__global__ __launch_bounds__(1024) void topcolw_k(const float* __restrict__ alpha,
                                                  const float* __restrict__ dnorm,
                                                  float* __restrict__ colw) {
  __shared__ unsigned vals[NN];
  __shared__ int hist[256];
  __shared__ unsigned selp_s;
  __shared__ int selr_s;
  int b = blockIdx.x, t = threadIdx.x;
  vals[t] = __float_as_uint(alpha[b * NN + t]);
  vals[t + 1024] = __float_as_uint(alpha[b * NN + t + 1024]);
  if (t == 0) { selp_s = 0u; selr_s = KSEL; }
  __syncthreads();
  for (int shift = 24; shift >= 0; shift -= 8) {
    if (t < 256) hist[t] = 0;
    __syncthreads();
    unsigned pre = selp_s; int rank = selr_s;
    unsigned hm = (shift == 24) ? 0u : (0xFFFFFFFFu << (shift + 8));
    for (int e = t; e < NN; e += 1024) {
      unsigned v = vals[e];
      if ((v & hm) == (pre & hm)) atomicAdd(&hist[(v >> shift) & 255], 1);
    }
    __syncthreads();
    for (int off2 = 1; off2 < 256; off2 <<= 1) {
      int v = 0;
      if (t < 256 - off2) v = hist[t + off2];
      __syncthreads();
      if (t < 256 - off2) hist[t] += v;
      __syncthreads();
    }
    if (t < 256) {
      int cge = hist[t];
      int cgt = (t == 255) ? 0 : hist[t + 1];
      if (cge >= rank && cgt < rank) {
        selp_s = pre | ((unsigned)t << shift);
        selr_s = rank - cgt;
      }
    }
    __syncthreads();
  }
  float cu = __uint_as_float(selp_s);
  for (int ii = t; ii < MPAD; ii += 1024) {
    float c = fmaxf(__uint_as_float(vals[ii]) + 1e-7f - cu, 0.f);
    colw[b * MPAD + ii] = dnorm[b * MPAD + ii] * c;
  }
}

// ---------- L0 scale from binary AdjH + scale bf16-splits ----------
__global__ __launch_bounds__(256) void scaleB_k(const ushort_t* __restrict__ H,
                                                const float* __restrict__ colw,
                                                const float* __restrict__ dnorm,
                                                const float* __restrict__ rz,
                                                float* __restrict__ scale,
                                                ushort_t* __restrict__ sH,
                                                ushort_t* __restrict__ sL) {
  int gw = (blockIdx.x * 256 + threadIdx.x) >> 6;
  int lane = threadIdx.x & 63;
  int b = gw >> 11, i = gw & (NN - 1);
  const uint4* rowH = (const uint4*)(H + (long long)gw * NN);
  const float4* c4 = (const float4*)(colw + (long long)b * NN);
  float s = 0.f;
  for (int j = lane; j < NN / 8; j += 64) {
    uint4 av = rowH[j];
    float4 ca = c4[2 * j], cb = c4[2 * j + 1];
    if (av.x & 0xFFFFu) s += ca.x;  if (av.x >> 16) s += ca.y;
    if (av.y & 0xFFFFu) s += ca.z;  if (av.y >> 16) s += ca.w;
    if (av.z & 0xFFFFu) s += cb.x;  if (av.z >> 16) s += cb.y;
    if (av.w & 0xFFFFu) s += cb.z;  if (av.w >> 16) s += cb.w;
  }
  for (int off = 32; off > 0; off >>= 1) s += __shfl_down(s, off);
  if (lane == 0) {
    float rsum = rz[gw] * dnorm[gw] * (s + colw[(long long)b * NN + i]);
    float sc = rz[gw] * dnorm[gw] / fmaxf(rsum, 1e-12f);
    scale[gw] = sc;
    ushort_t h = f2bf(sc);
    sH[gw] = h;
    sL[gw] = f2bf(sc - bf2f(h));
  }
}

// ---------- L1 scale (fp32 A) ----------
__global__ __launch_bounds__(256) void scale_k(const float* __restrict__ A,
                                               const float* __restrict__ colw,
                                               const float* __restrict__ dnorm,
                                               const float* __restrict__ rz,
                                               float* __restrict__ scale, int R) {
  int gw = (blockIdx.x * 256 + threadIdx.x) >> 6;
  int lane = threadIdx.x & 63;
  int b = gw / R, i = gw - b * R;
  const float4* row = (const float4*)(A + (long long)gw * R);
  const float4* cw4 = (const float4*)(colw + (long long)b * R);
  int R4 = R >> 2;
  float s = 0.f;
  for (int j = lane; j < R4; j += 64) {
    float4 a = row[j], c = cw4[j];
    s += a.x * c.x + a.y * c.y + a.z * c.z + a.w * c.w;
  }
  for (int off = 32; off > 0; off >>= 1) s += __shfl_down(s, off);
  if (lane == 0) {
    float rsum = rz[gw] * dnorm[gw] * (s + colw[(long long)b * R + i]);
    scale[gw] = rz[gw] * dnorm[gw] / fmaxf(rsum, 1e-12f);
  }
}

// ---------- Abin[i][n] = AdjH[keep_i][n] + delta (exact bf16); cwk[i] = colw[keep_i] ----------
__global__ void writeAbin_k(const ushort_t* __restrict__ H, const int* __restrict__ keepidx,
                            const float* __restrict__ colw,
                            ushort_t* __restrict__ Abin, float* __restrict__ cwk) {
  long long g = (long long)blockIdx.x * 256 + threadIdx.x;
  int bi = (int)(g >> 9);
  int n = (int)(g & 511) * 4;
  int b = bi / MPAD;
  long long o = (long long)bi * NN + n;
  int row = keepidx[bi];
  if (row < 0) {
    *(uint2*)&Abin[o] = make_uint2(0, 0);
    if (n == 0) cwk[bi] = 0.f;
    return;
  }
  uint2 av = *(const uint2*)(H + ((long long)b * NN + row) * NN + n);
  ushort_t e0 = (ushort_t)(av.x & 0xFFFFu), e1 = (ushort_t)(av.x >> 16);
  ushort_t e2 = (ushort_t)(av.y & 0xFFFFu), e3 = (ushort_t)(av.y >> 16);
  if (n     == row) e0 = f2bf(bf2f(e0) + 1.f);
  if (n + 1 == row) e1 = f2bf(bf2f(e1) + 1.f);
  if (n + 2 == row) e2 = f2bf(bf2f(e2) + 1.f);
  if (n + 3 == row) e3 = f2bf(bf2f(e3) + 1.f);
  *(uint2*)&Abin[o] = make_uint2((unsigned)e0 | ((unsigned)e1 << 16),
                                 (unsigned)e2 | ((unsigned)e3 << 16));
  if (n == 0) cwk[bi] = colw[b * NN + row];
}

// ---------- L1 compact S2^T ----------
__global__ void writeS2c_k(const float* __restrict__ A2c, const float* __restrict__ scale,
                           const float* __restrict__ colw,
                           ushort_t* __restrict__ Sh, ushort_t* __restrict__ Sl) {
  int g = blockIdx.x * 256 + threadIdx.x;
  int bl = g / (MPAD / 4);
  int k = (g - bl * (MPAD / 4)) * 4;
  int b = bl / MPAD, l = bl - b * MPAD;
  long long o = (long long)bl * MPAD + k;
  float cw = colw[b * MPAD + l];
  float4 sc = *(const float4*)(scale + b * MPAD + k);
  float4 av = *(const float4*)(A2c + o);
  float v0 = sc.x * (av.x + (float)(k     == l)) * cw;
  float v1 = sc.y * (av.y + (float)(k + 1 == l)) * cw;
  float v2 = sc.z * (av.z + (float)(k + 2 == l)) * cw;
  float v3 = sc.w * (av.w + (float)(k + 3 == l)) * cw;
  ushort_t h0 = f2bf(v0), h1 = f2bf(v1), h2 = f2bf(v2), h3 = f2bf(v3);
  *(uint2*)&Sh[o] = make_uint2((unsigned)h0 | ((unsigned)h1 << 16),
                               (unsigned)h2 | ((unsigned)h3 << 16));
  ushort_t l0 = f2bf(v0 - bf2f(h0)), l1 = f2bf(v1 - bf2f(h1));
  ushort_t l2 = f2bf(v2 - bf2f(h2)), l3 = f2bf(v3 - bf2f(h3));
  *(uint2*)&Sl[o] = make_uint2((unsigned)l0 | ((unsigned)l1 << 16),
                               (unsigned)l2 | ((unsigned)l3 << 16));
}

// ---------- transpose + split, optional per-row scale ----------
__global__ __launch_bounds__(256) void cvt_xT_k(const float* __restrict__ X,
                                                const float* __restrict__ rsc,
                                                ushort_t* __restrict__ Th, ushort_t* __restrict__ Tl,
                                                int Nn, int Fd) {
  __shared__ float t[32][33];
  int b = blockIdx.z;
  int n0 = blockIdx.x * 32, f0 = blockIdx.y * 32;
  int tx = threadIdx.x & 31, ty = threadIdx.x >> 5;
  const float* Xb = X + ((long long)b * Nn + n0) * Fd + f0;
  for (int r = ty; r < 32; r += 8) {
    float sc = rsc ? rsc[(long long)b * Nn + n0 + r] : 1.f;
    t[r][tx] = sc * Xb[(long long)r * Fd + tx];
  }
  __syncthreads();
  for (int r = ty; r < 32; r += 8) {
    float v = t[tx][r];
    ushort_t h = f2bf(v);
    long long idx = ((long long)b * Fd + f0 + r) * Nn + n0 + tx;
    Th[idx] = h;
    Tl[idx] = f2bf(v - bf2f(h));
  }
}

// ============ MFMA split-bf16 GEMM, batch->XCD swizzled, optional split-K ============
template<int SA, int SB, int BSEL, int SYMM, int EPI>
__global__ __launch_bounds__(256) void mgemm_k(
    const ushort_t* __restrict__ Ah, const ushort_t* __restrict__ Al,
    const ushort_t* __restrict__ Bh, const ushort_t* __restrict__ Bl,
    const ushort_t* __restrict__ bsH, const ushort_t* __restrict__ bsL,
    float* __restrict__ Co, ushort_t* __restrict__ Toh, ushort_t* __restrict__ Tol,
    int M, int Ncol, int K, long long sA, long long sB, long long sC,
    const float* __restrict__ cwv, int gx, int ks, long long sPart) {
  __shared__ ushort_t Ahs[128 * 32];
  __shared__ ushort_t Bhs[128 * 32];
  __shared__ ushort_t Als[SA ? 128 * 32 : 64];
  __shared__ ushort_t Bls[SB ? 128 * 32 : 64];

  int tid = threadIdx.x;
  int id = blockIdx.x;
  long long bz = id & 7;
  int rest = id >> 3;
  int kslice = rest % ks;
  int t0 = rest / ks;
  int tm, tn;
  if constexpr (SYMM) {
    tm = 0; int base = 0;
    while (base + tm + 1 <= t0) { base += tm + 1; tm++; }
    tn = t0 - base;
  } else {
    tn = t0 % gx; tm = t0 / gx;
  }
  int n0 = tn * 128, m0 = tm * 128;
  const ushort_t* Ahb = Ah + bz * sA;
  const ushort_t* Alb = SA ? (Al + bz * sA) : Ah;
  const ushort_t* Bhb = Bh + bz * sB;
  const ushort_t* Blb = (SB && !BSEL) ? (Bl + bz * sB) : Bh;
  const ushort_t* bsHb = BSEL ? (bsH + bz * NN) : (const ushort_t*)0;
  const ushort_t* bsLb = BSEL ? (bsL + bz * NN) : (const ushort_t*)0;

  int sr = tid >> 2;
  int sc = (tid & 3) * 8;
  int lane = tid & 63, w = tid >> 6;
  int wm = (w >> 1) * 64, wn = (w & 1) * 64;
  int fr = lane & 15;
  int fo = (lane >> 4) * 8;
  int q = lane >> 4;

  f32x4 acc[4][4];
  f32x4 zz = {0.f, 0.f, 0.f, 0.f};
#pragma unroll
  for (int i = 0; i < 4; i++)
#pragma unroll
    for (int j = 0; j < 4; j++) acc[i][j] = zz;

  int Kpc = K / ks;
  int kbeg = kslice * Kpc;
  for (int k0 = kbeg; k0 < kbeg + Kpc; k0 += 32) {
    __syncthreads();
#pragma unroll
    for (int r = 0; r < 128; r += 64) {
      GLDS16(Ahb + (long long)(m0 + sr + r) * K + k0 + sc, &Ahs[(r + sr) * 32 + sc]);
      if constexpr (SA) {
        GLDS16(Alb + (long long)(m0 + sr + r) * K + k0 + sc, &Als[(r + sr) * 32 + sc]);
      }
    }
    if constexpr (BSEL) {
      uint4 shv = *(const uint4*)(bsHb + k0 + sc);
      uint4 slv = *(const uint4*)(bsLb + k0 + sc);
      const unsigned* shp = (const unsigned*)&shv;
      const unsigned* slp = (const unsigned*)&slv;
#pragma unroll
      for (int r = 0; r < 128; r += 64) {
        uint4 av = *(const uint4*)(Bhb + (long long)(n0 + sr + r) * K + k0 + sc);
        const unsigned* ap = (const unsigned*)&av;
        uint4 oh, ol;
        unsigned* ohp = (unsigned*)&oh;
        unsigned* olp = (unsigned*)&ol;
#pragma unroll
        for (int q2 = 0; q2 < 4; q2++) {
          unsigned a = ap[q2];
          unsigned msk = ((a & 0xFFFFu) ? 0xFFFFu : 0u) | ((a >> 16) ? 0xFFFF0000u : 0u);
          ohp[q2] = shp[q2] & msk;
          olp[q2] = slp[q2] & msk;
        }
        *(uint4*)&Bhs[(sr + r) * 32 + sc] = oh;
        *(uint4*)&Bls[(sr + r) * 32 + sc] = ol;
      }
    } else {
#pragma unroll
      for (int r = 0; r < 128; r += 64) {
        GLDS16(Bhb + (long long)(n0 + sr + r) * K + k0 + sc, &Bhs[(r + sr) * 32 + sc]);
        if constexpr (SB) {
          GLDS16(Blb + (long long)(n0 + sr + r) * K + k0 + sc, &Bls[(r + sr) * 32 + sc]);
        }
      }
    }
    __syncthreads();

    short8 ah[4], al[4], bh[4], bl[4];
#pragma unroll
    for (int i = 0; i < 4; i++) {
      ah[i] = *(const short8*)&Ahs[(wm + i * 16 + fr) * 32 + fo];
      if constexpr (SA) al[i] = *(const short8*)&Als[(wm + i * 16 + fr) * 32 + fo];
    }
#pragma unroll
    for (int j = 0; j < 4; j++) {
      bh[j] = *(const short8*)&Bhs[(wn + j * 16 + fr) * 32 + fo];
      if constexpr (SB) bl[j] = *(const short8*)&Bls[(wn + j * 16 + fr) * 32 + fo];
    }
#pragma unroll
    for (int i = 0; i < 4; i++)
#pragma unroll
      for (int j = 0; j < 4; j++) {
        acc[i][j] = __builtin_amdgcn_mfma_f32_16x16x32_bf16(ah[i], bh[j], acc[i][j], 0, 0, 0);
        if constexpr (SB)
          acc[i][j] = __builtin_amdgcn_mfma_f32_16x16x32_bf16(ah[i], bl[j], acc[i][j], 0, 0, 0);
        if constexpr (SA)
          acc[i][j] = __builtin_amdgcn_mfma_f32_16x16x32_bf16(al[i], bh[j], acc[i][j], 0, 0, 0);
      }
  }

#pragma unroll
  for (int i = 0; i < 4; i++)
#pragma unroll
    for (int j = 0; j < 4; j++)
#pragma unroll
      for (int r = 0; r < 4; r++) {
        float v = acc[i][j][r];
        int row = m0 + wm + i * 16 + q * 4 + r;
        int col = n0 + wn + j * 16 + fr;
        long long idx = bz * sC + (long long)row * Ncol + col;
        if constexpr (EPI == 0) {
          Co[kslice * sPart + idx] = v;
        } else if constexpr (EPI == 1) {
          ushort_t h = f2bf(v);
          Toh[idx] = h;
          Tol[idx] = f2bf(v - bf2f(h));
        } else if constexpr (EPI == 5) {
          float vq = floorf(v * 10000.f) / 10000.f;
          ushort_t h = f2bf(vq);
          ushort_t lo = f2bf(vq - bf2f(h));
          Co[idx] = vq; Toh[idx] = h; Tol[idx] = lo;
          if constexpr (SYMM) {
            if (tm != tn) {
              long long idxT = bz * sC + (long long)col * Ncol + row;
              Co[idxT] = vq; Toh[idxT] = h; Tol[idxT] = lo;
            }
          }
        } else if constexpr (EPI == 6) {
          Co[idx] = cwv[bz * MPAD + row] * v;
        } else if constexpr (EPI == 7) {
          float vs = cwv[bz * MPAD + row] * cwv[bz * MPAD + col] * v;
          float vq = floorf(vs * 10000.f) / 10000.f;
          ushort_t h = f2bf(vq);
          ushort_t lo = f2bf(vq - bf2f(h));
          Co[idx] = vq; Toh[idx] = h; Tol[idx] = lo;
          if constexpr (SYMM) {
            if (tm != tn) {
              long long idxT = bz * sC + (long long)col * Ncol + row;
              Co[idxT] = vq; Toh[idxT] = h; Tol[idxT] = lo;
            }
          }
        } else {  // EPI == 8
          float vs = v * cwv[bz * NN + col];
          ushort_t h = f2bf(vs);
          Toh[idx] = h;
          Tol[idx] = f2bf(vs - bf2f(h));
        }
      }
}

// ---------- GCN1 epilogue (sums 2 split-K partials) ----------
__global__ void epi_k(const float* __restrict__ acc0, const float* __restrict__ acc1,
                      const float* __restrict__ xw,
                      const float* __restrict__ dgcn, const float* __restrict__ diag,
                      const float* __restrict__ bias, const float* __restrict__ mask,
                      float* __restrict__ outx) {
  long long i = (long long)blockIdx.x * 256 + threadIdx.x;
  int rowi = (int)(i >> 7);
  int f = (int)(i & 127);
  float d = dgcn[rowi];
  float t = d * (acc0[i] + acc1[i] + (1.f - diag[rowi]) * d * xw[i]) + bias[f];
  t *= mask[rowi];
  outx[i] = fmaxf(t, 0.f);
}

// ---------- final epilogue (sums 2 split-K partials) ----------
__global__ void epic_k(const float* __restrict__ acc0, const float* __restrict__ acc1,
                       const float* __restrict__ xw,
                       const float* __restrict__ dgcn, const float* __restrict__ diag,
                       const float* __restrict__ bias, const float* __restrict__ mask,
                       const int* __restrict__ kmap, float* __restrict__ outx) {
  long long i = (long long)blockIdx.x * 256 + threadIdx.x;
  int rowi = (int)(i >> 8);
  int f = (int)(i & 255);
  int b = rowi / MPAD;
  int km = kmap[rowi];
  float mv = (km >= 0) ? mask[b * NN + km] : 1.f;
  float d = dgcn[rowi];
  float t = d * (acc0[i] + acc1[i] + (1.f - diag[rowi]) * d * xw[i]) + bias[f];
  outx[i] = t * mv;
}

// ---------- sum split-K partials, optional row scale (shift = log2 Fd) ----------
__global__ void sumP_k(const float* __restrict__ parts, float* __restrict__ out,
                       int np, long long psize, const float* __restrict__ cwv, int shift) {
  long long i = (long long)blockIdx.x * 256 + threadIdx.x;
  float s = 0.f;
  for (int p = 0; p < np; p++) s += parts[p * psize + i];
  float c = cwv ? cwv[(int)(i >> shift)] : 1.f;
  out[i] = c * s;
}

// ---------- two-stage column means ----------
__global__ void pmean_k(const float* __restrict__ X, float* __restrict__ part,
                        int Nn, int Fd, int rpc) {
  int b = blockIdx.y, c = blockIdx.x, f = threadIdx.x;
  const float* p = X + ((long long)b * Nn + (long long)c * rpc) * Fd + f;
  float s = 0.f;
  for (int r = 0; r < rpc; r++) s += p[(long long)r * Fd];
  part[((long long)b * gridDim.x + c) * Fd + f] = s;
}

__global__ void fmean_k(const float* __restrict__ part, int nch, int Fd, float corr,
                        const float* __restrict__ bias, float* __restrict__ out, int outoff) {
  int b = blockIdx.x, f = threadIdx.x;
  float s = 0.f;
  for (int c = 0; c < nch; c++) s += part[((long long)b * nch + c) * Fd + f];
  float cv = bias ? corr * bias[f] : 0.f;
  out[b * (HH + FF) + outoff + f] = s * (1.f / NN) + cv;
}

// ---------- fp32 VALU GEMM; epilogue also emits rsc-scaled transposed bf16 splits ----------
__global__ __launch_bounds__(256) void gemm_k(const float* __restrict__ A, const float* __restrict__ B,
                                              float* __restrict__ C,
                                              const float* __restrict__ rsc,
                                              ushort_t* __restrict__ Th, ushort_t* __restrict__ Tl,
                                              int M, int Nw, int Kk, int Nn,
                                              long long sA, long long sB, long long sC) {
  __shared__ float As[16][128];
  __shared__ float Bs[16][128];
  int tid = threadIdx.x;
  int n0 = blockIdx.x * 128, m0 = blockIdx.y * 128;
  int bz = blockIdx.z;
  const float* Ab = A + (long long)bz * sA;
  const float* Bb = B + (long long)bz * sB;
  float* Cb = C + (long long)bz * sC;
  float acc[8][8];
#pragma unroll
  for (int i = 0; i < 8; i++)
#pragma unroll
    for (int j = 0; j < 8; j++) acc[i][j] = 0.f;
  int tx = tid & 15, ty = tid >> 4;

  for (int k0 = 0; k0 < Kk; k0 += 16) {
    {
      int r = tid >> 2, c = (tid & 3) << 2;
#pragma unroll
      for (int rr = 0; rr < 2; rr++) {
        int rrow = r + rr * 64;
        float4 v = *(const float4*)(Ab + (long long)(m0 + rrow) * Kk + k0 + c);
        As[c + 0][rrow] = v.x; As[c + 1][rrow] = v.y;
        As[c + 2][rrow] = v.z; As[c + 3][rrow] = v.w;
      }
    }
    {
      int kk = tid >> 5, cc = (tid & 31) << 2;
#pragma unroll
      for (int k2 = 0; k2 < 2; k2++) {
        float4 v = *(const float4*)(Bb + (long long)(k0 + kk + k2 * 8) * Nw + n0 + cc);
        *(float4*)&Bs[kk + k2 * 8][cc] = v;
      }
    }
    __syncthreads();
#pragma unroll
    for (int kk = 0; kk < 16; kk++) {
      float a[8], bb[8];
      *(float4*)&a[0]  = *(float4*)&As[kk][ty * 8];
      *(float4*)&a[4]  = *(float4*)&As[kk][ty * 8 + 4];
      *(float4*)&bb[0] = *(float4*)&Bs[kk][tx * 8];
      *(float4*)&bb[4] = *(float4*)&Bs[kk][tx * 8 + 4];
#pragma unroll
      for (int i = 0; i < 8; i++)
#pragma unroll
        for (int j = 0; j < 8; j++) acc[i][j] += a[i] * bb[j];
    }
    __syncthreads();
  }
#pragma unroll
  for (int i = 0; i < 8; i++) {
    float* cp = Cb + (long long)(m0 + ty * 8 + i) * Nw + n0 + tx * 8;
    *(float4*)cp = *(float4*)&acc[i][0];
    *(float4*)(cp + 4) = *(float4*)&acc[i][4];
  }
  // transposed split store: T[(b*Fd + col)*Nn + row] = rsc[b*Nn+row] * v
  if (Th) {
#pragma unroll
    for (int j = 0; j < 8; j++) {
      int col = n0 + tx * 8 + j;
      ushort_t hs[8], ls[8];
#pragma unroll
      for (int i = 0; i < 8; i++) {
        int r2 = m0 + ty * 8 + i;
        float v = rsc[(long long)bz * Nn + r2] * acc[i][j];
        hs[i] = f2bf(v);
        ls[i] = f2bf(v - bf2f(hs[i]));
      }
      long long o = ((long long)bz * Nw + col) * Nn + m0 + ty * 8;
      *(uint4*)&Th[o] = *(uint4*)hs;
      *(uint4*)&Tl[o] = *(uint4*)ls;
    }
  }
}

extern "C" void kernel_launch(void* const* d_in, const int* in_sizes, int n_in,
                              void* d_out, int out_size, void* d_ws, size_t ws_size,
                              hipStream_t stream) {
  const float* x    = (const float*)d_in[0];
  const float* adj  = (const float*)d_in[1];
  const float* mask = (const float*)d_in[2];
  const float* W1   = (const float*)d_in[3];
  const float* b1   = (const float*)d_in[4];
  const float* Watt = (const float*)d_in[5];
  const float* batt = (const float*)d_in[6];
  const float* W2   = (const float*)d_in[7];
  const float* b2   = (const float*)d_in[8];
  float* out = (float*)d_out;

  const long long NN2  = (long long)NN * NN;
  const long long CSTR = (long long)MPAD * NN;
  const long long CTOT = (long long)NB * CSTR;
  const long long M2   = (long long)MPAD * MPAD;
  const long long M2T  = (long long)NB * M2;
  const long long NH   = (long long)NROWS * HH;     // 2,097,152
  const long long MH   = (long long)MC * HH;        // 1,179,648
  const long long MF   = (long long)MC * FF;        // 2,359,296

  // ---- workspace (~260 MB) ----
  float* ws = (float*)d_ws;
  long long off = 0;
  ushort_t* S2cH = (ushort_t*)(ws + off); off += M2T;
  float* A2CR = ws + off; off += M2T * 2;
  float* TcF  = ws + off; off += CTOT;
  ushort_t* Abin = (ushort_t*)(ws + off); off += CTOT / 2;
  float* xa   = ws + off; off += NH;
  float* x2c  = ws + off; off += MH;
  float* x3c  = ws + off; off += MH;
  float* diag   = ws + off; off += NROWS;
  float* dgcn   = ws + off; off += NROWS;
  float* dnorm  = ws + off; off += NROWS;
  float* rz     = ws + off; off += NROWS;
  float* wv     = ws + off; off += NROWS;
  float* alphav = ws + off; off += (long long)NB * NN;
  float* colwv  = ws + off; off += NROWS;
  float* scalev = ws + off; off += NROWS;
  ushort_t* sHs = (ushort_t*)(ws + off); off += NROWS / 2;
  ushort_t* sLs = (ushort_t*)(ws + off); off += NROWS / 2;
  int* keepidx  = (int*)(ws + off); off += NB * MPAD;
  float* cwk    = ws + off; off += MC;
  float* partm  = ws + off; off += NB * 16 * FF;

  ushort_t* S2cL = S2cH + M2T;
  ushort_t* AdjH = (ushort_t*)A2CR;
  float* A2cF = A2CR;
  ushort_t* A2cH = (ushort_t*)(A2CR + M2T);
  ushort_t* A2cL = A2cH + M2T;

  // TcF phase aliases
  float* u1 = TcF;                                   // GCN1 xw1 (NH)
  float* u2p = TcF + NH;                             // GCN1 acc partials (2 x NH)
  ushort_t* y1Th = (ushort_t*)(TcF + 3 * NH);        // y1T splits
  ushort_t* y1Tl = y1Th + NH;
  ushort_t* Rh = (ushort_t*)TcF;                     // R splits (CTOT each) [G1n..G2n]
  ushort_t* Rl = Rh + CTOT;
  ushort_t* xT1h = (ushort_t*)TcF;                   // x1T splits [G3n]
  ushort_t* xT1l = xT1h + NH;
  float* g3p = TcF + NH;                             // G3n partials (4 x MH)
  ushort_t* Tc2H = (ushort_t*)TcF;                   // L1 tmp2 splits (M2T each)
  ushort_t* Tc2L = Tc2H + M2T;
  ushort_t* x2Th = (ushort_t*)(TcF + M2T);           // x2T splits [G3']
  ushort_t* x2Tl = x2Th + MH;
  float* g3pp = TcF + M2T + MH;                      // G3' partials (3 x MH)
  float* u1f = TcF;                                  // final xw2c (MF)
  ushort_t* y2Th = (ushort_t*)(TcF + MF);            // y2T splits
  ushort_t* y2Tl = y2Th + MF;
  float* u2fp = TcF + 2 * MF;                        // final acc partials (2 x MF)

  // ================= GCN1 (full space) =================
  rowstats_k<<<NROWS / 4, 256, 0, stream>>>(adj, AdjH, diag, dgcn, dnorm, rz, NN);
  // xw1 = x@W1; epilogue emits y1T = dgcn-scaled transposed splits
  gemm_k<<<dim3(1, NN / 128, NB), 256, 0, stream>>>(
      x, W1, u1, dgcn, y1Th, y1Tl, NN, HH, FF, NN,
      (long long)NN * FF, 0, (long long)NN * HH);
  // acc1 = adjbin @ y1, split-K x2
  mgemm_k<0, 1, 0, 0, 0><<<1 * (NN / 128) * NB * 2, 256, 0, stream>>>(
      AdjH, 0, y1Th, y1Tl, 0, 0, u2p, 0, 0,
      NN, HH, NN, NN2, (long long)HH * NN, (long long)NN * HH, 0, 1, 2, NH);
  epi_k<<<(int)(NH / 256), 256, 0, stream>>>(u2p, u2p + NH, u1, dgcn, diag, b1, mask, xa);
  pmean_k<<<dim3(16, NB), HH, 0, stream>>>(xa, partm, NN, HH, 128);
  fmean_k<<<NB, HH, 0, stream>>>(partm, 16, HH, 0.f, 0, out, 0);

  // ================= coarsen layer 0 =================
  wvec_k<<<NROWS / 4, 256, 0, stream>>>(xa, Watt, batt, dnorm, wv);
  alphaB_k<<<NROWS / 4, 256, 0, stream>>>(AdjH, wv, dnorm, rz, alphav);
  topkeep_k<<<NB, 1024, 0, stream>>>(alphav, dnorm, rz, colwv, keepidx);
  scaleB_k<<<NROWS / 4, 256, 0, stream>>>(AdjH, colwv, dnorm, rz, scalev, sHs, sLs);
  writeAbin_k<<<(int)(CTOT / 4 / 256), 256, 0, stream>>>(AdjH, keepidx, colwv, Abin, cwk);
  // G1n: R = (Abin @ [scale_n * adjbin]) * scale_col
  mgemm_k<0, 1, 1, 0, 8><<<(NN / 128) * (MPAD / 128) * NB, 256, 0, stream>>>(
      Abin, 0, AdjH, 0, sHs, sLs, 0, Rh, Rl,
      MPAD, NN, NN, CSTR, NN2, CSTR, scalev, NN / 128, 1, 0);
  // G2n: A2c = cw*cw*(R @ Abin^T) quantized, symmetric lower-triangle + mirror
  mgemm_k<1, 0, 0, 1, 7><<<45 * NB, 256, 0, stream>>>(
      Rh, Rl, Abin, 0, 0, 0, A2cF, A2cH, A2cL,
      MPAD, MPAD, NN, CSTR, CSTR, M2, cwk, MPAD / 128, 1, 0);
  // G3n: x2c = cw * (Abin @ (scale*x1)), split-K x4
  cvt_xT_k<<<dim3(NN / 32, HH / 32, NB), 256, 0, stream>>>(xa, scalev, xT1h, xT1l, NN, HH);
  mgemm_k<0, 1, 0, 0, 0><<<1 * (MPAD / 128) * NB * 4, 256, 0, stream>>>(
      Abin, 0, xT1h, xT1l, 0, 0, g3p, 0, 0,
      MPAD, HH, NN, CSTR, (long long)HH * NN, (long long)MPAD * HH, 0, 1, 4, MH);
  sumP_k<<<(int)(MH / 256), 256, 0, stream>>>(g3p, x2c, 4, MH, cwk, 7);

  // ================= coarsen layer 1 (all compact) =================
  rowstatsw_k<<<MC / 4, 256, 0, stream>>>(A2cF, x2c, Watt, batt, diag, dgcn, dnorm, rz, wv, MPAD);
  alpha_k<<<MC / 4, 256, 0, stream>>>(A2cF, wv, dnorm, rz, alphav, MPAD);
  padfill_k<<<((NN - MPAD) * NB) / 256, 256, 0, stream>>>(alphav);
  topcolw_k<<<NB, 1024, 0, stream>>>(alphav, dnorm, colwv);
  scale_k<<<MC / 4, 256, 0, stream>>>(A2cF, colwv, dnorm, rz, scalev, MPAD);
  writeS2c_k<<<(int)(M2T / 4 / 256), 256, 0, stream>>>(A2cF, scalev, colwv, S2cH, S2cL);
  // G1': tmp2^T = S2^T @ A2c
  mgemm_k<1, 1, 0, 0, 1><<<(MPAD / 128) * (MPAD / 128) * NB, 256, 0, stream>>>(
      S2cH, S2cL, A2cH, A2cL, 0, 0, 0, Tc2H, Tc2L,
      MPAD, MPAD, MPAD, M2, M2, M2, 0, MPAD / 128, 1, 0);
  // G2': A3c = S2^T @ tmp2 quantized, symmetric lower-triangle + mirror
  mgemm_k<1, 1, 0, 1, 5><<<45 * NB, 256, 0, stream>>>(
      S2cH, S2cL, Tc2H, Tc2L, 0, 0, A2cF, A2cH, A2cL,
      MPAD, MPAD, MPAD, M2, M2, M2, 0, MPAD / 128, 1, 0);
  // G3': x3c = S2^T @ x2c, split-K x3
  cvt_xT_k<<<dim3(MPAD / 32, HH / 32, NB), 256, 0, stream>>>(x2c, 0, x2Th, x2Tl, MPAD, HH);
  mgemm_k<1, 1, 0, 0, 0><<<1 * (MPAD / 128) * NB * 3, 256, 0, stream>>>(
      S2cH, S2cL, x2Th, x2Tl, 0, 0, g3pp, 0, 0,
      MPAD, HH, MPAD, M2, (long long)HH * MPAD, (long long)MPAD * HH, 0, 1, 3, MH);
  sumP_k<<<(int)(MH / 256), 256, 0, stream>>>(g3pp, x3c, 3, MH, 0, 7);

  // ================= final GCN (compact) =================
  rowstats_k<<<MC / 4, 256, 0, stream>>>(A2cF, 0, diag, dgcn, dnorm, rz, MPAD);
  // xw2 = x3c@W2; epilogue emits y2T = dgcn-scaled transposed splits
  gemm_k<<<dim3(FF / 128, MPAD / 128, NB), 256, 0, stream>>>(
      x3c, W2, u1f, dgcn, y2Th, y2Tl, MPAD, FF, HH, MPAD,
      (long long)MPAD * HH, 0, (long long)MPAD * FF);
  // acc = A3c @ y2, split-K x2
  mgemm_k<1, 1, 0, 0, 0><<<(FF / 128) * (MPAD / 128) * NB * 2, 256, 0, stream>>>(
      A2cH, A2cL, y2Th, y2Tl, 0, 0, u2fp, 0, 0,
      MPAD, FF, MPAD, M2, (long long)FF * MPAD, (long long)MPAD * FF, 0, FF / 128, 2, MF);
  epic_k<<<(int)(MF / 256), 256, 0, stream>>>(u2fp, u2fp + MF, u1f, dgcn, diag, b2, mask,
                                              keepidx, u2fp);
  pmean_k<<<dim3(9, NB), FF, 0, stream>>>(u2fp, partm, MPAD, FF, 128);
  fmean_k<<<NB, FF, 0, stream>>>(partm, 9, FF, (float)(NN - MPAD) / NN, b2, out, HH);
}